// Round 7
// baseline (468.434 us; speedup 1.0000x reference)
//
#include <hip/hip_runtime.h>
#include <hip/hip_bf16.h>
#include <math.h>

#define DIMN   1024
#define HEADS  16
#define DHEAD  64
#define CTXD   768
#define FFH    4096
#define NTOK   4096
#define SEQ    2048
#define NCTX   77
#define CTOK   154

typedef unsigned short u16;
typedef __bf16 bf16x8 __attribute__((ext_vector_type(8)));
typedef float  f32x4  __attribute__((ext_vector_type(4)));

__device__ __forceinline__ u16 f2bf(float f) {
  union { float f; unsigned u; } c; c.f = f;
  unsigned r = c.u + 0x7FFFu + ((c.u >> 16) & 1u);
  return (u16)(r >> 16);
}
__device__ __forceinline__ float bf2f(u16 h) {
  union { unsigned u; float f; } c; c.u = ((unsigned)h) << 16; return c.f;
}

__device__ __forceinline__ void gload16(const void* g, void* l) {
  __builtin_amdgcn_global_load_lds(
      (__attribute__((address_space(1))) void*)(void*)(g),
      (__attribute__((address_space(3))) void*)(l), 16, 0, 0);
}

__device__ __forceinline__ f32x4 mfma16(bf16x8 a, bf16x8 b, f32x4 c) {
  return __builtin_amdgcn_mfma_f32_16x16x32_bf16(a, b, c, 0, 0, 0);
}

// ---------------- batched weight convert+transpose: W[K][N] f32 -> WT[N][K] bf16
struct WBatch { const float* s[6]; u16* d[6]; };

template<int NB>
__global__ __launch_bounds__(256)
void wconvB_k(WBatch wb, int K, int N)
{
  __shared__ u16 t[64][65];
  const float* __restrict__ W  = wb.s[blockIdx.z];
  u16* __restrict__       WT   = wb.d[blockIdx.z];
  int n0 = blockIdx.x * 64, k0 = blockIdx.y * 64;
  int tid = threadIdx.x;
  int rr = tid >> 4, cc = tid & 15;
#pragma unroll
  for (int i = 0; i < 4; ++i) {
    int kr = rr + i * 16;
    const float4 v = *(const float4*)&W[(size_t)(k0 + kr) * N + n0 + cc * 4];
    t[kr][cc*4+0] = f2bf(v.x); t[kr][cc*4+1] = f2bf(v.y);
    t[kr][cc*4+2] = f2bf(v.z); t[kr][cc*4+3] = f2bf(v.w);
  }
  __syncthreads();
#pragma unroll
  for (int i = 0; i < 4; ++i) {
    int nr = rr + i * 16;
    int r0 = cc * 4;
    ushort4 o;
    o.x = t[r0+0][nr]; o.y = t[r0+1][nr]; o.z = t[r0+2][nr]; o.w = t[r0+3][nr];
    *(ushort4*)&WT[(size_t)(n0 + nr) * K + k0 + r0] = o;
  }
}

__global__ __launch_bounds__(256)
void wconv_k(const float* __restrict__ W, u16* __restrict__ WT, int K, int N)
{
  __shared__ u16 t[64][65];
  int n0 = blockIdx.x * 64, k0 = blockIdx.y * 64;
  int tid = threadIdx.x;
  int rr = tid >> 4, cc = tid & 15;
#pragma unroll
  for (int i = 0; i < 4; ++i) {
    int kr = rr + i * 16;
    const float4 v = *(const float4*)&W[(size_t)(k0 + kr) * N + n0 + cc * 4];
    t[kr][cc*4+0] = f2bf(v.x); t[kr][cc*4+1] = f2bf(v.y);
    t[kr][cc*4+2] = f2bf(v.z); t[kr][cc*4+3] = f2bf(v.w);
  }
  __syncthreads();
#pragma unroll
  for (int i = 0; i < 4; ++i) {
    int nr = rr + i * 16;
    int r0 = cc * 4;
    ushort4 o;
    o.x = t[r0+0][nr]; o.y = t[r0+1][nr]; o.z = t[r0+2][nr]; o.w = t[r0+3][nr];
    *(ushort4*)&WT[(size_t)(n0 + nr) * K + k0 + r0] = o;
  }
}

// ---------------- f32 -> bf16 elementwise (context)
__global__ void cconv_k(const float* __restrict__ c, u16* __restrict__ o, int n)
{
  int i = blockIdx.x * 256 + threadIdx.x;
  if (i < n) o[i] = f2bf(c[i]);
}

// ---------------- LayerNorm: f32 row[1024] -> bf16
__global__ __launch_bounds__(256)
void ln_k(const float* __restrict__ x, const float* __restrict__ gm,
          const float* __restrict__ bt, u16* __restrict__ o)
{
  int row = blockIdx.x;
  int tid = threadIdx.x;
  const float4 v = *(const float4*)&x[(size_t)row * DIMN + tid * 4];
  float s = v.x + v.y + v.z + v.w;
  float q = v.x*v.x + v.y*v.y + v.z*v.z + v.w*v.w;
#pragma unroll
  for (int off = 32; off; off >>= 1) { s += __shfl_xor(s, off); q += __shfl_xor(q, off); }
  __shared__ float ss[4], qq[4];
  int wave = tid >> 6;
  if ((tid & 63) == 0) { ss[wave] = s; qq[wave] = q; }
  __syncthreads();
  s = ss[0] + ss[1] + ss[2] + ss[3];
  q = qq[0] + qq[1] + qq[2] + qq[3];
  float mu = s * (1.0f / DIMN);
  float var = q * (1.0f / DIMN) - mu * mu;
  float rs = rsqrtf(var + 1e-5f);
  const float4 gv = *(const float4*)&gm[tid * 4];
  const float4 bv = *(const float4*)&bt[tid * 4];
  ushort4 r;
  r.x = f2bf((v.x - mu) * rs * gv.x + bv.x);
  r.y = f2bf((v.y - mu) * rs * gv.y + bv.y);
  r.z = f2bf((v.z - mu) * rs * gv.z + bv.z);
  r.w = f2bf((v.w - mu) * rs * gv.w + bv.w);
  *(ushort4*)&o[(size_t)row * DIMN + tid * 4] = r;
}

// ---------------- GEMM v5: 256 threads, 4 waves, 64x64 wave tile, 2-buf counted vmcnt
// A[M][K] bf16 row-major, Bt[N][K] bf16
// MODE 0: out bf16 = acc + bias
// MODE 2: out f32 = acc + bias + resid
// MODE 3: vt store (kv-permuted within 64-granule to match attn P layout)
// MODE 4: QKV fused: colgrp 0->obf (q), 1->ob2 (k), 2->ob3 (vt store)
// MODE 5: KV fused:  colgrp 0->obf (k), 1->ob3 (vt store)
template<int MODE>
__global__ __launch_bounds__(256, 2)
void gemm_k(const u16* __restrict__ A, const u16* __restrict__ Bt,
            int M, int N, int K,
            const float* __restrict__ bias, const float* __restrict__ resid,
            u16* __restrict__ obf, float* __restrict__ of32,
            int seq, int vstride,
            u16* __restrict__ ob2, u16* __restrict__ ob3)
{
  __shared__ __align__(16) u16 As[2][128 * 32];
  __shared__ __align__(16) u16 Bs[2][128 * 32];
  const int tid = threadIdx.x;
  const int lane = tid & 63, wave = tid >> 6;
  const int wr = wave >> 1, wc = wave & 1;          // 2 x 2 wave grid, 64x64 each
  const int g = lane >> 4, r16 = lane & 15;
  const int m0 = blockIdx.x * 128, n0 = blockIdx.y * 128;

  f32x4 acc[4][4] = {};

  // staging: each thread 2 A-chunks + 2 B-chunks of 16B (512 chunks per matrix)
  int ar0[2], br0[2], chs0[2];
#pragma unroll
  for (int i = 0; i < 2; ++i) {
    const int c = tid + i * 256;
    const int r = c >> 2, ch = c & 3;
    chs0[i] = ch ^ ((r >> 1) & 3);
    ar0[i] = (m0 + r > M - 1) ? (M - 1) : (m0 + r);
    br0[i] = n0 + r;
  }

  auto stage = [&](int buf, int kt) {
#pragma unroll
    for (int i = 0; i < 2; ++i) {
      const int c = tid + i * 256;
      gload16(A  + (size_t)ar0[i] * K + kt + chs0[i] * 8, &As[buf][c * 8]);
      gload16(Bt + (size_t)br0[i] * K + kt + chs0[i] * 8, &Bs[buf][c * 8]);
    }
  };

  stage(0, 0);

  const int nkt = K >> 5;
  for (int t = 0; t < nkt; ++t) {
    const int cur = t & 1;
    if (t + 1 < nkt) {
      stage(cur ^ 1, (t + 1) << 5);
      asm volatile("s_waitcnt vmcnt(4)" ::: "memory");   // stage(t) landed; t+1 in flight
    } else {
      asm volatile("s_waitcnt vmcnt(0)" ::: "memory");
    }
    __builtin_amdgcn_s_barrier();                        // B1

    bf16x8 af[4], bfr[4];
#pragma unroll
    for (int mi = 0; mi < 4; ++mi) {
      int r = wr * 64 + mi * 16 + r16;
      int cph = g ^ ((r >> 1) & 3);
      af[mi] = *(const bf16x8*)&As[cur][(r * 4 + cph) * 8];
    }
#pragma unroll
    for (int ni = 0; ni < 4; ++ni) {
      int r = wc * 64 + ni * 16 + r16;
      int cph = g ^ ((r >> 1) & 3);
      bfr[ni] = *(const bf16x8*)&Bs[cur][(r * 4 + cph) * 8];
    }
    __builtin_amdgcn_s_setprio(1);
#pragma unroll
    for (int mi = 0; mi < 4; ++mi)
#pragma unroll
      for (int ni = 0; ni < 4; ++ni)
        acc[mi][ni] = mfma16(af[mi], bfr[ni], acc[mi][ni]);
    __builtin_amdgcn_s_setprio(0);

    __builtin_amdgcn_s_barrier();                        // B2 (WAR)
  }

  const int grp = n0 >> 10;           // column group for fused modes
#pragma unroll
  for (int ni = 0; ni < 4; ++ni) {
    int col = n0 + wc * 64 + ni * 16 + r16;
    float bv = 0.0f;
    if constexpr (MODE == 0 || MODE == 2) bv = bias ? bias[col] : 0.0f;
    const int c1 = col & 1023;
#pragma unroll
    for (int mi = 0; mi < 4; ++mi) {
      f32x4 c = acc[mi][ni];
#pragma unroll
      for (int rg = 0; rg < 4; ++rg) {
        int row = m0 + wr * 64 + mi * 16 + g * 4 + rg;
        if (row < M) {
          float v = c[rg] + bv;
          if constexpr (MODE == 0) {
            obf[(size_t)row * N + col] = f2bf(v);
          } else if constexpr (MODE == 2) {
            size_t o = (size_t)row * N + col;
            of32[o] = v + resid[o];
          } else if constexpr (MODE == 3) {
            int b = row / seq, srow_ = row - b * seq;
            int jg = srow_ >> 6, j = srow_ & 63;
            int pos = jg * 64 + ((j & 15) << 2) + (j >> 4);
            obf[((size_t)b * HEADS * DHEAD + c1) * vstride + pos] = f2bf(v);
          } else if constexpr (MODE == 4) {
            if (grp == 0) {
              obf[(size_t)row * 1024 + c1] = f2bf(v);
            } else if (grp == 1) {
              ob2[(size_t)row * 1024 + c1] = f2bf(v);
            } else {
              int b = row / seq, srow_ = row - b * seq;
              int jg = srow_ >> 6, j = srow_ & 63;
              int pos = jg * 64 + ((j & 15) << 2) + (j >> 4);
              ob3[((size_t)b * HEADS * DHEAD + c1) * vstride + pos] = f2bf(v);
            }
          } else {  // MODE 5
            if (grp == 0) {
              obf[(size_t)row * 1024 + c1] = f2bf(v);
            } else {
              int b = row / seq, srow_ = row - b * seq;
              int jg = srow_ >> 6, j = srow_ & 63;
              int pos = jg * 64 + ((j & 15) << 2) + (j >> 4);
              ob3[((size_t)b * HEADS * DHEAD + c1) * vstride + pos] = f2bf(v);
            }
          }
        }
      }
    }
  }
}

// ---------------- fused GEGLU GEMM v2: 256 threads, 4 waves, 64x64 wave tile
// out = (A@B1 + ba) * gelu(A@B2 + bg)
__global__ __launch_bounds__(256, 2)
void geglu_k(const u16* __restrict__ A, const u16* __restrict__ B1t,
             const u16* __restrict__ B2t,
             const float* __restrict__ ba, const float* __restrict__ bg,
             u16* __restrict__ out, int M, int N)
{
  __shared__ __align__(16) u16 As[2][128 * 32];
  __shared__ __align__(16) u16 B1s[2][128 * 32];
  __shared__ __align__(16) u16 B2s[2][128 * 32];
  const int tid = threadIdx.x;
  const int lane = tid & 63, wave = tid >> 6;
  const int wr = wave >> 1, wc = wave & 1;
  const int g = lane >> 4, r16 = lane & 15;
  const int m0 = blockIdx.x * 128, n0 = blockIdx.y * 128;
  const int K = 1024;

  f32x4 acca[4][4] = {}, accg[4][4] = {};

  int ar0[2], br0[2], chs0[2];
#pragma unroll
  for (int i = 0; i < 2; ++i) {
    const int c = tid + i * 256;
    const int r = c >> 2, ch = c & 3;
    chs0[i] = ch ^ ((r >> 1) & 3);
    ar0[i] = m0 + r;
    br0[i] = n0 + r;
  }

  auto stage = [&](int buf, int kt) {
#pragma unroll
    for (int i = 0; i < 2; ++i) {
      const int c = tid + i * 256;
      gload16(A   + (size_t)ar0[i] * K + kt + chs0[i] * 8, &As[buf][c * 8]);
      gload16(B1t + (size_t)br0[i] * K + kt + chs0[i] * 8, &B1s[buf][c * 8]);
      gload16(B2t + (size_t)br0[i] * K + kt + chs0[i] * 8, &B2s[buf][c * 8]);
    }
  };

  stage(0, 0);

  const int nkt = K >> 5;
  for (int t = 0; t < nkt; ++t) {
    const int cur = t & 1;
    if (t + 1 < nkt) {
      stage(cur ^ 1, (t + 1) << 5);
      asm volatile("s_waitcnt vmcnt(6)" ::: "memory");
    } else {
      asm volatile("s_waitcnt vmcnt(0)" ::: "memory");
    }
    __builtin_amdgcn_s_barrier();                        // B1

    bf16x8 af[4], b1f[4], b2f[4];
#pragma unroll
    for (int mi = 0; mi < 4; ++mi) {
      int r = wr * 64 + mi * 16 + r16;
      int cph = g ^ ((r >> 1) & 3);
      af[mi] = *(const bf16x8*)&As[cur][(r * 4 + cph) * 8];
    }
#pragma unroll
    for (int ni = 0; ni < 4; ++ni) {
      int r = wc * 64 + ni * 16 + r16;
      int cph = g ^ ((r >> 1) & 3);
      b1f[ni] = *(const bf16x8*)&B1s[cur][(r * 4 + cph) * 8];
      b2f[ni] = *(const bf16x8*)&B2s[cur][(r * 4 + cph) * 8];
    }
    __builtin_amdgcn_s_setprio(1);
#pragma unroll
    for (int mi = 0; mi < 4; ++mi)
#pragma unroll
      for (int ni = 0; ni < 4; ++ni) {
        acca[mi][ni] = mfma16(af[mi], b1f[ni], acca[mi][ni]);
        accg[mi][ni] = mfma16(af[mi], b2f[ni], accg[mi][ni]);
      }
    __builtin_amdgcn_s_setprio(0);

    __builtin_amdgcn_s_barrier();                        // B2
  }

#pragma unroll
  for (int ni = 0; ni < 4; ++ni) {
    int col = n0 + wc * 64 + ni * 16 + r16;
    float bva = ba[col], bvg = bg[col];
#pragma unroll
    for (int mi = 0; mi < 4; ++mi) {
#pragma unroll
      for (int rg = 0; rg < 4; ++rg) {
        int row = m0 + wr * 64 + mi * 16 + g * 4 + rg;
        float a  = acca[mi][ni][rg] + bva;
        float gt = accg[mi][ni][rg] + bvg;
        float gl = 0.5f * gt * (1.0f + erff(gt * 0.70710678f));
        out[(size_t)row * N + col] = f2bf(a * gl);
      }
    }
  }
}

// ---------------- flash attention v4 (counted vmcnt + raw barriers)
__global__ __launch_bounds__(256)
void attn_k(const u16* __restrict__ q, const u16* __restrict__ k,
            const u16* __restrict__ vt, u16* __restrict__ o,
            int kvlen, int seqk, int vstride)
{
  __shared__ __align__(16) u16 Ks[2][64 * 64];
  __shared__ __align__(16) u16 Vs[2][64 * 64];
  __shared__ __align__(16) u16 Ps[4][32 * 72];
  const int tid = threadIdx.x, lane = tid & 63, wave = tid >> 6;
  const int g = lane >> 4, r16 = lane & 15;
  const int bh = blockIdx.y;
  const int b = bh >> 4, h = bh & 15;
  const int q0 = blockIdx.x * 128 + wave * 32;
  const float C = 0.18033688f;   // log2(e)/8

  bf16x8 aq[2][2];
#pragma unroll
  for (int qs = 0; qs < 2; ++qs) {
    const size_t qoff = (size_t)(b * SEQ + q0 + qs * 16 + r16) * DIMN + h * DHEAD;
#pragma unroll
    for (int kc = 0; kc < 2; ++kc)
      aq[qs][kc] = *(const bf16x8*)&q[qoff + kc * 32 + g * 8];
  }
  asm volatile("" :: "v"(aq[0][0]), "v"(aq[0][1]), "v"(aq[1][0]), "v"(aq[1][1]));

  f32x4 oacc[2][4] = {};
  float mi[2][4], li[2][4];
#pragma unroll
  for (int qs = 0; qs < 2; ++qs)
#pragma unroll
    for (int rg = 0; rg < 4; ++rg) { mi[qs][rg] = -3e38f; li[qs][rg] = 0.f; }

  const size_t vtbase = (size_t)(b * HEADS + h) * DHEAD * vstride;
  const size_t kbase  = (size_t)b * seqk * DIMN + h * DHEAD;
  const int nkv = (kvlen + 63) >> 6;

  auto stage = [&](int buf, int kv0) {
#pragma unroll
    for (int i = 0; i < 2; ++i) {
      const int c = tid + i * 256;
      const int row = c >> 3, ch = c & 7;
      const int chs = ch ^ (row & 7);
      int kr = kv0 + row; if (kr > kvlen - 1) kr = kvlen - 1;
      gload16(k + kbase + (size_t)kr * DIMN + chs * 8, &Ks[buf][c * 8]);
    }
#pragma unroll
    for (int i = 0; i < 2; ++i) {
      const int c = tid + i * 256;
      const int row = c >> 3, ch = c & 7;
      const int chs = ch ^ (row & 7);
      gload16(vt + vtbase + (size_t)row * vstride + kv0 + chs * 8, &Vs[buf][c * 8]);
    }
  };

  stage(0, 0);

  for (int kvb = 0; kvb < nkv; ++kvb) {
    const int kv0 = kvb * 64;
    const int cur = kvb & 1;
    if (kvb + 1 < nkv) {
      stage(cur ^ 1, kv0 + 64);
      asm volatile("s_waitcnt vmcnt(4)" ::: "memory");
    } else {
      asm volatile("s_waitcnt vmcnt(0)" ::: "memory");
    }
    __builtin_amdgcn_s_barrier();                        // B1

    // ---- QK^T: 16 MFMA
    f32x4 sa[2][4];
#pragma unroll
    for (int qs = 0; qs < 2; ++qs)
#pragma unroll
      for (int st = 0; st < 4; ++st) sa[qs][st] = (f32x4){0.f, 0.f, 0.f, 0.f};
    __builtin_amdgcn_s_setprio(1);
#pragma unroll
    for (int st = 0; st < 4; ++st) {
      const int kvr = st * 16 + r16;
#pragma unroll
      for (int kc = 0; kc < 2; ++kc) {
        const int chs = (kc * 4 + g) ^ (kvr & 7);
        const bf16x8 kf = *(const bf16x8*)&Ks[cur][kvr * 64 + chs * 8];
        sa[0][st] = mfma16(aq[0][kc], kf, sa[0][st]);
        sa[1][st] = mfma16(aq[1][kc], kf, sa[1][st]);
      }
    }
    __builtin_amdgcn_s_setprio(0);

    // ---- tail mask (cross-attn last tile only)
    if (kv0 + 64 > kvlen) {
#pragma unroll
      for (int st = 0; st < 4; ++st)
        if (kv0 + st * 16 + r16 >= kvlen) {
#pragma unroll
          for (int qs = 0; qs < 2; ++qs)
#pragma unroll
            for (int rg = 0; rg < 4; ++rg) sa[qs][st][rg] = -3e38f;
        }
    }

    // ---- defer-max check
    float bad = 0.f;
    float m4v[2][4];
#pragma unroll
    for (int qs = 0; qs < 2; ++qs)
#pragma unroll
      for (int rg = 0; rg < 4; ++rg) {
        float m4 = fmaxf(fmaxf(sa[qs][0][rg], sa[qs][1][rg]),
                         fmaxf(sa[qs][2][rg], sa[qs][3][rg]));
        m4v[qs][rg] = m4;
        bad = fmaxf(bad, m4 - mi[qs][rg]);
      }
    if (__any(bad > 16.0f)) {
#pragma unroll
      for (int qs = 0; qs < 2; ++qs)
#pragma unroll
        for (int rg = 0; rg < 4; ++rg) {
          float mx = m4v[qs][rg];
#pragma unroll
          for (int off = 1; off < 16; off <<= 1) mx = fmaxf(mx, __shfl_xor(mx, off));
          const float nm = fmaxf(mi[qs][rg], mx);
          const float corr = __builtin_amdgcn_exp2f((mi[qs][rg] - nm) * C);
          mi[qs][rg] = nm;
          li[qs][rg] *= corr;
#pragma unroll
          for (int ds = 0; ds < 4; ++ds) oacc[qs][ds][rg] *= corr;
        }
    }

    // ---- P = exp, lane-local li accumulate, packed bf16 store
#pragma unroll
    for (int qs = 0; qs < 2; ++qs) {
#pragma unroll
      for (int rg = 0; rg < 4; ++rg) {
        const float mc = mi[qs][rg] * C;
        const float p0 = __builtin_amdgcn_exp2f(__builtin_fmaf(sa[qs][0][rg], C, -mc));
        const float p1 = __builtin_amdgcn_exp2f(__builtin_fmaf(sa[qs][1][rg], C, -mc));
        const float p2 = __builtin_amdgcn_exp2f(__builtin_fmaf(sa[qs][2][rg], C, -mc));
        const float p3 = __builtin_amdgcn_exp2f(__builtin_fmaf(sa[qs][3][rg], C, -mc));
        li[qs][rg] += (p0 + p1) + (p2 + p3);
        unsigned lo, hi;
        asm("v_cvt_pk_bf16_f32 %0, %1, %2" : "=v"(lo) : "v"(p0), "v"(p1));
        asm("v_cvt_pk_bf16_f32 %0, %1, %2" : "=v"(hi) : "v"(p2), "v"(p3));
        const int prow = qs * 16 + g * 4 + rg;
        uint2 pk; pk.x = lo; pk.y = hi;
        *(uint2*)&Ps[wave][prow * 72 + r16 * 4] = pk;
      }
    }

    // ---- PV: 16 MFMA
    __builtin_amdgcn_s_setprio(1);
#pragma unroll
    for (int kc = 0; kc < 2; ++kc) {
      const bf16x8 pa0 = *(const bf16x8*)&Ps[wave][(r16)      * 72 + kc * 32 + g * 8];
      const bf16x8 pa1 = *(const bf16x8*)&Ps[wave][(16 + r16) * 72 + kc * 32 + g * 8];
#pragma unroll
      for (int ds = 0; ds < 4; ++ds) {
        const int dr = ds * 16 + r16;
        const int chs = (kc * 4 + g) ^ (dr & 7);
        const bf16x8 vf = *(const bf16x8*)&Vs[cur][dr * 64 + chs * 8];
        oacc[0][ds] = mfma16(pa0, vf, oacc[0][ds]);
        oacc[1][ds] = mfma16(pa1, vf, oacc[1][ds]);
      }
    }
    __builtin_amdgcn_s_setprio(0);

    __builtin_amdgcn_s_barrier();                        // B2
  }

#pragma unroll
  for (int qs = 0; qs < 2; ++qs)
#pragma unroll
    for (int rg = 0; rg < 4; ++rg) {
      float s = li[qs][rg];
#pragma unroll
      for (int off = 1; off < 16; off <<= 1) s += __shfl_xor(s, off);
      li[qs][rg] = s;
    }

#pragma unroll
  for (int qs = 0; qs < 2; ++qs)
#pragma unroll
    for (int rg = 0; rg < 4; ++rg) {
      const float inv = 1.0f / li[qs][rg];
      const int row = q0 + qs * 16 + g * 4 + rg;
      const size_t base = (size_t)(b * SEQ + row) * DIMN + h * DHEAD;
#pragma unroll
      for (int ds = 0; ds < 4; ++ds)
        o[base + ds * 16 + r16] = f2bf(oacc[qs][ds][rg] * inv);
    }
}

extern "C" void kernel_launch(void* const* d_in, const int* in_sizes, int n_in,
                              void* d_out, int out_size, void* d_ws, size_t ws_size,
                              hipStream_t stream)
{
  const float* x   = (const float*)d_in[0];
  const float* ctx = (const float*)d_in[1];
  const float* Wq1 = (const float*)d_in[2];
  const float* Wk1 = (const float*)d_in[3];
  const float* Wv1 = (const float*)d_in[4];
  const float* Wo1 = (const float*)d_in[5];
  const float* bo1 = (const float*)d_in[6];
  const float* Wq2 = (const float*)d_in[7];
  const float* Wk2 = (const float*)d_in[8];
  const float* Wv2 = (const float*)d_in[9];
  const float* Wo2 = (const float*)d_in[10];
  const float* bo2 = (const float*)d_in[11];
  const float* Wp  = (const float*)d_in[12];
  const float* bp  = (const float*)d_in[13];
  const float* W2  = (const float*)d_in[14];
  const float* b2  = (const float*)d_in[15];
  const float* g1  = (const float*)d_in[16];
  const float* be1 = (const float*)d_in[17];
  const float* g2  = (const float*)d_in[18];
  const float* be2 = (const float*)d_in[19];
  const float* g3  = (const float*)d_in[20];
  const float* be3 = (const float*)d_in[21];

  char* ws = (char*)d_ws;
  size_t off = 0;
  auto alloc = [&](size_t bytes) -> void* {
    void* p = ws + off;
    off += (bytes + 255) & ~(size_t)255;
    return p;
  };

  u16* WqT1 = (u16*)alloc((size_t)1024 * 1024 * 2);   // contiguous with WkT1, WvT1
  u16* WkT1 = (u16*)alloc((size_t)1024 * 1024 * 2);
  u16* WvT1 = (u16*)alloc((size_t)1024 * 1024 * 2);
  u16* WoT1 = (u16*)alloc((size_t)1024 * 1024 * 2);
  u16* WqT2 = (u16*)alloc((size_t)1024 * 1024 * 2);
  u16* WkT2 = (u16*)alloc((size_t)1024 * 768 * 2);    // contiguous with WvT2
  u16* WvT2 = (u16*)alloc((size_t)1024 * 768 * 2);
  u16* WoT2 = (u16*)alloc((size_t)1024 * 1024 * 2);
  u16* WpT  = (u16*)alloc((size_t)8192 * 1024 * 2);
  u16* W2T  = (u16*)alloc((size_t)1024 * 4096 * 2);
  float* x1f = (float*)alloc((size_t)NTOK * DIMN * 4);
  float* x2f = (float*)alloc((size_t)NTOK * DIMN * 4);
  u16* ctxb = (u16*)alloc((size_t)CTOK * CTXD * 2);
  u16* k2b  = (u16*)alloc((size_t)CTOK * DIMN * 2);
  u16* vt2b = (u16*)alloc((size_t)2 * HEADS * DHEAD * 128 * 2);
  u16* hb   = (u16*)alloc((size_t)NTOK * DIMN * 2);
  u16* qb   = (u16*)alloc((size_t)NTOK * DIMN * 2);
  u16* kb   = (u16*)alloc((size_t)NTOK * DIMN * 2);
  u16* vtb  = (u16*)alloc((size_t)NTOK * DIMN * 2);
  u16* ab   = (u16*)alloc((size_t)NTOK * DIMN * 2);
  u16* ub   = qb; // reuse qb..ab region (32MB) for FF intermediate [4096][4096]

  dim3 blk(256);

  // batched weight conversions
  WBatch wb6;
  wb6.s[0] = Wq1; wb6.d[0] = WqT1;
  wb6.s[1] = Wk1; wb6.d[1] = WkT1;
  wb6.s[2] = Wv1; wb6.d[2] = WvT1;
  wb6.s[3] = Wo1; wb6.d[3] = WoT1;
  wb6.s[4] = Wq2; wb6.d[4] = WqT2;
  wb6.s[5] = Wo2; wb6.d[5] = WoT2;
  wconvB_k<6><<<dim3(16, 16, 6), blk, 0, stream>>>(wb6, 1024, 1024);
  WBatch wb2;
  wb2.s[0] = Wk2; wb2.d[0] = WkT2;
  wb2.s[1] = Wv2; wb2.d[1] = WvT2;
  wb2.s[2] = nullptr; wb2.d[2] = nullptr;
  wb2.s[3] = nullptr; wb2.d[3] = nullptr;
  wb2.s[4] = nullptr; wb2.d[4] = nullptr;
  wb2.s[5] = nullptr; wb2.d[5] = nullptr;
  wconvB_k<2><<<dim3(16, 12, 2), blk, 0, stream>>>(wb2, 768, 1024);
  wconv_k<<<dim3(128, 16), blk, 0, stream>>>(Wp, WpT, 1024, 8192);
  wconv_k<<<dim3(16, 64), blk, 0, stream>>>(W2, W2T, 4096, 1024);
  cconv_k<<<dim3((CTOK * CTXD + 255) / 256), blk, 0, stream>>>(ctx, ctxb, CTOK * CTXD);

  // ---- self attention block (QKV fused: WqT1/WkT1/WvT1 contiguous, N=3072)
  ln_k<<<NTOK, 256, 0, stream>>>(x, g1, be1, hb);
  gemm_k<4><<<dim3(32, 24), blk, 0, stream>>>(hb, WqT1, NTOK, 3072, 1024, nullptr, nullptr, qb, nullptr, SEQ, SEQ, kb, vtb);
  attn_k<<<dim3(16, 32), blk, 0, stream>>>(qb, kb, vtb, ab, SEQ, SEQ, SEQ);
  gemm_k<2><<<dim3(32, 8), blk, 0, stream>>>(ab, WoT1, NTOK, 1024, 1024, bo1, x, nullptr, x1f, 0, 0, nullptr, nullptr);

  // ---- cross attention block (K2+V2 fused over ctx, N=2048)
  ln_k<<<NTOK, 256, 0, stream>>>(x1f, g2, be2, hb);
  gemm_k<0><<<dim3(32, 8), blk, 0, stream>>>(hb, WqT2, NTOK, 1024, 1024, nullptr, nullptr, qb, nullptr, 0, 0, nullptr, nullptr);
  gemm_k<5><<<dim3(2, 16), blk, 0, stream>>>(ctxb, WkT2, CTOK, 2048, 768, nullptr, nullptr, k2b, nullptr, NCTX, 128, nullptr, vt2b);
  attn_k<<<dim3(16, 32), blk, 0, stream>>>(qb, k2b, vt2b, ab, NCTX, NCTX, 128);
  gemm_k<2><<<dim3(32, 8), blk, 0, stream>>>(ab, WoT2, NTOK, 1024, 1024, bo2, x1f, nullptr, x2f, 0, 0, nullptr, nullptr);

  // ---- GEGLU FF block
  ln_k<<<NTOK, 256, 0, stream>>>(x2f, g3, be3, hb);
  geglu_k<<<dim3(32, 32), blk, 0, stream>>>(hb, WpT, WpT + (size_t)4096 * 1024, bp, bp + 4096, ub, NTOK, FFH);
  gemm_k<2><<<dim3(32, 8), blk, 0, stream>>>(ub, W2T, NTOK, 1024, 4096, b2, x2f, nullptr, (float*)d_out, 0, 0, nullptr, nullptr);

  (void)in_sizes; (void)n_in; (void)out_size; (void)ws_size;
}

// Round 8
// 435.471 us; speedup vs baseline: 1.0757x; 1.0757x over previous
//
#include <hip/hip_runtime.h>
#include <hip/hip_bf16.h>
#include <math.h>

#define DIMN   1024
#define HEADS  16
#define DHEAD  64
#define CTXD   768
#define FFH    4096
#define NTOK   4096
#define SEQ    2048
#define NCTX   77
#define CTOK   154

typedef unsigned short u16;
typedef __bf16 bf16x8 __attribute__((ext_vector_type(8)));
typedef float  f32x4  __attribute__((ext_vector_type(4)));

__device__ __forceinline__ u16 f2bf(float f) {
  union { float f; unsigned u; } c; c.f = f;
  unsigned r = c.u + 0x7FFFu + ((c.u >> 16) & 1u);
  return (u16)(r >> 16);
}
__device__ __forceinline__ float bf2f(u16 h) {
  union { unsigned u; float f; } c; c.u = ((unsigned)h) << 16; return c.f;
}

__device__ __forceinline__ void gload16(const void* g, void* l) {
  __builtin_amdgcn_global_load_lds(
      (__attribute__((address_space(1))) void*)(void*)(g),
      (__attribute__((address_space(3))) void*)(l), 16, 0, 0);
}

__device__ __forceinline__ f32x4 mfma16(bf16x8 a, bf16x8 b, f32x4 c) {
  return __builtin_amdgcn_mfma_f32_16x16x32_bf16(a, b, c, 0, 0, 0);
}

// ---------------- batched weight convert+transpose: W[K][N] f32 -> WT[N][K] bf16
struct WBatch { const float* s[6]; u16* d[6]; };

template<int NB>
__global__ __launch_bounds__(256)
void wconvB_k(WBatch wb, int K, int N)
{
  __shared__ u16 t[64][65];
  const float* __restrict__ W  = wb.s[blockIdx.z];
  u16* __restrict__       WT   = wb.d[blockIdx.z];
  int n0 = blockIdx.x * 64, k0 = blockIdx.y * 64;
  int tid = threadIdx.x;
  int rr = tid >> 4, cc = tid & 15;
#pragma unroll
  for (int i = 0; i < 4; ++i) {
    int kr = rr + i * 16;
    const float4 v = *(const float4*)&W[(size_t)(k0 + kr) * N + n0 + cc * 4];
    t[kr][cc*4+0] = f2bf(v.x); t[kr][cc*4+1] = f2bf(v.y);
    t[kr][cc*4+2] = f2bf(v.z); t[kr][cc*4+3] = f2bf(v.w);
  }
  __syncthreads();
#pragma unroll
  for (int i = 0; i < 4; ++i) {
    int nr = rr + i * 16;
    int r0 = cc * 4;
    ushort4 o;
    o.x = t[r0+0][nr]; o.y = t[r0+1][nr]; o.z = t[r0+2][nr]; o.w = t[r0+3][nr];
    *(ushort4*)&WT[(size_t)(n0 + nr) * K + k0 + r0] = o;
  }
}

__global__ __launch_bounds__(256)
void wconv_k(const float* __restrict__ W, u16* __restrict__ WT, int K, int N)
{
  __shared__ u16 t[64][65];
  int n0 = blockIdx.x * 64, k0 = blockIdx.y * 64;
  int tid = threadIdx.x;
  int rr = tid >> 4, cc = tid & 15;
#pragma unroll
  for (int i = 0; i < 4; ++i) {
    int kr = rr + i * 16;
    const float4 v = *(const float4*)&W[(size_t)(k0 + kr) * N + n0 + cc * 4];
    t[kr][cc*4+0] = f2bf(v.x); t[kr][cc*4+1] = f2bf(v.y);
    t[kr][cc*4+2] = f2bf(v.z); t[kr][cc*4+3] = f2bf(v.w);
  }
  __syncthreads();
#pragma unroll
  for (int i = 0; i < 4; ++i) {
    int nr = rr + i * 16;
    int r0 = cc * 4;
    ushort4 o;
    o.x = t[r0+0][nr]; o.y = t[r0+1][nr]; o.z = t[r0+2][nr]; o.w = t[r0+3][nr];
    *(ushort4*)&WT[(size_t)(n0 + nr) * K + k0 + r0] = o;
  }
}

// ---------------- f32 -> bf16 elementwise (context)
__global__ void cconv_k(const float* __restrict__ c, u16* __restrict__ o, int n)
{
  int i = blockIdx.x * 256 + threadIdx.x;
  if (i < n) o[i] = f2bf(c[i]);
}

// ---------------- LayerNorm: f32 row[1024] -> bf16
__global__ __launch_bounds__(256)
void ln_k(const float* __restrict__ x, const float* __restrict__ gm,
          const float* __restrict__ bt, u16* __restrict__ o)
{
  int row = blockIdx.x;
  int tid = threadIdx.x;
  const float4 v = *(const float4*)&x[(size_t)row * DIMN + tid * 4];
  float s = v.x + v.y + v.z + v.w;
  float q = v.x*v.x + v.y*v.y + v.z*v.z + v.w*v.w;
#pragma unroll
  for (int off = 32; off; off >>= 1) { s += __shfl_xor(s, off); q += __shfl_xor(q, off); }
  __shared__ float ss[4], qq[4];
  int wave = tid >> 6;
  if ((tid & 63) == 0) { ss[wave] = s; qq[wave] = q; }
  __syncthreads();
  s = ss[0] + ss[1] + ss[2] + ss[3];
  q = qq[0] + qq[1] + qq[2] + qq[3];
  float mu = s * (1.0f / DIMN);
  float var = q * (1.0f / DIMN) - mu * mu;
  float rs = rsqrtf(var + 1e-5f);
  const float4 gv = *(const float4*)&gm[tid * 4];
  const float4 bv = *(const float4*)&bt[tid * 4];
  ushort4 r;
  r.x = f2bf((v.x - mu) * rs * gv.x + bv.x);
  r.y = f2bf((v.y - mu) * rs * gv.y + bv.y);
  r.z = f2bf((v.z - mu) * rs * gv.z + bv.z);
  r.w = f2bf((v.w - mu) * rs * gv.w + bv.w);
  *(ushort4*)&o[(size_t)row * DIMN + tid * 4] = r;
}

// ---------------- GEMM (R5-proven): 512 threads, 8 waves (32x64 wave tile), 2-buf counted vmcnt
// A[M][K] bf16 row-major, Bt[N][K] bf16
// MODE 0: out bf16 = acc + bias
// MODE 2: out f32 = acc + bias + resid
// MODE 3: vt store (kv-permuted within 64-granule to match attn P layout)
// MODE 4: QKV fused: colgrp 0->obf (q), 1->ob2 (k), 2->ob3 (vt store)
// MODE 5: KV fused:  colgrp 0->obf (k), 1->ob3 (vt store)
template<int MODE>
__global__ __launch_bounds__(512, 4)
void gemm_k(const u16* __restrict__ A, const u16* __restrict__ Bt,
            int M, int N, int K,
            const float* __restrict__ bias, const float* __restrict__ resid,
            u16* __restrict__ obf, float* __restrict__ of32,
            int seq, int vstride,
            u16* __restrict__ ob2, u16* __restrict__ ob3)
{
  __shared__ __align__(16) u16 As[2][128 * 32];
  __shared__ __align__(16) u16 Bs[2][128 * 32];
  const int tid = threadIdx.x;
  const int lane = tid & 63, wave = tid >> 6;
  const int wr = wave >> 1, wc = wave & 1;          // 4 x 2 wave grid
  const int g = lane >> 4, r16 = lane & 15;
  const int m0 = blockIdx.x * 128, n0 = blockIdx.y * 128;

  f32x4 acc[2][4] = {};

  const int srow = tid >> 2;          // 0..127
  const int sch  = tid & 3;           // 0..3
  const int schs = sch ^ ((srow >> 1) & 3);
  const int arow = (m0 + srow > M - 1) ? (M - 1) : (m0 + srow);
  const size_t abase = (size_t)arow * K + schs * 8;
  const size_t bbase = (size_t)(n0 + srow) * K + schs * 8;

  auto stage = [&](int buf, int kt) {
    gload16(A  + abase + kt, &As[buf][tid * 8]);
    gload16(Bt + bbase + kt, &Bs[buf][tid * 8]);
  };

  stage(0, 0);

  const int nkt = K >> 5;
  for (int t = 0; t < nkt; ++t) {
    const int cur = t & 1;
    if (t + 1 < nkt) {
      stage(cur ^ 1, (t + 1) << 5);
      asm volatile("s_waitcnt vmcnt(2)" ::: "memory");   // stage(t) landed; t+1 in flight
    } else {
      asm volatile("s_waitcnt vmcnt(0)" ::: "memory");
    }
    __builtin_amdgcn_s_barrier();                        // B1

    bf16x8 af[2], bfr[4];
#pragma unroll
    for (int mi = 0; mi < 2; ++mi) {
      int r = wr * 32 + mi * 16 + r16;
      int cph = g ^ ((r >> 1) & 3);
      af[mi] = *(const bf16x8*)&As[cur][(r * 4 + cph) * 8];
    }
#pragma unroll
    for (int ni = 0; ni < 4; ++ni) {
      int r = wc * 64 + ni * 16 + r16;
      int cph = g ^ ((r >> 1) & 3);
      bfr[ni] = *(const bf16x8*)&Bs[cur][(r * 4 + cph) * 8];
    }
    __builtin_amdgcn_s_setprio(1);
#pragma unroll
    for (int mi = 0; mi < 2; ++mi)
#pragma unroll
      for (int ni = 0; ni < 4; ++ni)
        acc[mi][ni] = mfma16(af[mi], bfr[ni], acc[mi][ni]);
    __builtin_amdgcn_s_setprio(0);

    __builtin_amdgcn_s_barrier();                        // B2 (WAR)
  }

  const int grp = n0 >> 10;           // column group for fused modes
#pragma unroll
  for (int ni = 0; ni < 4; ++ni) {
    int col = n0 + wc * 64 + ni * 16 + r16;
    float bv = 0.0f;
    if constexpr (MODE == 0 || MODE == 2) bv = bias ? bias[col] : 0.0f;
    const int c1 = col & 1023;
#pragma unroll
    for (int mi = 0; mi < 2; ++mi) {
      f32x4 c = acc[mi][ni];
#pragma unroll
      for (int rg = 0; rg < 4; ++rg) {
        int row = m0 + wr * 32 + mi * 16 + g * 4 + rg;
        if (row < M) {
          float v = c[rg] + bv;
          if constexpr (MODE == 0) {
            obf[(size_t)row * N + col] = f2bf(v);
          } else if constexpr (MODE == 2) {
            size_t o = (size_t)row * N + col;
            of32[o] = v + resid[o];
          } else if constexpr (MODE == 3) {
            int b = row / seq, srow_ = row - b * seq;
            int jg = srow_ >> 6, j = srow_ & 63;
            int pos = jg * 64 + ((j & 15) << 2) + (j >> 4);
            obf[((size_t)b * HEADS * DHEAD + c1) * vstride + pos] = f2bf(v);
          } else if constexpr (MODE == 4) {
            if (grp == 0) {
              obf[(size_t)row * 1024 + c1] = f2bf(v);
            } else if (grp == 1) {
              ob2[(size_t)row * 1024 + c1] = f2bf(v);
            } else {
              int b = row / seq, srow_ = row - b * seq;
              int jg = srow_ >> 6, j = srow_ & 63;
              int pos = jg * 64 + ((j & 15) << 2) + (j >> 4);
              ob3[((size_t)b * HEADS * DHEAD + c1) * vstride + pos] = f2bf(v);
            }
          } else {  // MODE 5
            if (grp == 0) {
              obf[(size_t)row * 1024 + c1] = f2bf(v);
            } else {
              int b = row / seq, srow_ = row - b * seq;
              int jg = srow_ >> 6, j = srow_ & 63;
              int pos = jg * 64 + ((j & 15) << 2) + (j >> 4);
              ob3[((size_t)b * HEADS * DHEAD + c1) * vstride + pos] = f2bf(v);
            }
          }
        }
      }
    }
  }
}

// ---------------- fused GEGLU GEMM v3: 256x128 block, 8 waves (64x64 dual tile),
// 4-buffer 3-deep prefetch, counted vmcnt.  out = (A@B1 + ba) * gelu(A@B2 + bg)
__global__ __launch_bounds__(512, 2)
void geglu256_k(const u16* __restrict__ A, const u16* __restrict__ B1t,
                const u16* __restrict__ B2t,
                const float* __restrict__ ba, const float* __restrict__ bg,
                u16* __restrict__ out, int M, int N)
{
  __shared__ __align__(16) u16 As[4][256 * 32];    // 64 KB
  __shared__ __align__(16) u16 B1s[4][128 * 32];   // 32 KB
  __shared__ __align__(16) u16 B2s[4][128 * 32];   // 32 KB
  const int tid = threadIdx.x;
  const int lane = tid & 63, wave = tid >> 6;
  const int wm = wave >> 1, wn = wave & 1;          // 4(M) x 2(N) waves, 64x64 each
  const int g = lane >> 4, r16 = lane & 15;
  const int m0 = blockIdx.x * 256, n0 = blockIdx.y * 128;
  const int K = 1024;

  f32x4 acca[4][4] = {}, accg[4][4] = {};

  // A staging: 1024 chunks of 16B; thread handles c = tid, tid+512
  int aro[2], acs[2];
#pragma unroll
  for (int i = 0; i < 2; ++i) {
    const int c = tid + i * 512;
    const int r = c >> 2, ch = c & 3;
    acs[i] = ch ^ ((r >> 1) & 3);
    aro[i] = m0 + r;
  }
  // B staging: 512 chunks; thread handles c = tid
  const int brr = tid >> 2;
  const int bcs = (tid & 3) ^ ((brr >> 1) & 3);
  const size_t b1base = (size_t)(n0 + brr) * K + bcs * 8;

  auto stage = [&](int buf, int kt) {
#pragma unroll
    for (int i = 0; i < 2; ++i)
      gload16(A + (size_t)aro[i] * K + kt + acs[i] * 8, &As[buf][(tid + i * 512) * 8]);
    gload16(B1t + b1base + kt, &B1s[buf][tid * 8]);
    gload16(B2t + b1base + kt, &B2s[buf][tid * 8]);
  };

  const int nkt = K >> 5;   // 32
  stage(0, 0);
  stage(1, 32);
  stage(2, 64);

  for (int t = 0; t < nkt; ++t) {
    if (t + 3 < nkt) {
      stage((t + 3) & 3, (t + 3) << 5);
      asm volatile("s_waitcnt vmcnt(12)" ::: "memory");  // t landed; t+1..t+3 in flight
    } else {
      const int ah = nkt - 1 - t;                        // stages still in flight
      if (ah == 2)      asm volatile("s_waitcnt vmcnt(8)" ::: "memory");
      else if (ah == 1) asm volatile("s_waitcnt vmcnt(4)" ::: "memory");
      else              asm volatile("s_waitcnt vmcnt(0)" ::: "memory");
    }
    __builtin_amdgcn_s_barrier();                        // B1

    const int cb = t & 3;
    bf16x8 af[4], b1f[4], b2f[4];
#pragma unroll
    for (int mi = 0; mi < 4; ++mi) {
      int r = wm * 64 + mi * 16 + r16;
      int cph = g ^ ((r >> 1) & 3);
      af[mi] = *(const bf16x8*)&As[cb][(r * 4 + cph) * 8];
    }
#pragma unroll
    for (int ni = 0; ni < 4; ++ni) {
      int r = wn * 64 + ni * 16 + r16;
      int cph = g ^ ((r >> 1) & 3);
      b1f[ni] = *(const bf16x8*)&B1s[cb][(r * 4 + cph) * 8];
      b2f[ni] = *(const bf16x8*)&B2s[cb][(r * 4 + cph) * 8];
    }
    __builtin_amdgcn_s_setprio(1);
#pragma unroll
    for (int mi = 0; mi < 4; ++mi)
#pragma unroll
      for (int ni = 0; ni < 4; ++ni) {
        acca[mi][ni] = mfma16(af[mi], b1f[ni], acca[mi][ni]);
        accg[mi][ni] = mfma16(af[mi], b2f[ni], accg[mi][ni]);
      }
    __builtin_amdgcn_s_setprio(0);

    __builtin_amdgcn_s_barrier();                        // B2 (WAR)
  }

#pragma unroll
  for (int ni = 0; ni < 4; ++ni) {
    int col = n0 + wn * 64 + ni * 16 + r16;
    float bva = ba[col], bvg = bg[col];
#pragma unroll
    for (int mi = 0; mi < 4; ++mi) {
#pragma unroll
      for (int rg = 0; rg < 4; ++rg) {
        int row = m0 + wm * 64 + mi * 16 + g * 4 + rg;
        float a  = acca[mi][ni][rg] + bva;
        float gt = accg[mi][ni][rg] + bvg;
        float gl = 0.5f * gt * (1.0f + erff(gt * 0.70710678f));
        out[(size_t)row * N + col] = f2bf(a * gl);
      }
    }
  }
}

// ---------------- flash attention v4 (counted vmcnt + raw barriers)
__global__ __launch_bounds__(256)
void attn_k(const u16* __restrict__ q, const u16* __restrict__ k,
            const u16* __restrict__ vt, u16* __restrict__ o,
            int kvlen, int seqk, int vstride)
{
  __shared__ __align__(16) u16 Ks[2][64 * 64];
  __shared__ __align__(16) u16 Vs[2][64 * 64];
  __shared__ __align__(16) u16 Ps[4][32 * 72];
  const int tid = threadIdx.x, lane = tid & 63, wave = tid >> 6;
  const int g = lane >> 4, r16 = lane & 15;
  const int bh = blockIdx.y;
  const int b = bh >> 4, h = bh & 15;
  const int q0 = blockIdx.x * 128 + wave * 32;
  const float C = 0.18033688f;   // log2(e)/8

  bf16x8 aq[2][2];
#pragma unroll
  for (int qs = 0; qs < 2; ++qs) {
    const size_t qoff = (size_t)(b * SEQ + q0 + qs * 16 + r16) * DIMN + h * DHEAD;
#pragma unroll
    for (int kc = 0; kc < 2; ++kc)
      aq[qs][kc] = *(const bf16x8*)&q[qoff + kc * 32 + g * 8];
  }
  asm volatile("" :: "v"(aq[0][0]), "v"(aq[0][1]), "v"(aq[1][0]), "v"(aq[1][1]));

  f32x4 oacc[2][4] = {};
  float mi[2][4], li[2][4];
#pragma unroll
  for (int qs = 0; qs < 2; ++qs)
#pragma unroll
    for (int rg = 0; rg < 4; ++rg) { mi[qs][rg] = -3e38f; li[qs][rg] = 0.f; }

  const size_t vtbase = (size_t)(b * HEADS + h) * DHEAD * vstride;
  const size_t kbase  = (size_t)b * seqk * DIMN + h * DHEAD;
  const int nkv = (kvlen + 63) >> 6;

  auto stage = [&](int buf, int kv0) {
#pragma unroll
    for (int i = 0; i < 2; ++i) {
      const int c = tid + i * 256;
      const int row = c >> 3, ch = c & 7;
      const int chs = ch ^ (row & 7);
      int kr = kv0 + row; if (kr > kvlen - 1) kr = kvlen - 1;
      gload16(k + kbase + (size_t)kr * DIMN + chs * 8, &Ks[buf][c * 8]);
    }
#pragma unroll
    for (int i = 0; i < 2; ++i) {
      const int c = tid + i * 256;
      const int row = c >> 3, ch = c & 7;
      const int chs = ch ^ (row & 7);
      gload16(vt + vtbase + (size_t)row * vstride + kv0 + chs * 8, &Vs[buf][c * 8]);
    }
  };

  stage(0, 0);

  for (int kvb = 0; kvb < nkv; ++kvb) {
    const int kv0 = kvb * 64;
    const int cur = kvb & 1;
    if (kvb + 1 < nkv) {
      stage(cur ^ 1, kv0 + 64);
      asm volatile("s_waitcnt vmcnt(4)" ::: "memory");
    } else {
      asm volatile("s_waitcnt vmcnt(0)" ::: "memory");
    }
    __builtin_amdgcn_s_barrier();                        // B1

    // ---- QK^T: 16 MFMA
    f32x4 sa[2][4];
#pragma unroll
    for (int qs = 0; qs < 2; ++qs)
#pragma unroll
      for (int st = 0; st < 4; ++st) sa[qs][st] = (f32x4){0.f, 0.f, 0.f, 0.f};
    __builtin_amdgcn_s_setprio(1);
#pragma unroll
    for (int st = 0; st < 4; ++st) {
      const int kvr = st * 16 + r16;
#pragma unroll
      for (int kc = 0; kc < 2; ++kc) {
        const int chs = (kc * 4 + g) ^ (kvr & 7);
        const bf16x8 kf = *(const bf16x8*)&Ks[cur][kvr * 64 + chs * 8];
        sa[0][st] = mfma16(aq[0][kc], kf, sa[0][st]);
        sa[1][st] = mfma16(aq[1][kc], kf, sa[1][st]);
      }
    }
    __builtin_amdgcn_s_setprio(0);

    // ---- tail mask (cross-attn last tile only)
    if (kv0 + 64 > kvlen) {
#pragma unroll
      for (int st = 0; st < 4; ++st)
        if (kv0 + st * 16 + r16 >= kvlen) {
#pragma unroll
          for (int qs = 0; qs < 2; ++qs)
#pragma unroll
            for (int rg = 0; rg < 4; ++rg) sa[qs][st][rg] = -3e38f;
        }
    }

    // ---- defer-max check
    float bad = 0.f;
    float m4v[2][4];
#pragma unroll
    for (int qs = 0; qs < 2; ++qs)
#pragma unroll
      for (int rg = 0; rg < 4; ++rg) {
        float m4 = fmaxf(fmaxf(sa[qs][0][rg], sa[qs][1][rg]),
                         fmaxf(sa[qs][2][rg], sa[qs][3][rg]));
        m4v[qs][rg] = m4;
        bad = fmaxf(bad, m4 - mi[qs][rg]);
      }
    if (__any(bad > 16.0f)) {
#pragma unroll
      for (int qs = 0; qs < 2; ++qs)
#pragma unroll
        for (int rg = 0; rg < 4; ++rg) {
          float mx = m4v[qs][rg];
#pragma unroll
          for (int off = 1; off < 16; off <<= 1) mx = fmaxf(mx, __shfl_xor(mx, off));
          const float nm = fmaxf(mi[qs][rg], mx);
          const float corr = __builtin_amdgcn_exp2f((mi[qs][rg] - nm) * C);
          mi[qs][rg] = nm;
          li[qs][rg] *= corr;
#pragma unroll
          for (int ds = 0; ds < 4; ++ds) oacc[qs][ds][rg] *= corr;
        }
    }

    // ---- P = exp, lane-local li accumulate, packed bf16 store
#pragma unroll
    for (int qs = 0; qs < 2; ++qs) {
#pragma unroll
      for (int rg = 0; rg < 4; ++rg) {
        const float mc = mi[qs][rg] * C;
        const float p0 = __builtin_amdgcn_exp2f(__builtin_fmaf(sa[qs][0][rg], C, -mc));
        const float p1 = __builtin_amdgcn_exp2f(__builtin_fmaf(sa[qs][1][rg], C, -mc));
        const float p2 = __builtin_amdgcn_exp2f(__builtin_fmaf(sa[qs][2][rg], C, -mc));
        const float p3 = __builtin_amdgcn_exp2f(__builtin_fmaf(sa[qs][3][rg], C, -mc));
        li[qs][rg] += (p0 + p1) + (p2 + p3);
        unsigned lo, hi;
        asm("v_cvt_pk_bf16_f32 %0, %1, %2" : "=v"(lo) : "v"(p0), "v"(p1));
        asm("v_cvt_pk_bf16_f32 %0, %1, %2" : "=v"(hi) : "v"(p2), "v"(p3));
        const int prow = qs * 16 + g * 4 + rg;
        uint2 pk; pk.x = lo; pk.y = hi;
        *(uint2*)&Ps[wave][prow * 72 + r16 * 4] = pk;
      }
    }

    // ---- PV: 16 MFMA
    __builtin_amdgcn_s_setprio(1);
#pragma unroll
    for (int kc = 0; kc < 2; ++kc) {
      const bf16x8 pa0 = *(const bf16x8*)&Ps[wave][(r16)      * 72 + kc * 32 + g * 8];
      const bf16x8 pa1 = *(const bf16x8*)&Ps[wave][(16 + r16) * 72 + kc * 32 + g * 8];
#pragma unroll
      for (int ds = 0; ds < 4; ++ds) {
        const int dr = ds * 16 + r16;
        const int chs = (kc * 4 + g) ^ (dr & 7);
        const bf16x8 vf = *(const bf16x8*)&Vs[cur][dr * 64 + chs * 8];
        oacc[0][ds] = mfma16(pa0, vf, oacc[0][ds]);
        oacc[1][ds] = mfma16(pa1, vf, oacc[1][ds]);
      }
    }
    __builtin_amdgcn_s_setprio(0);

    __builtin_amdgcn_s_barrier();                        // B2
  }

#pragma unroll
  for (int qs = 0; qs < 2; ++qs)
#pragma unroll
    for (int rg = 0; rg < 4; ++rg) {
      float s = li[qs][rg];
#pragma unroll
      for (int off = 1; off < 16; off <<= 1) s += __shfl_xor(s, off);
      li[qs][rg] = s;
    }

#pragma unroll
  for (int qs = 0; qs < 2; ++qs)
#pragma unroll
    for (int rg = 0; rg < 4; ++rg) {
      const float inv = 1.0f / li[qs][rg];
      const int row = q0 + qs * 16 + g * 4 + rg;
      const size_t base = (size_t)(b * SEQ + row) * DIMN + h * DHEAD;
#pragma unroll
      for (int ds = 0; ds < 4; ++ds)
        o[base + ds * 16 + r16] = f2bf(oacc[qs][ds][rg] * inv);
    }
}

extern "C" void kernel_launch(void* const* d_in, const int* in_sizes, int n_in,
                              void* d_out, int out_size, void* d_ws, size_t ws_size,
                              hipStream_t stream)
{
  const float* x   = (const float*)d_in[0];
  const float* ctx = (const float*)d_in[1];
  const float* Wq1 = (const float*)d_in[2];
  const float* Wk1 = (const float*)d_in[3];
  const float* Wv1 = (const float*)d_in[4];
  const float* Wo1 = (const float*)d_in[5];
  const float* bo1 = (const float*)d_in[6];
  const float* Wq2 = (const float*)d_in[7];
  const float* Wk2 = (const float*)d_in[8];
  const float* Wv2 = (const float*)d_in[9];
  const float* Wo2 = (const float*)d_in[10];
  const float* bo2 = (const float*)d_in[11];
  const float* Wp  = (const float*)d_in[12];
  const float* bp  = (const float*)d_in[13];
  const float* W2  = (const float*)d_in[14];
  const float* b2  = (const float*)d_in[15];
  const float* g1  = (const float*)d_in[16];
  const float* be1 = (const float*)d_in[17];
  const float* g2  = (const float*)d_in[18];
  const float* be2 = (const float*)d_in[19];
  const float* g3  = (const float*)d_in[20];
  const float* be3 = (const float*)d_in[21];

  char* ws = (char*)d_ws;
  size_t off = 0;
  auto alloc = [&](size_t bytes) -> void* {
    void* p = ws + off;
    off += (bytes + 255) & ~(size_t)255;
    return p;
  };

  u16* WqT1 = (u16*)alloc((size_t)1024 * 1024 * 2);   // contiguous with WkT1, WvT1
  u16* WkT1 = (u16*)alloc((size_t)1024 * 1024 * 2);
  u16* WvT1 = (u16*)alloc((size_t)1024 * 1024 * 2);
  u16* WoT1 = (u16*)alloc((size_t)1024 * 1024 * 2);
  u16* WqT2 = (u16*)alloc((size_t)1024 * 1024 * 2);
  u16* WkT2 = (u16*)alloc((size_t)1024 * 768 * 2);    // contiguous with WvT2
  u16* WvT2 = (u16*)alloc((size_t)1024 * 768 * 2);
  u16* WoT2 = (u16*)alloc((size_t)1024 * 1024 * 2);
  u16* WpT  = (u16*)alloc((size_t)8192 * 1024 * 2);
  u16* W2T  = (u16*)alloc((size_t)1024 * 4096 * 2);
  float* x1f = (float*)alloc((size_t)NTOK * DIMN * 4);
  float* x2f = (float*)alloc((size_t)NTOK * DIMN * 4);
  u16* ctxb = (u16*)alloc((size_t)CTOK * CTXD * 2);
  u16* k2b  = (u16*)alloc((size_t)CTOK * DIMN * 2);
  u16* vt2b = (u16*)alloc((size_t)2 * HEADS * DHEAD * 128 * 2);
  u16* hb   = (u16*)alloc((size_t)NTOK * DIMN * 2);
  u16* qb   = (u16*)alloc((size_t)NTOK * DIMN * 2);
  u16* kb   = (u16*)alloc((size_t)NTOK * DIMN * 2);
  u16* vtb  = (u16*)alloc((size_t)NTOK * DIMN * 2);
  u16* ab   = (u16*)alloc((size_t)NTOK * DIMN * 2);
  u16* ub   = qb; // reuse qb..ab region (32MB) for FF intermediate [4096][4096]

  dim3 blk(256);
  dim3 blk5(512);

  // batched weight conversions
  WBatch wb6;
  wb6.s[0] = Wq1; wb6.d[0] = WqT1;
  wb6.s[1] = Wk1; wb6.d[1] = WkT1;
  wb6.s[2] = Wv1; wb6.d[2] = WvT1;
  wb6.s[3] = Wo1; wb6.d[3] = WoT1;
  wb6.s[4] = Wq2; wb6.d[4] = WqT2;
  wb6.s[5] = Wo2; wb6.d[5] = WoT2;
  wconvB_k<6><<<dim3(16, 16, 6), blk, 0, stream>>>(wb6, 1024, 1024);
  WBatch wb2;
  wb2.s[0] = Wk2; wb2.d[0] = WkT2;
  wb2.s[1] = Wv2; wb2.d[1] = WvT2;
  wb2.s[2] = nullptr; wb2.d[2] = nullptr;
  wb2.s[3] = nullptr; wb2.d[3] = nullptr;
  wb2.s[4] = nullptr; wb2.d[4] = nullptr;
  wb2.s[5] = nullptr; wb2.d[5] = nullptr;
  wconvB_k<2><<<dim3(16, 12, 2), blk, 0, stream>>>(wb2, 768, 1024);
  wconv_k<<<dim3(128, 16), blk, 0, stream>>>(Wp, WpT, 1024, 8192);
  wconv_k<<<dim3(16, 64), blk, 0, stream>>>(W2, W2T, 4096, 1024);
  cconv_k<<<dim3((CTOK * CTXD + 255) / 256), blk, 0, stream>>>(ctx, ctxb, CTOK * CTXD);

  // ---- self attention block (QKV fused: WqT1/WkT1/WvT1 contiguous, N=3072)
  ln_k<<<NTOK, 256, 0, stream>>>(x, g1, be1, hb);
  gemm_k<4><<<dim3(32, 24), blk5, 0, stream>>>(hb, WqT1, NTOK, 3072, 1024, nullptr, nullptr, qb, nullptr, SEQ, SEQ, kb, vtb);
  attn_k<<<dim3(16, 32), blk, 0, stream>>>(qb, kb, vtb, ab, SEQ, SEQ, SEQ);
  gemm_k<2><<<dim3(32, 8), blk5, 0, stream>>>(ab, WoT1, NTOK, 1024, 1024, bo1, x, nullptr, x1f, 0, 0, nullptr, nullptr);

  // ---- cross attention block (K2+V2 fused over ctx, N=2048)
  ln_k<<<NTOK, 256, 0, stream>>>(x1f, g2, be2, hb);
  gemm_k<0><<<dim3(32, 8), blk5, 0, stream>>>(hb, WqT2, NTOK, 1024, 1024, nullptr, nullptr, qb, nullptr, 0, 0, nullptr, nullptr);
  gemm_k<5><<<dim3(2, 16), blk5, 0, stream>>>(ctxb, WkT2, CTOK, 2048, 768, nullptr, nullptr, k2b, nullptr, NCTX, 128, nullptr, vt2b);
  attn_k<<<dim3(16, 32), blk, 0, stream>>>(qb, k2b, vt2b, ab, NCTX, NCTX, 128);
  gemm_k<2><<<dim3(32, 8), blk5, 0, stream>>>(ab, WoT2, NTOK, 1024, 1024, bo2, x1f, nullptr, x2f, 0, 0, nullptr, nullptr);

  // ---- GEGLU FF block
  ln_k<<<NTOK, 256, 0, stream>>>(x2f, g3, be3, hb);
  geglu256_k<<<dim3(16, 32), blk5, 0, stream>>>(hb, WpT, WpT + (size_t)4096 * 1024, bp, bp + 4096, ub, NTOK, FFH);
  gemm_k<2><<<dim3(32, 8), blk5, 0, stream>>>(ub, W2T, NTOK, 1024, 4096, b2, x2f, nullptr, (float*)d_out, 0, 0, nullptr, nullptr);

  (void)in_sizes; (void)n_in; (void)out_size; (void)ws_size;
}

// Round 9
// 434.626 us; speedup vs baseline: 1.0778x; 1.0019x over previous
//
#include <hip/hip_runtime.h>
#include <hip/hip_bf16.h>
#include <math.h>

#define DIMN   1024
#define HEADS  16
#define DHEAD  64
#define CTXD   768
#define FFH    4096
#define NTOK   4096
#define SEQ    2048
#define NCTX   77
#define CTOK   154

typedef unsigned short u16;
typedef __bf16 bf16x8 __attribute__((ext_vector_type(8)));
typedef float  f32x4  __attribute__((ext_vector_type(4)));

__device__ __forceinline__ u16 f2bf(float f) {
  union { float f; unsigned u; } c; c.f = f;
  unsigned r = c.u + 0x7FFFu + ((c.u >> 16) & 1u);
  return (u16)(r >> 16);
}
__device__ __forceinline__ float bf2f(u16 h) {
  union { unsigned u; float f; } c; c.u = ((unsigned)h) << 16; return c.f;
}

__device__ __forceinline__ void gload16(const void* g, void* l) {
  __builtin_amdgcn_global_load_lds(
      (__attribute__((address_space(1))) void*)(void*)(g),
      (__attribute__((address_space(3))) void*)(l), 16, 0, 0);
}

__device__ __forceinline__ f32x4 mfma16(bf16x8 a, bf16x8 b, f32x4 c) {
  return __builtin_amdgcn_mfma_f32_16x16x32_bf16(a, b, c, 0, 0, 0);
}

// ---------------- batched weight convert+transpose: W[K][N] f32 -> WT[N][K] bf16
struct WBatch { const float* s[6]; u16* d[6]; };

template<int NB>
__global__ __launch_bounds__(256)
void wconvB_k(WBatch wb, int K, int N)
{
  __shared__ u16 t[64][65];
  const float* __restrict__ W  = wb.s[blockIdx.z];
  u16* __restrict__       WT   = wb.d[blockIdx.z];
  int n0 = blockIdx.x * 64, k0 = blockIdx.y * 64;
  int tid = threadIdx.x;
  int rr = tid >> 4, cc = tid & 15;
#pragma unroll
  for (int i = 0; i < 4; ++i) {
    int kr = rr + i * 16;
    const float4 v = *(const float4*)&W[(size_t)(k0 + kr) * N + n0 + cc * 4];
    t[kr][cc*4+0] = f2bf(v.x); t[kr][cc*4+1] = f2bf(v.y);
    t[kr][cc*4+2] = f2bf(v.z); t[kr][cc*4+3] = f2bf(v.w);
  }
  __syncthreads();
#pragma unroll
  for (int i = 0; i < 4; ++i) {
    int nr = rr + i * 16;
    int r0 = cc * 4;
    ushort4 o;
    o.x = t[r0+0][nr]; o.y = t[r0+1][nr]; o.z = t[r0+2][nr]; o.w = t[r0+3][nr];
    *(ushort4*)&WT[(size_t)(n0 + nr) * K + k0 + r0] = o;
  }
}

__global__ __launch_bounds__(256)
void wconv_k(const float* __restrict__ W, u16* __restrict__ WT, int K, int N)
{
  __shared__ u16 t[64][65];
  int n0 = blockIdx.x * 64, k0 = blockIdx.y * 64;
  int tid = threadIdx.x;
  int rr = tid >> 4, cc = tid & 15;
#pragma unroll
  for (int i = 0; i < 4; ++i) {
    int kr = rr + i * 16;
    const float4 v = *(const float4*)&W[(size_t)(k0 + kr) * N + n0 + cc * 4];
    t[kr][cc*4+0] = f2bf(v.x); t[kr][cc*4+1] = f2bf(v.y);
    t[kr][cc*4+2] = f2bf(v.z); t[kr][cc*4+3] = f2bf(v.w);
  }
  __syncthreads();
#pragma unroll
  for (int i = 0; i < 4; ++i) {
    int nr = rr + i * 16;
    int r0 = cc * 4;
    ushort4 o;
    o.x = t[r0+0][nr]; o.y = t[r0+1][nr]; o.z = t[r0+2][nr]; o.w = t[r0+3][nr];
    *(ushort4*)&WT[(size_t)(n0 + nr) * K + k0 + r0] = o;
  }
}

// ---------------- f32 -> bf16 elementwise (context)
__global__ void cconv_k(const float* __restrict__ c, u16* __restrict__ o, int n)
{
  int i = blockIdx.x * 256 + threadIdx.x;
  if (i < n) o[i] = f2bf(c[i]);
}

// ---------------- LayerNorm: f32 row[1024] -> bf16
__global__ __launch_bounds__(256)
void ln_k(const float* __restrict__ x, const float* __restrict__ gm,
          const float* __restrict__ bt, u16* __restrict__ o)
{
  int row = blockIdx.x;
  int tid = threadIdx.x;
  const float4 v = *(const float4*)&x[(size_t)row * DIMN + tid * 4];
  float s = v.x + v.y + v.z + v.w;
  float q = v.x*v.x + v.y*v.y + v.z*v.z + v.w*v.w;
#pragma unroll
  for (int off = 32; off; off >>= 1) { s += __shfl_xor(s, off); q += __shfl_xor(q, off); }
  __shared__ float ss[4], qq[4];
  int wave = tid >> 6;
  if ((tid & 63) == 0) { ss[wave] = s; qq[wave] = q; }
  __syncthreads();
  s = ss[0] + ss[1] + ss[2] + ss[3];
  q = qq[0] + qq[1] + qq[2] + qq[3];
  float mu = s * (1.0f / DIMN);
  float var = q * (1.0f / DIMN) - mu * mu;
  float rs = rsqrtf(var + 1e-5f);
  const float4 gv = *(const float4*)&gm[tid * 4];
  const float4 bv = *(const float4*)&bt[tid * 4];
  ushort4 r;
  r.x = f2bf((v.x - mu) * rs * gv.x + bv.x);
  r.y = f2bf((v.y - mu) * rs * gv.y + bv.y);
  r.z = f2bf((v.z - mu) * rs * gv.z + bv.z);
  r.w = f2bf((v.w - mu) * rs * gv.w + bv.w);
  *(ushort4*)&o[(size_t)row * DIMN + tid * 4] = r;
}

// ---------------- GEMM (R5-proven): 512 threads, 8 waves (32x64 wave tile), 2-buf counted vmcnt
template<int MODE>
__global__ __launch_bounds__(512, 4)
void gemm_k(const u16* __restrict__ A, const u16* __restrict__ Bt,
            int M, int N, int K,
            const float* __restrict__ bias, const float* __restrict__ resid,
            u16* __restrict__ obf, float* __restrict__ of32,
            int seq, int vstride,
            u16* __restrict__ ob2, u16* __restrict__ ob3)
{
  __shared__ __align__(16) u16 As[2][128 * 32];
  __shared__ __align__(16) u16 Bs[2][128 * 32];
  const int tid = threadIdx.x;
  const int lane = tid & 63, wave = tid >> 6;
  const int wr = wave >> 1, wc = wave & 1;          // 4 x 2 wave grid
  const int g = lane >> 4, r16 = lane & 15;
  const int m0 = blockIdx.x * 128, n0 = blockIdx.y * 128;

  f32x4 acc[2][4] = {};

  const int srow = tid >> 2;          // 0..127
  const int sch  = tid & 3;           // 0..3
  const int schs = sch ^ ((srow >> 1) & 3);
  const int arow = (m0 + srow > M - 1) ? (M - 1) : (m0 + srow);
  const size_t abase = (size_t)arow * K + schs * 8;
  const size_t bbase = (size_t)(n0 + srow) * K + schs * 8;

  auto stage = [&](int buf, int kt) {
    gload16(A  + abase + kt, &As[buf][tid * 8]);
    gload16(Bt + bbase + kt, &Bs[buf][tid * 8]);
  };

  stage(0, 0);

  const int nkt = K >> 5;
  for (int t = 0; t < nkt; ++t) {
    const int cur = t & 1;
    if (t + 1 < nkt) {
      stage(cur ^ 1, (t + 1) << 5);
      asm volatile("s_waitcnt vmcnt(2)" ::: "memory");   // stage(t) landed; t+1 in flight
    } else {
      asm volatile("s_waitcnt vmcnt(0)" ::: "memory");
    }
    __builtin_amdgcn_s_barrier();                        // B1

    bf16x8 af[2], bfr[4];
#pragma unroll
    for (int mi = 0; mi < 2; ++mi) {
      int r = wr * 32 + mi * 16 + r16;
      int cph = g ^ ((r >> 1) & 3);
      af[mi] = *(const bf16x8*)&As[cur][(r * 4 + cph) * 8];
    }
#pragma unroll
    for (int ni = 0; ni < 4; ++ni) {
      int r = wc * 64 + ni * 16 + r16;
      int cph = g ^ ((r >> 1) & 3);
      bfr[ni] = *(const bf16x8*)&Bs[cur][(r * 4 + cph) * 8];
    }
    __builtin_amdgcn_s_setprio(1);
#pragma unroll
    for (int mi = 0; mi < 2; ++mi)
#pragma unroll
      for (int ni = 0; ni < 4; ++ni)
        acc[mi][ni] = mfma16(af[mi], bfr[ni], acc[mi][ni]);
    __builtin_amdgcn_s_setprio(0);

    __builtin_amdgcn_s_barrier();                        // B2 (WAR)
  }

  const int grp = n0 >> 10;           // column group for fused modes
#pragma unroll
  for (int ni = 0; ni < 4; ++ni) {
    int col = n0 + wc * 64 + ni * 16 + r16;
    float bv = 0.0f;
    if constexpr (MODE == 0 || MODE == 2) bv = bias ? bias[col] : 0.0f;
    const int c1 = col & 1023;
#pragma unroll
    for (int mi = 0; mi < 2; ++mi) {
      f32x4 c = acc[mi][ni];
#pragma unroll
      for (int rg = 0; rg < 4; ++rg) {
        int row = m0 + wr * 32 + mi * 16 + g * 4 + rg;
        if (row < M) {
          float v = c[rg] + bv;
          if constexpr (MODE == 0) {
            obf[(size_t)row * N + col] = f2bf(v);
          } else if constexpr (MODE == 2) {
            size_t o = (size_t)row * N + col;
            of32[o] = v + resid[o];
          } else if constexpr (MODE == 3) {
            int b = row / seq, srow_ = row - b * seq;
            int jg = srow_ >> 6, j = srow_ & 63;
            int pos = jg * 64 + ((j & 15) << 2) + (j >> 4);
            obf[((size_t)b * HEADS * DHEAD + c1) * vstride + pos] = f2bf(v);
          } else if constexpr (MODE == 4) {
            if (grp == 0) {
              obf[(size_t)row * 1024 + c1] = f2bf(v);
            } else if (grp == 1) {
              ob2[(size_t)row * 1024 + c1] = f2bf(v);
            } else {
              int b = row / seq, srow_ = row - b * seq;
              int jg = srow_ >> 6, j = srow_ & 63;
              int pos = jg * 64 + ((j & 15) << 2) + (j >> 4);
              ob3[((size_t)b * HEADS * DHEAD + c1) * vstride + pos] = f2bf(v);
            }
          } else {  // MODE 5
            if (grp == 0) {
              obf[(size_t)row * 1024 + c1] = f2bf(v);
            } else {
              int b = row / seq, srow_ = row - b * seq;
              int jg = srow_ >> 6, j = srow_ & 63;
              int pos = jg * 64 + ((j & 15) << 2) + (j >> 4);
              ob3[((size_t)b * HEADS * DHEAD + c1) * vstride + pos] = f2bf(v);
            }
          }
        }
      }
    }
  }
}

// ---------------- GEGLU 8-phase-lite: BM=256 BN=128 BK=32, 3-buf 2-deep prefetch,
// 8 waves (4M x 2N) of 64x64 dual-acc; 2 phases per K-tile, counted vmcnt(4).
// out = (A@B1 + ba) * gelu(A@B2 + bg)
__global__ __launch_bounds__(512, 2)
void geglu8p_k(const u16* __restrict__ A, const u16* __restrict__ B1t,
               const u16* __restrict__ B2t,
               const float* __restrict__ ba, const float* __restrict__ bg,
               u16* __restrict__ out, int M, int N)
{
  __shared__ __align__(16) u16 As[3][256 * 32];    // 48 KB
  __shared__ __align__(16) u16 B1s[3][128 * 32];   // 24 KB
  __shared__ __align__(16) u16 B2s[3][128 * 32];   // 24 KB
  const int tid = threadIdx.x;
  const int lane = tid & 63, wave = tid >> 6;
  const int wm = wave >> 1, wn = wave & 1;          // 4(M) x 2(N), 64x64 dual each
  const int g = lane >> 4, r16 = lane & 15;
  const int m0 = blockIdx.x * 256, n0 = blockIdx.y * 128;
  const int K = 1024;

  f32x4 acca[4][4] = {}, accg[4][4] = {};

  // A staging: 1024 chunks of 16B -> 2 per thread
  int aro[2], acs[2];
#pragma unroll
  for (int i = 0; i < 2; ++i) {
    const int c = tid + i * 512;
    const int r = c >> 2, ch = c & 3;
    acs[i] = ch ^ ((r >> 1) & 3);
    aro[i] = m0 + r;
  }
  // B staging: 512 chunks each -> 1 per thread
  const int brr = tid >> 2;
  const int bcs = (tid & 3) ^ ((brr >> 1) & 3);
  const size_t bbase = (size_t)(n0 + brr) * K + bcs * 8;

  auto stageA = [&](int buf, int kt) {
#pragma unroll
    for (int i = 0; i < 2; ++i)
      gload16(A + (size_t)aro[i] * K + kt + acs[i] * 8, &As[buf][(tid + i * 512) * 8]);
  };
  auto stageB = [&](int buf, int kt) {
    gload16(B1t + bbase + kt, &B1s[buf][tid * 8]);
    gload16(B2t + bbase + kt, &B2s[buf][tid * 8]);
  };

  const int nkt = K >> 5;   // 32
  stageA(0, 0);  stageB(0, 0);
  stageA(1, 32); stageB(1, 32);
  asm volatile("s_waitcnt vmcnt(4)" ::: "memory");   // tile 0 landed
  __builtin_amdgcn_s_barrier();

  int cur = 0;
  for (int t = 0; t < nkt; ++t) {
    const int nb = (cur == 0) ? 2 : cur - 1;         // (cur+2)%3
    const bool pf = (t + 2 < nkt);

    // ======== phase 0: rows wm*64 + 0..31 (B frags read once, held) ========
    bf16x8 b1f[4], b2f[4], af[2];
#pragma unroll
    for (int ni = 0; ni < 4; ++ni) {
      int r = wn * 64 + ni * 16 + r16;
      int cph = g ^ ((r >> 1) & 3);
      b1f[ni] = *(const bf16x8*)&B1s[cur][(r * 4 + cph) * 8];
      b2f[ni] = *(const bf16x8*)&B2s[cur][(r * 4 + cph) * 8];
    }
#pragma unroll
    for (int mi = 0; mi < 2; ++mi) {
      int r = wm * 64 + mi * 16 + r16;
      int cph = g ^ ((r >> 1) & 3);
      af[mi] = *(const bf16x8*)&As[cur][(r * 4 + cph) * 8];
    }
    if (pf) stageA(nb, (t + 2) << 5);
    __builtin_amdgcn_s_barrier();
    __builtin_amdgcn_s_setprio(1);
#pragma unroll
    for (int mi = 0; mi < 2; ++mi)
#pragma unroll
      for (int ni = 0; ni < 4; ++ni) {
        acca[mi][ni] = mfma16(af[mi], b1f[ni], acca[mi][ni]);
        accg[mi][ni] = mfma16(af[mi], b2f[ni], accg[mi][ni]);
      }
    __builtin_amdgcn_s_setprio(0);
    __builtin_amdgcn_s_barrier();

    // ======== phase 1: rows wm*64 + 32..63 (reuse b1f/b2f) ========
#pragma unroll
    for (int mi = 0; mi < 2; ++mi) {
      int r = wm * 64 + 32 + mi * 16 + r16;
      int cph = g ^ ((r >> 1) & 3);
      af[mi] = *(const bf16x8*)&As[cur][(r * 4 + cph) * 8];
    }
    if (pf) stageB(nb, (t + 2) << 5);
    if (t + 1 < nkt) {
      if (pf) asm volatile("s_waitcnt vmcnt(4)" ::: "memory");  // t+1 landed; t+2 in flight
      else    asm volatile("s_waitcnt vmcnt(0)" ::: "memory");
    }
    __builtin_amdgcn_s_barrier();
    __builtin_amdgcn_s_setprio(1);
#pragma unroll
    for (int mi = 0; mi < 2; ++mi)
#pragma unroll
      for (int ni = 0; ni < 4; ++ni) {
        acca[2 + mi][ni] = mfma16(af[mi], b1f[ni], acca[2 + mi][ni]);
        accg[2 + mi][ni] = mfma16(af[mi], b2f[ni], accg[2 + mi][ni]);
      }
    __builtin_amdgcn_s_setprio(0);
    __builtin_amdgcn_s_barrier();

    cur = (cur == 2) ? 0 : cur + 1;
  }

#pragma unroll
  for (int ni = 0; ni < 4; ++ni) {
    int col = n0 + wn * 64 + ni * 16 + r16;
    float bva = ba[col], bvg = bg[col];
#pragma unroll
    for (int mi = 0; mi < 4; ++mi) {
#pragma unroll
      for (int rg = 0; rg < 4; ++rg) {
        int row = m0 + wm * 64 + mi * 16 + g * 4 + rg;
        float a  = acca[mi][ni][rg] + bva;
        float gt = accg[mi][ni][rg] + bvg;
        float gl = 0.5f * gt * (1.0f + erff(gt * 0.70710678f));
        out[(size_t)row * N + col] = f2bf(a * gl);
      }
    }
  }
}

// ---------------- flash attention v4 (counted vmcnt + raw barriers)
__global__ __launch_bounds__(256)
void attn_k(const u16* __restrict__ q, const u16* __restrict__ k,
            const u16* __restrict__ vt, u16* __restrict__ o,
            int kvlen, int seqk, int vstride)
{
  __shared__ __align__(16) u16 Ks[2][64 * 64];
  __shared__ __align__(16) u16 Vs[2][64 * 64];
  __shared__ __align__(16) u16 Ps[4][32 * 72];
  const int tid = threadIdx.x, lane = tid & 63, wave = tid >> 6;
  const int g = lane >> 4, r16 = lane & 15;
  const int bh = blockIdx.y;
  const int b = bh >> 4, h = bh & 15;
  const int q0 = blockIdx.x * 128 + wave * 32;
  const float C = 0.18033688f;   // log2(e)/8

  bf16x8 aq[2][2];
#pragma unroll
  for (int qs = 0; qs < 2; ++qs) {
    const size_t qoff = (size_t)(b * SEQ + q0 + qs * 16 + r16) * DIMN + h * DHEAD;
#pragma unroll
    for (int kc = 0; kc < 2; ++kc)
      aq[qs][kc] = *(const bf16x8*)&q[qoff + kc * 32 + g * 8];
  }
  asm volatile("" :: "v"(aq[0][0]), "v"(aq[0][1]), "v"(aq[1][0]), "v"(aq[1][1]));

  f32x4 oacc[2][4] = {};
  float mi[2][4], li[2][4];
#pragma unroll
  for (int qs = 0; qs < 2; ++qs)
#pragma unroll
    for (int rg = 0; rg < 4; ++rg) { mi[qs][rg] = -3e38f; li[qs][rg] = 0.f; }

  const size_t vtbase = (size_t)(b * HEADS + h) * DHEAD * vstride;
  const size_t kbase  = (size_t)b * seqk * DIMN + h * DHEAD;
  const int nkv = (kvlen + 63) >> 6;

  auto stage = [&](int buf, int kv0) {
#pragma unroll
    for (int i = 0; i < 2; ++i) {
      const int c = tid + i * 256;
      const int row = c >> 3, ch = c & 7;
      const int chs = ch ^ (row & 7);
      int kr = kv0 + row; if (kr > kvlen - 1) kr = kvlen - 1;
      gload16(k + kbase + (size_t)kr * DIMN + chs * 8, &Ks[buf][c * 8]);
    }
#pragma unroll
    for (int i = 0; i < 2; ++i) {
      const int c = tid + i * 256;
      const int row = c >> 3, ch = c & 7;
      const int chs = ch ^ (row & 7);
      gload16(vt + vtbase + (size_t)row * vstride + kv0 + chs * 8, &Vs[buf][c * 8]);
    }
  };

  stage(0, 0);

  for (int kvb = 0; kvb < nkv; ++kvb) {
    const int kv0 = kvb * 64;
    const int cur = kvb & 1;
    if (kvb + 1 < nkv) {
      stage(cur ^ 1, kv0 + 64);
      asm volatile("s_waitcnt vmcnt(4)" ::: "memory");
    } else {
      asm volatile("s_waitcnt vmcnt(0)" ::: "memory");
    }
    __builtin_amdgcn_s_barrier();                        // B1

    // ---- QK^T: 16 MFMA
    f32x4 sa[2][4];
#pragma unroll
    for (int qs = 0; qs < 2; ++qs)
#pragma unroll
      for (int st = 0; st < 4; ++st) sa[qs][st] = (f32x4){0.f, 0.f, 0.f, 0.f};
    __builtin_amdgcn_s_setprio(1);
#pragma unroll
    for (int st = 0; st < 4; ++st) {
      const int kvr = st * 16 + r16;
#pragma unroll
      for (int kc = 0; kc < 2; ++kc) {
        const int chs = (kc * 4 + g) ^ (kvr & 7);
        const bf16x8 kf = *(const bf16x8*)&Ks[cur][kvr * 64 + chs * 8];
        sa[0][st] = mfma16(aq[0][kc], kf, sa[0][st]);
        sa[1][st] = mfma16(aq[1][kc], kf, sa[1][st]);
      }
    }
    __builtin_amdgcn_s_setprio(0);

    // ---- tail mask (cross-attn last tile only)
    if (kv0 + 64 > kvlen) {
#pragma unroll
      for (int st = 0; st < 4; ++st)
        if (kv0 + st * 16 + r16 >= kvlen) {
#pragma unroll
          for (int qs = 0; qs < 2; ++qs)
#pragma unroll
            for (int rg = 0; rg < 4; ++rg) sa[qs][st][rg] = -3e38f;
        }
    }

    // ---- defer-max check
    float bad = 0.f;
    float m4v[2][4];
#pragma unroll
    for (int qs = 0; qs < 2; ++qs)
#pragma unroll
      for (int rg = 0; rg < 4; ++rg) {
        float m4 = fmaxf(fmaxf(sa[qs][0][rg], sa[qs][1][rg]),
                         fmaxf(sa[qs][2][rg], sa[qs][3][rg]));
        m4v[qs][rg] = m4;
        bad = fmaxf(bad, m4 - mi[qs][rg]);
      }
    if (__any(bad > 16.0f)) {
#pragma unroll
      for (int qs = 0; qs < 2; ++qs)
#pragma unroll
        for (int rg = 0; rg < 4; ++rg) {
          float mx = m4v[qs][rg];
#pragma unroll
          for (int off = 1; off < 16; off <<= 1) mx = fmaxf(mx, __shfl_xor(mx, off));
          const float nm = fmaxf(mi[qs][rg], mx);
          const float corr = __builtin_amdgcn_exp2f((mi[qs][rg] - nm) * C);
          mi[qs][rg] = nm;
          li[qs][rg] *= corr;
#pragma unroll
          for (int ds = 0; ds < 4; ++ds) oacc[qs][ds][rg] *= corr;
        }
    }

    // ---- P = exp, lane-local li accumulate, packed bf16 store
#pragma unroll
    for (int qs = 0; qs < 2; ++qs) {
#pragma unroll
      for (int rg = 0; rg < 4; ++rg) {
        const float mc = mi[qs][rg] * C;
        const float p0 = __builtin_amdgcn_exp2f(__builtin_fmaf(sa[qs][0][rg], C, -mc));
        const float p1 = __builtin_amdgcn_exp2f(__builtin_fmaf(sa[qs][1][rg], C, -mc));
        const float p2 = __builtin_amdgcn_exp2f(__builtin_fmaf(sa[qs][2][rg], C, -mc));
        const float p3 = __builtin_amdgcn_exp2f(__builtin_fmaf(sa[qs][3][rg], C, -mc));
        li[qs][rg] += (p0 + p1) + (p2 + p3);
        unsigned lo, hi;
        asm("v_cvt_pk_bf16_f32 %0, %1, %2" : "=v"(lo) : "v"(p0), "v"(p1));
        asm("v_cvt_pk_bf16_f32 %0, %1, %2" : "=v"(hi) : "v"(p2), "v"(p3));
        const int prow = qs * 16 + g * 4 + rg;
        uint2 pk; pk.x = lo; pk.y = hi;
        *(uint2*)&Ps[wave][prow * 72 + r16 * 4] = pk;
      }
    }

    // ---- PV: 16 MFMA
    __builtin_amdgcn_s_setprio(1);
#pragma unroll
    for (int kc = 0; kc < 2; ++kc) {
      const bf16x8 pa0 = *(const bf16x8*)&Ps[wave][(r16)      * 72 + kc * 32 + g * 8];
      const bf16x8 pa1 = *(const bf16x8*)&Ps[wave][(16 + r16) * 72 + kc * 32 + g * 8];
#pragma unroll
      for (int ds = 0; ds < 4; ++ds) {
        const int dr = ds * 16 + r16;
        const int chs = (kc * 4 + g) ^ (dr & 7);
        const bf16x8 vf = *(const bf16x8*)&Vs[cur][dr * 64 + chs * 8];
        oacc[0][ds] = mfma16(pa0, vf, oacc[0][ds]);
        oacc[1][ds] = mfma16(pa1, vf, oacc[1][ds]);
      }
    }
    __builtin_amdgcn_s_setprio(0);

    __builtin_amdgcn_s_barrier();                        // B2
  }

#pragma unroll
  for (int qs = 0; qs < 2; ++qs)
#pragma unroll
    for (int rg = 0; rg < 4; ++rg) {
      float s = li[qs][rg];
#pragma unroll
      for (int off = 1; off < 16; off <<= 1) s += __shfl_xor(s, off);
      li[qs][rg] = s;
    }

#pragma unroll
  for (int qs = 0; qs < 2; ++qs)
#pragma unroll
    for (int rg = 0; rg < 4; ++rg) {
      const float inv = 1.0f / li[qs][rg];
      const int row = q0 + qs * 16 + g * 4 + rg;
      const size_t base = (size_t)(b * SEQ + row) * DIMN + h * DHEAD;
#pragma unroll
      for (int ds = 0; ds < 4; ++ds)
        o[base + ds * 16 + r16] = f2bf(oacc[qs][ds][rg] * inv);
    }
}

extern "C" void kernel_launch(void* const* d_in, const int* in_sizes, int n_in,
                              void* d_out, int out_size, void* d_ws, size_t ws_size,
                              hipStream_t stream)
{
  const float* x   = (const float*)d_in[0];
  const float* ctx = (const float*)d_in[1];
  const float* Wq1 = (const float*)d_in[2];
  const float* Wk1 = (const float*)d_in[3];
  const float* Wv1 = (const float*)d_in[4];
  const float* Wo1 = (const float*)d_in[5];
  const float* bo1 = (const float*)d_in[6];
  const float* Wq2 = (const float*)d_in[7];
  const float* Wk2 = (const float*)d_in[8];
  const float* Wv2 = (const float*)d_in[9];
  const float* Wo2 = (const float*)d_in[10];
  const float* bo2 = (const float*)d_in[11];
  const float* Wp  = (const float*)d_in[12];
  const float* bp  = (const float*)d_in[13];
  const float* W2  = (const float*)d_in[14];
  const float* b2  = (const float*)d_in[15];
  const float* g1  = (const float*)d_in[16];
  const float* be1 = (const float*)d_in[17];
  const float* g2  = (const float*)d_in[18];
  const float* be2 = (const float*)d_in[19];
  const float* g3  = (const float*)d_in[20];
  const float* be3 = (const float*)d_in[21];

  char* ws = (char*)d_ws;
  size_t off = 0;
  auto alloc = [&](size_t bytes) -> void* {
    void* p = ws + off;
    off += (bytes + 255) & ~(size_t)255;
    return p;
  };

  u16* WqT1 = (u16*)alloc((size_t)1024 * 1024 * 2);   // contiguous with WkT1, WvT1
  u16* WkT1 = (u16*)alloc((size_t)1024 * 1024 * 2);
  u16* WvT1 = (u16*)alloc((size_t)1024 * 1024 * 2);
  u16* WoT1 = (u16*)alloc((size_t)1024 * 1024 * 2);
  u16* WqT2 = (u16*)alloc((size_t)1024 * 1024 * 2);
  u16* WkT2 = (u16*)alloc((size_t)1024 * 768 * 2);    // contiguous with WvT2
  u16* WvT2 = (u16*)alloc((size_t)1024 * 768 * 2);
  u16* WoT2 = (u16*)alloc((size_t)1024 * 1024 * 2);
  u16* WpT  = (u16*)alloc((size_t)8192 * 1024 * 2);
  u16* W2T  = (u16*)alloc((size_t)1024 * 4096 * 2);
  float* x1f = (float*)alloc((size_t)NTOK * DIMN * 4);
  float* x2f = (float*)alloc((size_t)NTOK * DIMN * 4);
  u16* ctxb = (u16*)alloc((size_t)CTOK * CTXD * 2);
  u16* k2b  = (u16*)alloc((size_t)CTOK * DIMN * 2);
  u16* vt2b = (u16*)alloc((size_t)2 * HEADS * DHEAD * 128 * 2);
  u16* hb   = (u16*)alloc((size_t)NTOK * DIMN * 2);
  u16* qb   = (u16*)alloc((size_t)NTOK * DIMN * 2);
  u16* kb   = (u16*)alloc((size_t)NTOK * DIMN * 2);
  u16* vtb  = (u16*)alloc((size_t)NTOK * DIMN * 2);
  u16* ab   = (u16*)alloc((size_t)NTOK * DIMN * 2);
  u16* ub   = qb; // reuse qb..ab region (32MB) for FF intermediate [4096][4096]

  dim3 blk(256);
  dim3 blk5(512);

  // batched weight conversions
  WBatch wb6;
  wb6.s[0] = Wq1; wb6.d[0] = WqT1;
  wb6.s[1] = Wk1; wb6.d[1] = WkT1;
  wb6.s[2] = Wv1; wb6.d[2] = WvT1;
  wb6.s[3] = Wo1; wb6.d[3] = WoT1;
  wb6.s[4] = Wq2; wb6.d[4] = WqT2;
  wb6.s[5] = Wo2; wb6.d[5] = WoT2;
  wconvB_k<6><<<dim3(16, 16, 6), blk, 0, stream>>>(wb6, 1024, 1024);
  WBatch wb2;
  wb2.s[0] = Wk2; wb2.d[0] = WkT2;
  wb2.s[1] = Wv2; wb2.d[1] = WvT2;
  wb2.s[2] = nullptr; wb2.d[2] = nullptr;
  wb2.s[3] = nullptr; wb2.d[3] = nullptr;
  wb2.s[4] = nullptr; wb2.d[4] = nullptr;
  wb2.s[5] = nullptr; wb2.d[5] = nullptr;
  wconvB_k<2><<<dim3(16, 12, 2), blk, 0, stream>>>(wb2, 768, 1024);
  wconv_k<<<dim3(128, 16), blk, 0, stream>>>(Wp, WpT, 1024, 8192);
  wconv_k<<<dim3(16, 64), blk, 0, stream>>>(W2, W2T, 4096, 1024);
  cconv_k<<<dim3((CTOK * CTXD + 255) / 256), blk, 0, stream>>>(ctx, ctxb, CTOK * CTXD);

  // ---- self attention block (QKV fused: WqT1/WkT1/WvT1 contiguous, N=3072)
  ln_k<<<NTOK, 256, 0, stream>>>(x, g1, be1, hb);
  gemm_k<4><<<dim3(32, 24), blk5, 0, stream>>>(hb, WqT1, NTOK, 3072, 1024, nullptr, nullptr, qb, nullptr, SEQ, SEQ, kb, vtb);
  attn_k<<<dim3(16, 32), blk, 0, stream>>>(qb, kb, vtb, ab, SEQ, SEQ, SEQ);
  gemm_k<2><<<dim3(32, 8), blk5, 0, stream>>>(ab, WoT1, NTOK, 1024, 1024, bo1, x, nullptr, x1f, 0, 0, nullptr, nullptr);

  // ---- cross attention block (K2+V2 fused over ctx, N=2048)
  ln_k<<<NTOK, 256, 0, stream>>>(x1f, g2, be2, hb);
  gemm_k<0><<<dim3(32, 8), blk5, 0, stream>>>(hb, WqT2, NTOK, 1024, 1024, nullptr, nullptr, qb, nullptr, 0, 0, nullptr, nullptr);
  gemm_k<5><<<dim3(2, 16), blk5, 0, stream>>>(ctxb, WkT2, CTOK, 2048, 768, nullptr, nullptr, k2b, nullptr, NCTX, 128, nullptr, vt2b);
  attn_k<<<dim3(16, 32), blk, 0, stream>>>(qb, k2b, vt2b, ab, NCTX, NCTX, 128);
  gemm_k<2><<<dim3(32, 8), blk5, 0, stream>>>(ab, WoT2, NTOK, 1024, 1024, bo2, x1f, nullptr, x2f, 0, 0, nullptr, nullptr);

  // ---- GEGLU FF block
  ln_k<<<NTOK, 256, 0, stream>>>(x2f, g3, be3, hb);
  geglu8p_k<<<dim3(16, 32), blk5, 0, stream>>>(hb, WpT, WpT + (size_t)4096 * 1024, bp, bp + 4096, ub, NTOK, FFH);
  gemm_k<2><<<dim3(32, 8), blk5, 0, stream>>>(ub, W2T, NTOK, 1024, 4096, b2, x2f, nullptr, (float*)d_out, 0, 0, nullptr, nullptr);

  (void)in_sizes; (void)n_in; (void)out_size; (void)ws_size;
}

// Round 10
// 404.620 us; speedup vs baseline: 1.1577x; 1.0742x over previous
//
#include <hip/hip_runtime.h>
#include <hip/hip_bf16.h>
#include <math.h>

#define DIMN   1024
#define HEADS  16
#define DHEAD  64
#define CTXD   768
#define FFH    4096
#define NTOK   4096
#define SEQ    2048
#define NCTX   77
#define CTOK   154

typedef unsigned short u16;
typedef __bf16 bf16x8 __attribute__((ext_vector_type(8)));
typedef float  f32x4  __attribute__((ext_vector_type(4)));

__device__ __forceinline__ u16 f2bf(float f) {
  union { float f; unsigned u; } c; c.f = f;
  unsigned r = c.u + 0x7FFFu + ((c.u >> 16) & 1u);
  return (u16)(r >> 16);
}
__device__ __forceinline__ float bf2f(u16 h) {
  union { unsigned u; float f; } c; c.u = ((unsigned)h) << 16; return c.f;
}

__device__ __forceinline__ void gload16(const void* g, void* l) {
  __builtin_amdgcn_global_load_lds(
      (__attribute__((address_space(1))) void*)(void*)(g),
      (__attribute__((address_space(3))) void*)(l), 16, 0, 0);
}

__device__ __forceinline__ f32x4 mfma16(bf16x8 a, bf16x8 b, f32x4 c) {
  return __builtin_amdgcn_mfma_f32_16x16x32_bf16(a, b, c, 0, 0, 0);
}

// ---------------- batched weight convert+transpose: W[K][N] f32 -> WT[N][K] bf16
struct WBatch { const float* s[6]; u16* d[6]; };

template<int NB>
__global__ __launch_bounds__(256)
void wconvB_k(WBatch wb, int K, int N)
{
  __shared__ u16 t[64][65];
  const float* __restrict__ W  = wb.s[blockIdx.z];
  u16* __restrict__       WT   = wb.d[blockIdx.z];
  int n0 = blockIdx.x * 64, k0 = blockIdx.y * 64;
  int tid = threadIdx.x;
  int rr = tid >> 4, cc = tid & 15;
#pragma unroll
  for (int i = 0; i < 4; ++i) {
    int kr = rr + i * 16;
    const float4 v = *(const float4*)&W[(size_t)(k0 + kr) * N + n0 + cc * 4];
    t[kr][cc*4+0] = f2bf(v.x); t[kr][cc*4+1] = f2bf(v.y);
    t[kr][cc*4+2] = f2bf(v.z); t[kr][cc*4+3] = f2bf(v.w);
  }
  __syncthreads();
#pragma unroll
  for (int i = 0; i < 4; ++i) {
    int nr = rr + i * 16;
    int r0 = cc * 4;
    ushort4 o;
    o.x = t[r0+0][nr]; o.y = t[r0+1][nr]; o.z = t[r0+2][nr]; o.w = t[r0+3][nr];
    *(ushort4*)&WT[(size_t)(n0 + nr) * K + k0 + r0] = o;
  }
}

__global__ __launch_bounds__(256)
void wconv_k(const float* __restrict__ W, u16* __restrict__ WT, int K, int N)
{
  __shared__ u16 t[64][65];
  int n0 = blockIdx.x * 64, k0 = blockIdx.y * 64;
  int tid = threadIdx.x;
  int rr = tid >> 4, cc = tid & 15;
#pragma unroll
  for (int i = 0; i < 4; ++i) {
    int kr = rr + i * 16;
    const float4 v = *(const float4*)&W[(size_t)(k0 + kr) * N + n0 + cc * 4];
    t[kr][cc*4+0] = f2bf(v.x); t[kr][cc*4+1] = f2bf(v.y);
    t[kr][cc*4+2] = f2bf(v.z); t[kr][cc*4+3] = f2bf(v.w);
  }
  __syncthreads();
#pragma unroll
  for (int i = 0; i < 4; ++i) {
    int nr = rr + i * 16;
    int r0 = cc * 4;
    ushort4 o;
    o.x = t[r0+0][nr]; o.y = t[r0+1][nr]; o.z = t[r0+2][nr]; o.w = t[r0+3][nr];
    *(ushort4*)&WT[(size_t)(n0 + nr) * K + k0 + r0] = o;
  }
}

// ---------------- f32 -> bf16 elementwise (context)
__global__ void cconv_k(const float* __restrict__ c, u16* __restrict__ o, int n)
{
  int i = blockIdx.x * 256 + threadIdx.x;
  if (i < n) o[i] = f2bf(c[i]);
}

// ---------------- LayerNorm: f32 row[1024] -> bf16
__global__ __launch_bounds__(256)
void ln_k(const float* __restrict__ x, const float* __restrict__ gm,
          const float* __restrict__ bt, u16* __restrict__ o)
{
  int row = blockIdx.x;
  int tid = threadIdx.x;
  const float4 v = *(const float4*)&x[(size_t)row * DIMN + tid * 4];
  float s = v.x + v.y + v.z + v.w;
  float q = v.x*v.x + v.y*v.y + v.z*v.z + v.w*v.w;
#pragma unroll
  for (int off = 32; off; off >>= 1) { s += __shfl_xor(s, off); q += __shfl_xor(q, off); }
  __shared__ float ss[4], qq[4];
  int wave = tid >> 6;
  if ((tid & 63) == 0) { ss[wave] = s; qq[wave] = q; }
  __syncthreads();
  s = ss[0] + ss[1] + ss[2] + ss[3];
  q = qq[0] + qq[1] + qq[2] + qq[3];
  float mu = s * (1.0f / DIMN);
  float var = q * (1.0f / DIMN) - mu * mu;
  float rs = rsqrtf(var + 1e-5f);
  const float4 gv = *(const float4*)&gm[tid * 4];
  const float4 bv = *(const float4*)&bt[tid * 4];
  ushort4 r;
  r.x = f2bf((v.x - mu) * rs * gv.x + bv.x);
  r.y = f2bf((v.y - mu) * rs * gv.y + bv.y);
  r.z = f2bf((v.z - mu) * rs * gv.z + bv.z);
  r.w = f2bf((v.w - mu) * rs * gv.w + bv.w);
  *(ushort4*)&o[(size_t)row * DIMN + tid * 4] = r;
}

// ---------------- GEMM (R5-proven): 512 threads, 8 waves (32x64 wave tile), 2-buf counted vmcnt
// Used for QKV (MODE 4) and KV2 (MODE 5) where grid > 256 blocks.
template<int MODE>
__global__ __launch_bounds__(512, 4)
void gemm_k(const u16* __restrict__ A, const u16* __restrict__ Bt,
            int M, int N, int K,
            const float* __restrict__ bias, const float* __restrict__ resid,
            u16* __restrict__ obf, float* __restrict__ of32,
            int seq, int vstride,
            u16* __restrict__ ob2, u16* __restrict__ ob3)
{
  __shared__ __align__(16) u16 As[2][128 * 32];
  __shared__ __align__(16) u16 Bs[2][128 * 32];
  const int tid = threadIdx.x;
  const int lane = tid & 63, wave = tid >> 6;
  const int wr = wave >> 1, wc = wave & 1;          // 4 x 2 wave grid
  const int g = lane >> 4, r16 = lane & 15;
  const int m0 = blockIdx.x * 128, n0 = blockIdx.y * 128;

  f32x4 acc[2][4] = {};

  const int srow = tid >> 2;          // 0..127
  const int sch  = tid & 3;           // 0..3
  const int schs = sch ^ ((srow >> 1) & 3);
  const int arow = (m0 + srow > M - 1) ? (M - 1) : (m0 + srow);
  const size_t abase = (size_t)arow * K + schs * 8;
  const size_t bbase = (size_t)(n0 + srow) * K + schs * 8;

  auto stage = [&](int buf, int kt) {
    gload16(A  + abase + kt, &As[buf][tid * 8]);
    gload16(Bt + bbase + kt, &Bs[buf][tid * 8]);
  };

  stage(0, 0);

  const int nkt = K >> 5;
  for (int t = 0; t < nkt; ++t) {
    const int cur = t & 1;
    if (t + 1 < nkt) {
      stage(cur ^ 1, (t + 1) << 5);
      asm volatile("s_waitcnt vmcnt(2)" ::: "memory");   // stage(t) landed; t+1 in flight
    } else {
      asm volatile("s_waitcnt vmcnt(0)" ::: "memory");
    }
    __builtin_amdgcn_s_barrier();                        // B1

    bf16x8 af[2], bfr[4];
#pragma unroll
    for (int mi = 0; mi < 2; ++mi) {
      int r = wr * 32 + mi * 16 + r16;
      int cph = g ^ ((r >> 1) & 3);
      af[mi] = *(const bf16x8*)&As[cur][(r * 4 + cph) * 8];
    }
#pragma unroll
    for (int ni = 0; ni < 4; ++ni) {
      int r = wc * 64 + ni * 16 + r16;
      int cph = g ^ ((r >> 1) & 3);
      bfr[ni] = *(const bf16x8*)&Bs[cur][(r * 4 + cph) * 8];
    }
    __builtin_amdgcn_s_setprio(1);
#pragma unroll
    for (int mi = 0; mi < 2; ++mi)
#pragma unroll
      for (int ni = 0; ni < 4; ++ni)
        acc[mi][ni] = mfma16(af[mi], bfr[ni], acc[mi][ni]);
    __builtin_amdgcn_s_setprio(0);

    __builtin_amdgcn_s_barrier();                        // B2 (WAR)
  }

  const int grp = n0 >> 10;           // column group for fused modes
#pragma unroll
  for (int ni = 0; ni < 4; ++ni) {
    int col = n0 + wc * 64 + ni * 16 + r16;
    float bv = 0.0f;
    if constexpr (MODE == 0 || MODE == 2) bv = bias ? bias[col] : 0.0f;
    const int c1 = col & 1023;
#pragma unroll
    for (int mi = 0; mi < 2; ++mi) {
      f32x4 c = acc[mi][ni];
#pragma unroll
      for (int rg = 0; rg < 4; ++rg) {
        int row = m0 + wr * 32 + mi * 16 + g * 4 + rg;
        if (row < M) {
          float v = c[rg] + bv;
          if constexpr (MODE == 0) {
            obf[(size_t)row * N + col] = f2bf(v);
          } else if constexpr (MODE == 2) {
            size_t o = (size_t)row * N + col;
            of32[o] = v + resid[o];
          } else if constexpr (MODE == 3) {
            int b = row / seq, srow_ = row - b * seq;
            int jg = srow_ >> 6, j = srow_ & 63;
            int pos = jg * 64 + ((j & 15) << 2) + (j >> 4);
            obf[((size_t)b * HEADS * DHEAD + c1) * vstride + pos] = f2bf(v);
          } else if constexpr (MODE == 4) {
            if (grp == 0) {
              obf[(size_t)row * 1024 + c1] = f2bf(v);
            } else if (grp == 1) {
              ob2[(size_t)row * 1024 + c1] = f2bf(v);
            } else {
              int b = row / seq, srow_ = row - b * seq;
              int jg = srow_ >> 6, j = srow_ & 63;
              int pos = jg * 64 + ((j & 15) << 2) + (j >> 4);
              ob3[((size_t)b * HEADS * DHEAD + c1) * vstride + pos] = f2bf(v);
            }
          } else {  // MODE 5
            if (grp == 0) {
              obf[(size_t)row * 1024 + c1] = f2bf(v);
            } else {
              int b = row / seq, srow_ = row - b * seq;
              int jg = srow_ >> 6, j = srow_ & 63;
              int pos = jg * 64 + ((j & 15) << 2) + (j >> 4);
              ob3[((size_t)b * HEADS * DHEAD + c1) * vstride + pos] = f2bf(v);
            }
          }
        }
      }
    }
  }
}

// ---------------- GEMM BK=64: for grid<=256 (1 block/CU) launches — LDS is free,
// barrier pairs halve, 32 MFMA per sync. MODE 0 / MODE 2 only. K % 64 == 0.
template<int MODE>
__global__ __launch_bounds__(512, 2)
void gemm64_k(const u16* __restrict__ A, const u16* __restrict__ Bt,
              int M, int N, int K,
              const float* __restrict__ bias, const float* __restrict__ resid,
              u16* __restrict__ obf, float* __restrict__ of32)
{
  __shared__ __align__(16) u16 As[2][128 * 64];   // 32 KB
  __shared__ __align__(16) u16 Bs[2][128 * 64];   // 32 KB
  const int tid = threadIdx.x;
  const int lane = tid & 63, wave = tid >> 6;
  const int wr = wave >> 1, wc = wave & 1;          // 4 x 2 wave grid, 32x64 tiles
  const int g = lane >> 4, r16 = lane & 15;
  const int m0 = blockIdx.x * 128, n0 = blockIdx.y * 128;

  f32x4 acc[2][4] = {};

  // staging: tile = 128 rows x 8 chunks(16B) = 1024 chunks -> 2 per thread per matrix
  int aro[2], bro[2], scs[2];
#pragma unroll
  for (int i = 0; i < 2; ++i) {
    const int c = tid + i * 512;
    const int r = c >> 3, ch = c & 7;
    scs[i] = ch ^ (r & 7);
    aro[i] = (m0 + r > M - 1) ? (M - 1) : (m0 + r);
    bro[i] = n0 + r;
  }

  auto stage = [&](int buf, int kt) {
#pragma unroll
    for (int i = 0; i < 2; ++i) {
      const int c = tid + i * 512;
      gload16(A  + (size_t)aro[i] * K + kt + scs[i] * 8, &As[buf][c * 8]);
      gload16(Bt + (size_t)bro[i] * K + kt + scs[i] * 8, &Bs[buf][c * 8]);
    }
  };

  stage(0, 0);

  const int nkt = K >> 6;
  for (int t = 0; t < nkt; ++t) {
    const int cur = t & 1;
    if (t + 1 < nkt) {
      stage(cur ^ 1, (t + 1) << 6);
      asm volatile("s_waitcnt vmcnt(4)" ::: "memory");   // stage(t) landed; t+1 in flight
    } else {
      asm volatile("s_waitcnt vmcnt(0)" ::: "memory");
    }
    __builtin_amdgcn_s_barrier();                        // B1

#pragma unroll
    for (int ks = 0; ks < 2; ++ks) {
      bf16x8 af[2], bfr[4];
#pragma unroll
      for (int mi = 0; mi < 2; ++mi) {
        int r = wr * 32 + mi * 16 + r16;
        int cph = (ks * 4 + g) ^ (r & 7);
        af[mi] = *(const bf16x8*)&As[cur][(r * 8 + cph) * 8];
      }
#pragma unroll
      for (int ni = 0; ni < 4; ++ni) {
        int r = wc * 64 + ni * 16 + r16;
        int cph = (ks * 4 + g) ^ (r & 7);
        bfr[ni] = *(const bf16x8*)&Bs[cur][(r * 8 + cph) * 8];
      }
      __builtin_amdgcn_s_setprio(1);
#pragma unroll
      for (int mi = 0; mi < 2; ++mi)
#pragma unroll
        for (int ni = 0; ni < 4; ++ni)
          acc[mi][ni] = mfma16(af[mi], bfr[ni], acc[mi][ni]);
      __builtin_amdgcn_s_setprio(0);
    }

    __builtin_amdgcn_s_barrier();                        // B2 (WAR)
  }

#pragma unroll
  for (int ni = 0; ni < 4; ++ni) {
    int col = n0 + wc * 64 + ni * 16 + r16;
    float bv = bias ? bias[col] : 0.0f;
#pragma unroll
    for (int mi = 0; mi < 2; ++mi) {
      f32x4 c = acc[mi][ni];
#pragma unroll
      for (int rg = 0; rg < 4; ++rg) {
        int row = m0 + wr * 32 + mi * 16 + g * 4 + rg;
        if (row < M) {
          float v = c[rg] + bv;
          if constexpr (MODE == 0) {
            obf[(size_t)row * N + col] = f2bf(v);
          } else {
            size_t o = (size_t)row * N + col;
            of32[o] = v + resid[o];
          }
        }
      }
    }
  }
}

// ---------------- fused GEGLU GEMM (R5-proven): 512 thr, 128x128, 2-buf counted vmcnt
__global__ __launch_bounds__(512, 2)
void geglu_k(const u16* __restrict__ A, const u16* __restrict__ B1t,
             const u16* __restrict__ B2t,
             const float* __restrict__ ba, const float* __restrict__ bg,
             u16* __restrict__ out, int M, int N)
{
  __shared__ __align__(16) u16 As[2][128 * 32];
  __shared__ __align__(16) u16 B1s[2][128 * 32];
  __shared__ __align__(16) u16 B2s[2][128 * 32];
  const int tid = threadIdx.x;
  const int lane = tid & 63, wave = tid >> 6;
  const int wr = wave >> 1, wc = wave & 1;
  const int g = lane >> 4, r16 = lane & 15;
  const int m0 = blockIdx.x * 128, n0 = blockIdx.y * 128;
  const int K = 1024;

  f32x4 acca[2][4] = {}, accg[2][4] = {};

  const int srow = tid >> 2;
  const int sch  = tid & 3;
  const int schs = sch ^ ((srow >> 1) & 3);
  const size_t abase = (size_t)(m0 + srow) * K + schs * 8;
  const size_t bbase = (size_t)(n0 + srow) * K + schs * 8;

  auto stage = [&](int buf, int kt) {
    gload16(A   + abase + kt, &As[buf][tid * 8]);
    gload16(B1t + bbase + kt, &B1s[buf][tid * 8]);
    gload16(B2t + bbase + kt, &B2s[buf][tid * 8]);
  };

  stage(0, 0);

  const int nkt = K >> 5;
  for (int t = 0; t < nkt; ++t) {
    const int cur = t & 1;
    if (t + 1 < nkt) {
      stage(cur ^ 1, (t + 1) << 5);
      asm volatile("s_waitcnt vmcnt(3)" ::: "memory");
    } else {
      asm volatile("s_waitcnt vmcnt(0)" ::: "memory");
    }
    __builtin_amdgcn_s_barrier();                        // B1

    bf16x8 af[2], b1f[4], b2f[4];
#pragma unroll
    for (int mi = 0; mi < 2; ++mi) {
      int r = wr * 32 + mi * 16 + r16;
      int cph = g ^ ((r >> 1) & 3);
      af[mi] = *(const bf16x8*)&As[cur][(r * 4 + cph) * 8];
    }
#pragma unroll
    for (int ni = 0; ni < 4; ++ni) {
      int r = wc * 64 + ni * 16 + r16;
      int cph = g ^ ((r >> 1) & 3);
      b1f[ni] = *(const bf16x8*)&B1s[cur][(r * 4 + cph) * 8];
      b2f[ni] = *(const bf16x8*)&B2s[cur][(r * 4 + cph) * 8];
    }
    __builtin_amdgcn_s_setprio(1);
#pragma unroll
    for (int mi = 0; mi < 2; ++mi)
#pragma unroll
      for (int ni = 0; ni < 4; ++ni) {
        acca[mi][ni] = mfma16(af[mi], b1f[ni], acca[mi][ni]);
        accg[mi][ni] = mfma16(af[mi], b2f[ni], accg[mi][ni]);
      }
    __builtin_amdgcn_s_setprio(0);

    __builtin_amdgcn_s_barrier();                        // B2
  }

#pragma unroll
  for (int ni = 0; ni < 4; ++ni) {
    int col = n0 + wc * 64 + ni * 16 + r16;
    float bva = ba[col], bvg = bg[col];
#pragma unroll
    for (int mi = 0; mi < 2; ++mi) {
#pragma unroll
      for (int rg = 0; rg < 4; ++rg) {
        int row = m0 + wr * 32 + mi * 16 + g * 4 + rg;
        float a  = acca[mi][ni][rg] + bva;
        float gt = accg[mi][ni][rg] + bvg;
        float gl = 0.5f * gt * (1.0f + erff(gt * 0.70710678f));
        out[(size_t)row * N + col] = f2bf(a * gl);
      }
    }
  }
}

// ---------------- flash attention v4 (counted vmcnt + raw barriers)
__global__ __launch_bounds__(256)
void attn_k(const u16* __restrict__ q, const u16* __restrict__ k,
            const u16* __restrict__ vt, u16* __restrict__ o,
            int kvlen, int seqk, int vstride)
{
  __shared__ __align__(16) u16 Ks[2][64 * 64];
  __shared__ __align__(16) u16 Vs[2][64 * 64];
  __shared__ __align__(16) u16 Ps[4][32 * 72];
  const int tid = threadIdx.x, lane = tid & 63, wave = tid >> 6;
  const int g = lane >> 4, r16 = lane & 15;
  const int bh = blockIdx.y;
  const int b = bh >> 4, h = bh & 15;
  const int q0 = blockIdx.x * 128 + wave * 32;
  const float C = 0.18033688f;   // log2(e)/8

  bf16x8 aq[2][2];
#pragma unroll
  for (int qs = 0; qs < 2; ++qs) {
    const size_t qoff = (size_t)(b * SEQ + q0 + qs * 16 + r16) * DIMN + h * DHEAD;
#pragma unroll
    for (int kc = 0; kc < 2; ++kc)
      aq[qs][kc] = *(const bf16x8*)&q[qoff + kc * 32 + g * 8];
  }
  asm volatile("" :: "v"(aq[0][0]), "v"(aq[0][1]), "v"(aq[1][0]), "v"(aq[1][1]));

  f32x4 oacc[2][4] = {};
  float mi[2][4], li[2][4];
#pragma unroll
  for (int qs = 0; qs < 2; ++qs)
#pragma unroll
    for (int rg = 0; rg < 4; ++rg) { mi[qs][rg] = -3e38f; li[qs][rg] = 0.f; }

  const size_t vtbase = (size_t)(b * HEADS + h) * DHEAD * vstride;
  const size_t kbase  = (size_t)b * seqk * DIMN + h * DHEAD;
  const int nkv = (kvlen + 63) >> 6;

  auto stage = [&](int buf, int kv0) {
#pragma unroll
    for (int i = 0; i < 2; ++i) {
      const int c = tid + i * 256;
      const int row = c >> 3, ch = c & 7;
      const int chs = ch ^ (row & 7);
      int kr = kv0 + row; if (kr > kvlen - 1) kr = kvlen - 1;
      gload16(k + kbase + (size_t)kr * DIMN + chs * 8, &Ks[buf][c * 8]);
    }
#pragma unroll
    for (int i = 0; i < 2; ++i) {
      const int c = tid + i * 256;
      const int row = c >> 3, ch = c & 7;
      const int chs = ch ^ (row & 7);
      gload16(vt + vtbase + (size_t)row * vstride + kv0 + chs * 8, &Vs[buf][c * 8]);
    }
  };

  stage(0, 0);

  for (int kvb = 0; kvb < nkv; ++kvb) {
    const int kv0 = kvb * 64;
    const int cur = kvb & 1;
    if (kvb + 1 < nkv) {
      stage(cur ^ 1, kv0 + 64);
      asm volatile("s_waitcnt vmcnt(4)" ::: "memory");
    } else {
      asm volatile("s_waitcnt vmcnt(0)" ::: "memory");
    }
    __builtin_amdgcn_s_barrier();                        // B1

    // ---- QK^T: 16 MFMA
    f32x4 sa[2][4];
#pragma unroll
    for (int qs = 0; qs < 2; ++qs)
#pragma unroll
      for (int st = 0; st < 4; ++st) sa[qs][st] = (f32x4){0.f, 0.f, 0.f, 0.f};
    __builtin_amdgcn_s_setprio(1);
#pragma unroll
    for (int st = 0; st < 4; ++st) {
      const int kvr = st * 16 + r16;
#pragma unroll
      for (int kc = 0; kc < 2; ++kc) {
        const int chs = (kc * 4 + g) ^ (kvr & 7);
        const bf16x8 kf = *(const bf16x8*)&Ks[cur][kvr * 64 + chs * 8];
        sa[0][st] = mfma16(aq[0][kc], kf, sa[0][st]);
        sa[1][st] = mfma16(aq[1][kc], kf, sa[1][st]);
      }
    }
    __builtin_amdgcn_s_setprio(0);

    // ---- tail mask (cross-attn last tile only)
    if (kv0 + 64 > kvlen) {
#pragma unroll
      for (int st = 0; st < 4; ++st)
        if (kv0 + st * 16 + r16 >= kvlen) {
#pragma unroll
          for (int qs = 0; qs < 2; ++qs)
#pragma unroll
            for (int rg = 0; rg < 4; ++rg) sa[qs][st][rg] = -3e38f;
        }
    }

    // ---- defer-max check
    float bad = 0.f;
    float m4v[2][4];
#pragma unroll
    for (int qs = 0; qs < 2; ++qs)
#pragma unroll
      for (int rg = 0; rg < 4; ++rg) {
        float m4 = fmaxf(fmaxf(sa[qs][0][rg], sa[qs][1][rg]),
                         fmaxf(sa[qs][2][rg], sa[qs][3][rg]));
        m4v[qs][rg] = m4;
        bad = fmaxf(bad, m4 - mi[qs][rg]);
      }
    if (__any(bad > 16.0f)) {
#pragma unroll
      for (int qs = 0; qs < 2; ++qs)
#pragma unroll
        for (int rg = 0; rg < 4; ++rg) {
          float mx = m4v[qs][rg];
#pragma unroll
          for (int off = 1; off < 16; off <<= 1) mx = fmaxf(mx, __shfl_xor(mx, off));
          const float nm = fmaxf(mi[qs][rg], mx);
          const float corr = __builtin_amdgcn_exp2f((mi[qs][rg] - nm) * C);
          mi[qs][rg] = nm;
          li[qs][rg] *= corr;
#pragma unroll
          for (int ds = 0; ds < 4; ++ds) oacc[qs][ds][rg] *= corr;
        }
    }

    // ---- P = exp, lane-local li accumulate, packed bf16 store
#pragma unroll
    for (int qs = 0; qs < 2; ++qs) {
#pragma unroll
      for (int rg = 0; rg < 4; ++rg) {
        const float mc = mi[qs][rg] * C;
        const float p0 = __builtin_amdgcn_exp2f(__builtin_fmaf(sa[qs][0][rg], C, -mc));
        const float p1 = __builtin_amdgcn_exp2f(__builtin_fmaf(sa[qs][1][rg], C, -mc));
        const float p2 = __builtin_amdgcn_exp2f(__builtin_fmaf(sa[qs][2][rg], C, -mc));
        const float p3 = __builtin_amdgcn_exp2f(__builtin_fmaf(sa[qs][3][rg], C, -mc));
        li[qs][rg] += (p0 + p1) + (p2 + p3);
        unsigned lo, hi;
        asm("v_cvt_pk_bf16_f32 %0, %1, %2" : "=v"(lo) : "v"(p0), "v"(p1));
        asm("v_cvt_pk_bf16_f32 %0, %1, %2" : "=v"(hi) : "v"(p2), "v"(p3));
        const int prow = qs * 16 + g * 4 + rg;
        uint2 pk; pk.x = lo; pk.y = hi;
        *(uint2*)&Ps[wave][prow * 72 + r16 * 4] = pk;
      }
    }

    // ---- PV: 16 MFMA
    __builtin_amdgcn_s_setprio(1);
#pragma unroll
    for (int kc = 0; kc < 2; ++kc) {
      const bf16x8 pa0 = *(const bf16x8*)&Ps[wave][(r16)      * 72 + kc * 32 + g * 8];
      const bf16x8 pa1 = *(const bf16x8*)&Ps[wave][(16 + r16) * 72 + kc * 32 + g * 8];
#pragma unroll
      for (int ds = 0; ds < 4; ++ds) {
        const int dr = ds * 16 + r16;
        const int chs = (kc * 4 + g) ^ (dr & 7);
        const bf16x8 vf = *(const bf16x8*)&Vs[cur][dr * 64 + chs * 8];
        oacc[0][ds] = mfma16(pa0, vf, oacc[0][ds]);
        oacc[1][ds] = mfma16(pa1, vf, oacc[1][ds]);
      }
    }
    __builtin_amdgcn_s_setprio(0);

    __builtin_amdgcn_s_barrier();                        // B2
  }

#pragma unroll
  for (int qs = 0; qs < 2; ++qs)
#pragma unroll
    for (int rg = 0; rg < 4; ++rg) {
      float s = li[qs][rg];
#pragma unroll
      for (int off = 1; off < 16; off <<= 1) s += __shfl_xor(s, off);
      li[qs][rg] = s;
    }

#pragma unroll
  for (int qs = 0; qs < 2; ++qs)
#pragma unroll
    for (int rg = 0; rg < 4; ++rg) {
      const float inv = 1.0f / li[qs][rg];
      const int row = q0 + qs * 16 + g * 4 + rg;
      const size_t base = (size_t)(b * SEQ + row) * DIMN + h * DHEAD;
#pragma unroll
      for (int ds = 0; ds < 4; ++ds)
        o[base + ds * 16 + r16] = f2bf(oacc[qs][ds][rg] * inv);
    }
}

extern "C" void kernel_launch(void* const* d_in, const int* in_sizes, int n_in,
                              void* d_out, int out_size, void* d_ws, size_t ws_size,
                              hipStream_t stream)
{
  const float* x   = (const float*)d_in[0];
  const float* ctx = (const float*)d_in[1];
  const float* Wq1 = (const float*)d_in[2];
  const float* Wk1 = (const float*)d_in[3];
  const float* Wv1 = (const float*)d_in[4];
  const float* Wo1 = (const float*)d_in[5];
  const float* bo1 = (const float*)d_in[6];
  const float* Wq2 = (const float*)d_in[7];
  const float* Wk2 = (const float*)d_in[8];
  const float* Wv2 = (const float*)d_in[9];
  const float* Wo2 = (const float*)d_in[10];
  const float* bo2 = (const float*)d_in[11];
  const float* Wp  = (const float*)d_in[12];
  const float* bp  = (const float*)d_in[13];
  const float* W2  = (const float*)d_in[14];
  const float* b2  = (const float*)d_in[15];
  const float* g1  = (const float*)d_in[16];
  const float* be1 = (const float*)d_in[17];
  const float* g2  = (const float*)d_in[18];
  const float* be2 = (const float*)d_in[19];
  const float* g3  = (const float*)d_in[20];
  const float* be3 = (const float*)d_in[21];

  char* ws = (char*)d_ws;
  size_t off = 0;
  auto alloc = [&](size_t bytes) -> void* {
    void* p = ws + off;
    off += (bytes + 255) & ~(size_t)255;
    return p;
  };

  u16* WqT1 = (u16*)alloc((size_t)1024 * 1024 * 2);   // contiguous with WkT1, WvT1
  u16* WkT1 = (u16*)alloc((size_t)1024 * 1024 * 2);
  u16* WvT1 = (u16*)alloc((size_t)1024 * 1024 * 2);
  u16* WoT1 = (u16*)alloc((size_t)1024 * 1024 * 2);
  u16* WqT2 = (u16*)alloc((size_t)1024 * 1024 * 2);
  u16* WkT2 = (u16*)alloc((size_t)1024 * 768 * 2);    // contiguous with WvT2
  u16* WvT2 = (u16*)alloc((size_t)1024 * 768 * 2);
  u16* WoT2 = (u16*)alloc((size_t)1024 * 1024 * 2);
  u16* WpT  = (u16*)alloc((size_t)8192 * 1024 * 2);
  u16* W2T  = (u16*)alloc((size_t)1024 * 4096 * 2);
  float* x1f = (float*)alloc((size_t)NTOK * DIMN * 4);
  float* x2f = (float*)alloc((size_t)NTOK * DIMN * 4);
  u16* ctxb = (u16*)alloc((size_t)CTOK * CTXD * 2);
  u16* k2b  = (u16*)alloc((size_t)CTOK * DIMN * 2);
  u16* vt2b = (u16*)alloc((size_t)2 * HEADS * DHEAD * 128 * 2);
  u16* hb   = (u16*)alloc((size_t)NTOK * DIMN * 2);
  u16* qb   = (u16*)alloc((size_t)NTOK * DIMN * 2);
  u16* kb   = (u16*)alloc((size_t)NTOK * DIMN * 2);
  u16* vtb  = (u16*)alloc((size_t)NTOK * DIMN * 2);
  u16* ab   = (u16*)alloc((size_t)NTOK * DIMN * 2);
  u16* ub   = qb; // reuse qb..ab region (32MB) for FF intermediate [4096][4096]

  dim3 blk(256);
  dim3 blk5(512);

  // batched weight conversions
  WBatch wb6;
  wb6.s[0] = Wq1; wb6.d[0] = WqT1;
  wb6.s[1] = Wk1; wb6.d[1] = WkT1;
  wb6.s[2] = Wv1; wb6.d[2] = WvT1;
  wb6.s[3] = Wo1; wb6.d[3] = WoT1;
  wb6.s[4] = Wq2; wb6.d[4] = WqT2;
  wb6.s[5] = Wo2; wb6.d[5] = WoT2;
  wconvB_k<6><<<dim3(16, 16, 6), blk, 0, stream>>>(wb6, 1024, 1024);
  WBatch wb2;
  wb2.s[0] = Wk2; wb2.d[0] = WkT2;
  wb2.s[1] = Wv2; wb2.d[1] = WvT2;
  wb2.s[2] = nullptr; wb2.d[2] = nullptr;
  wb2.s[3] = nullptr; wb2.d[3] = nullptr;
  wb2.s[4] = nullptr; wb2.d[4] = nullptr;
  wb2.s[5] = nullptr; wb2.d[5] = nullptr;
  wconvB_k<2><<<dim3(16, 12, 2), blk, 0, stream>>>(wb2, 768, 1024);
  wconv_k<<<dim3(128, 16), blk, 0, stream>>>(Wp, WpT, 1024, 8192);
  wconv_k<<<dim3(16, 64), blk, 0, stream>>>(W2, W2T, 4096, 1024);
  cconv_k<<<dim3((CTOK * CTXD + 255) / 256), blk, 0, stream>>>(ctx, ctxb, CTOK * CTXD);

  // ---- self attention block (QKV fused: WqT1/WkT1/WvT1 contiguous, N=3072)
  ln_k<<<NTOK, 256, 0, stream>>>(x, g1, be1, hb);
  gemm_k<4><<<dim3(32, 24), blk5, 0, stream>>>(hb, WqT1, NTOK, 3072, 1024, nullptr, nullptr, qb, nullptr, SEQ, SEQ, kb, vtb);
  attn_k<<<dim3(16, 32), blk, 0, stream>>>(qb, kb, vtb, ab, SEQ, SEQ, SEQ);
  gemm64_k<2><<<dim3(32, 8), blk5, 0, stream>>>(ab, WoT1, NTOK, 1024, 1024, bo1, x, nullptr, x1f);

  // ---- cross attention block (K2+V2 fused over ctx, N=2048)
  ln_k<<<NTOK, 256, 0, stream>>>(x1f, g2, be2, hb);
  gemm64_k<0><<<dim3(32, 8), blk5, 0, stream>>>(hb, WqT2, NTOK, 1024, 1024, nullptr, nullptr, qb, nullptr);
  gemm_k<5><<<dim3(2, 16), blk5, 0, stream>>>(ctxb, WkT2, CTOK, 2048, 768, nullptr, nullptr, k2b, nullptr, NCTX, 128, nullptr, vt2b);
  attn_k<<<dim3(16, 32), blk, 0, stream>>>(qb, k2b, vt2b, ab, NCTX, NCTX, 128);
  gemm64_k<2><<<dim3(32, 8), blk5, 0, stream>>>(ab, WoT2, NTOK, 1024, 1024, bo2, x1f, nullptr, x2f);

  // ---- GEGLU FF block
  ln_k<<<NTOK, 256, 0, stream>>>(x2f, g3, be3, hb);
  geglu_k<<<dim3(32, 32), blk5, 0, stream>>>(hb, WpT, WpT + (size_t)4096 * 1024, bp, bp + 4096, ub, NTOK, FFH);
  gemm64_k<2><<<dim3(32, 8), blk5, 0, stream>>>(ub, W2T, NTOK, 1024, 4096, b2, x2f, nullptr, (float*)d_out);

  (void)in_sizes; (void)n_in; (void)out_size; (void)ws_size;
}

// Round 11
// 401.015 us; speedup vs baseline: 1.1681x; 1.0090x over previous
//
#include <hip/hip_runtime.h>
#include <hip/hip_bf16.h>
#include <math.h>

#define DIMN   1024
#define HEADS  16
#define DHEAD  64
#define CTXD   768
#define FFH    4096
#define NTOK   4096
#define SEQ    2048
#define NCTX   77
#define CTOK   154

typedef unsigned short u16;
typedef __bf16 bf16x8 __attribute__((ext_vector_type(8)));
typedef float  f32x4  __attribute__((ext_vector_type(4)));

__device__ __forceinline__ u16 f2bf(float f) {
  union { float f; unsigned u; } c; c.f = f;
  unsigned r = c.u + 0x7FFFu + ((c.u >> 16) & 1u);
  return (u16)(r >> 16);
}
__device__ __forceinline__ float bf2f(u16 h) {
  union { unsigned u; float f; } c; c.u = ((unsigned)h) << 16; return c.f;
}

__device__ __forceinline__ void gload16(const void* g, void* l) {
  __builtin_amdgcn_global_load_lds(
      (__attribute__((address_space(1))) void*)(void*)(g),
      (__attribute__((address_space(3))) void*)(l), 16, 0, 0);
}

__device__ __forceinline__ f32x4 mfma16(bf16x8 a, bf16x8 b, f32x4 c) {
  return __builtin_amdgcn_mfma_f32_16x16x32_bf16(a, b, c, 0, 0, 0);
}

// ---------------- batched weight convert+transpose: W[K][N] f32 -> WT[N][K] bf16
struct WBatch { const float* s[6]; u16* d[6]; };

template<int NB>
__global__ __launch_bounds__(256)
void wconvB_k(WBatch wb, int K, int N)
{
  __shared__ u16 t[64][65];
  const float* __restrict__ W  = wb.s[blockIdx.z];
  u16* __restrict__       WT   = wb.d[blockIdx.z];
  int n0 = blockIdx.x * 64, k0 = blockIdx.y * 64;
  int tid = threadIdx.x;
  int rr = tid >> 4, cc = tid & 15;
#pragma unroll
  for (int i = 0; i < 4; ++i) {
    int kr = rr + i * 16;
    const float4 v = *(const float4*)&W[(size_t)(k0 + kr) * N + n0 + cc * 4];
    t[kr][cc*4+0] = f2bf(v.x); t[kr][cc*4+1] = f2bf(v.y);
    t[kr][cc*4+2] = f2bf(v.z); t[kr][cc*4+3] = f2bf(v.w);
  }
  __syncthreads();
#pragma unroll
  for (int i = 0; i < 4; ++i) {
    int nr = rr + i * 16;
    int r0 = cc * 4;
    ushort4 o;
    o.x = t[r0+0][nr]; o.y = t[r0+1][nr]; o.z = t[r0+2][nr]; o.w = t[r0+3][nr];
    *(ushort4*)&WT[(size_t)(n0 + nr) * K + k0 + r0] = o;
  }
}

__global__ __launch_bounds__(256)
void wconv_k(const float* __restrict__ W, u16* __restrict__ WT, int K, int N)
{
  __shared__ u16 t[64][65];
  int n0 = blockIdx.x * 64, k0 = blockIdx.y * 64;
  int tid = threadIdx.x;
  int rr = tid >> 4, cc = tid & 15;
#pragma unroll
  for (int i = 0; i < 4; ++i) {
    int kr = rr + i * 16;
    const float4 v = *(const float4*)&W[(size_t)(k0 + kr) * N + n0 + cc * 4];
    t[kr][cc*4+0] = f2bf(v.x); t[kr][cc*4+1] = f2bf(v.y);
    t[kr][cc*4+2] = f2bf(v.z); t[kr][cc*4+3] = f2bf(v.w);
  }
  __syncthreads();
#pragma unroll
  for (int i = 0; i < 4; ++i) {
    int nr = rr + i * 16;
    int r0 = cc * 4;
    ushort4 o;
    o.x = t[r0+0][nr]; o.y = t[r0+1][nr]; o.z = t[r0+2][nr]; o.w = t[r0+3][nr];
    *(ushort4*)&WT[(size_t)(n0 + nr) * K + k0 + r0] = o;
  }
}

// ---------------- f32 -> bf16 elementwise (context)
__global__ void cconv_k(const float* __restrict__ c, u16* __restrict__ o, int n)
{
  int i = blockIdx.x * 256 + threadIdx.x;
  if (i < n) o[i] = f2bf(c[i]);
}

// ---------------- LayerNorm: f32 row[1024] -> bf16
__global__ __launch_bounds__(256)
void ln_k(const float* __restrict__ x, const float* __restrict__ gm,
          const float* __restrict__ bt, u16* __restrict__ o)
{
  int row = blockIdx.x;
  int tid = threadIdx.x;
  const float4 v = *(const float4*)&x[(size_t)row * DIMN + tid * 4];
  float s = v.x + v.y + v.z + v.w;
  float q = v.x*v.x + v.y*v.y + v.z*v.z + v.w*v.w;
#pragma unroll
  for (int off = 32; off; off >>= 1) { s += __shfl_xor(s, off); q += __shfl_xor(q, off); }
  __shared__ float ss[4], qq[4];
  int wave = tid >> 6;
  if ((tid & 63) == 0) { ss[wave] = s; qq[wave] = q; }
  __syncthreads();
  s = ss[0] + ss[1] + ss[2] + ss[3];
  q = qq[0] + qq[1] + qq[2] + qq[3];
  float mu = s * (1.0f / DIMN);
  float var = q * (1.0f / DIMN) - mu * mu;
  float rs = rsqrtf(var + 1e-5f);
  const float4 gv = *(const float4*)&gm[tid * 4];
  const float4 bv = *(const float4*)&bt[tid * 4];
  ushort4 r;
  r.x = f2bf((v.x - mu) * rs * gv.x + bv.x);
  r.y = f2bf((v.y - mu) * rs * gv.y + bv.y);
  r.z = f2bf((v.z - mu) * rs * gv.z + bv.z);
  r.w = f2bf((v.w - mu) * rs * gv.w + bv.w);
  *(ushort4*)&o[(size_t)row * DIMN + tid * 4] = r;
}

// ---------------- LayerNorm: bf16 row[1024] -> bf16
__global__ __launch_bounds__(256)
void ln_b_k(const u16* __restrict__ x, const float* __restrict__ gm,
            const float* __restrict__ bt, u16* __restrict__ o)
{
  int row = blockIdx.x;
  int tid = threadIdx.x;
  const ushort4 u = *(const ushort4*)&x[(size_t)row * DIMN + tid * 4];
  float4 v;
  v.x = bf2f(u.x); v.y = bf2f(u.y); v.z = bf2f(u.z); v.w = bf2f(u.w);
  float s = v.x + v.y + v.z + v.w;
  float q = v.x*v.x + v.y*v.y + v.z*v.z + v.w*v.w;
#pragma unroll
  for (int off = 32; off; off >>= 1) { s += __shfl_xor(s, off); q += __shfl_xor(q, off); }
  __shared__ float ss[4], qq[4];
  int wave = tid >> 6;
  if ((tid & 63) == 0) { ss[wave] = s; qq[wave] = q; }
  __syncthreads();
  s = ss[0] + ss[1] + ss[2] + ss[3];
  q = qq[0] + qq[1] + qq[2] + qq[3];
  float mu = s * (1.0f / DIMN);
  float var = q * (1.0f / DIMN) - mu * mu;
  float rs = rsqrtf(var + 1e-5f);
  const float4 gv = *(const float4*)&gm[tid * 4];
  const float4 bv = *(const float4*)&bt[tid * 4];
  ushort4 r;
  r.x = f2bf((v.x - mu) * rs * gv.x + bv.x);
  r.y = f2bf((v.y - mu) * rs * gv.y + bv.y);
  r.z = f2bf((v.z - mu) * rs * gv.z + bv.z);
  r.w = f2bf((v.w - mu) * rs * gv.w + bv.w);
  *(ushort4*)&o[(size_t)row * DIMN + tid * 4] = r;
}

// ---------------- GEMM (R5-proven): 512 threads, 8 waves (32x64 wave tile), 2-buf counted vmcnt
// Used for QKV (MODE 4) and KV2 (MODE 5) where grid > 256 blocks.
template<int MODE>
__global__ __launch_bounds__(512, 4)
void gemm_k(const u16* __restrict__ A, const u16* __restrict__ Bt,
            int M, int N, int K,
            const float* __restrict__ bias, const float* __restrict__ resid,
            u16* __restrict__ obf, float* __restrict__ of32,
            int seq, int vstride,
            u16* __restrict__ ob2, u16* __restrict__ ob3)
{
  __shared__ __align__(16) u16 As[2][128 * 32];
  __shared__ __align__(16) u16 Bs[2][128 * 32];
  const int tid = threadIdx.x;
  const int lane = tid & 63, wave = tid >> 6;
  const int wr = wave >> 1, wc = wave & 1;          // 4 x 2 wave grid
  const int g = lane >> 4, r16 = lane & 15;
  const int m0 = blockIdx.x * 128, n0 = blockIdx.y * 128;

  f32x4 acc[2][4] = {};

  const int srow = tid >> 2;          // 0..127
  const int sch  = tid & 3;           // 0..3
  const int schs = sch ^ ((srow >> 1) & 3);
  const int arow = (m0 + srow > M - 1) ? (M - 1) : (m0 + srow);
  const size_t abase = (size_t)arow * K + schs * 8;
  const size_t bbase = (size_t)(n0 + srow) * K + schs * 8;

  auto stage = [&](int buf, int kt) {
    gload16(A  + abase + kt, &As[buf][tid * 8]);
    gload16(Bt + bbase + kt, &Bs[buf][tid * 8]);
  };

  stage(0, 0);

  const int nkt = K >> 5;
  for (int t = 0; t < nkt; ++t) {
    const int cur = t & 1;
    if (t + 1 < nkt) {
      stage(cur ^ 1, (t + 1) << 5);
      asm volatile("s_waitcnt vmcnt(2)" ::: "memory");   // stage(t) landed; t+1 in flight
    } else {
      asm volatile("s_waitcnt vmcnt(0)" ::: "memory");
    }
    __builtin_amdgcn_s_barrier();                        // B1

    bf16x8 af[2], bfr[4];
#pragma unroll
    for (int mi = 0; mi < 2; ++mi) {
      int r = wr * 32 + mi * 16 + r16;
      int cph = g ^ ((r >> 1) & 3);
      af[mi] = *(const bf16x8*)&As[cur][(r * 4 + cph) * 8];
    }
#pragma unroll
    for (int ni = 0; ni < 4; ++ni) {
      int r = wc * 64 + ni * 16 + r16;
      int cph = g ^ ((r >> 1) & 3);
      bfr[ni] = *(const bf16x8*)&Bs[cur][(r * 4 + cph) * 8];
    }
    __builtin_amdgcn_s_setprio(1);
#pragma unroll
    for (int mi = 0; mi < 2; ++mi)
#pragma unroll
      for (int ni = 0; ni < 4; ++ni)
        acc[mi][ni] = mfma16(af[mi], bfr[ni], acc[mi][ni]);
    __builtin_amdgcn_s_setprio(0);

    __builtin_amdgcn_s_barrier();                        // B2 (WAR)
  }

  const int grp = n0 >> 10;           // column group for fused modes
#pragma unroll
  for (int ni = 0; ni < 4; ++ni) {
    int col = n0 + wc * 64 + ni * 16 + r16;
    float bv = 0.0f;
    if constexpr (MODE == 0) bv = bias ? bias[col] : 0.0f;
    const int c1 = col & 1023;
#pragma unroll
    for (int mi = 0; mi < 2; ++mi) {
      f32x4 c = acc[mi][ni];
#pragma unroll
      for (int rg = 0; rg < 4; ++rg) {
        int row = m0 + wr * 32 + mi * 16 + g * 4 + rg;
        if (row < M) {
          float v = c[rg] + bv;
          if constexpr (MODE == 0) {
            obf[(size_t)row * N + col] = f2bf(v);
          } else if constexpr (MODE == 4) {
            if (grp == 0) {
              obf[(size_t)row * 1024 + c1] = f2bf(v);
            } else if (grp == 1) {
              ob2[(size_t)row * 1024 + c1] = f2bf(v);
            } else {
              int b = row / seq, srow_ = row - b * seq;
              int jg = srow_ >> 6, j = srow_ & 63;
              int pos = jg * 64 + ((j & 15) << 2) + (j >> 4);
              ob3[((size_t)b * HEADS * DHEAD + c1) * vstride + pos] = f2bf(v);
            }
          } else {  // MODE 5
            if (grp == 0) {
              obf[(size_t)row * 1024 + c1] = f2bf(v);
            } else {
              int b = row / seq, srow_ = row - b * seq;
              int jg = srow_ >> 6, j = srow_ & 63;
              int pos = jg * 64 + ((j & 15) << 2) + (j >> 4);
              ob3[((size_t)b * HEADS * DHEAD + c1) * vstride + pos] = f2bf(v);
            }
          }
        }
      }
    }
  }
}

// ---------------- GEMM BK=64 for grid<=256 launches.
// MODE 0: out bf16 = acc + bias (no resid)
// MODE 6: out bf16 = acc + bias + residf (f32 resid)
// MODE 7: out bf16 = acc + bias + residb (bf16 resid)
// MODE 8: out f32  = acc + bias + residb (bf16 resid)
template<int MODE>
__global__ __launch_bounds__(512, 2)
void gemm64_k(const u16* __restrict__ A, const u16* __restrict__ Bt,
              int M, int N, int K,
              const float* __restrict__ bias, const float* __restrict__ residf,
              const u16* __restrict__ residb,
              u16* __restrict__ obf, float* __restrict__ of32)
{
  __shared__ __align__(16) u16 As[2][128 * 64];   // 32 KB
  __shared__ __align__(16) u16 Bs[2][128 * 64];   // 32 KB
  const int tid = threadIdx.x;
  const int lane = tid & 63, wave = tid >> 6;
  const int wr = wave >> 1, wc = wave & 1;          // 4 x 2 wave grid, 32x64 tiles
  const int g = lane >> 4, r16 = lane & 15;
  const int m0 = blockIdx.x * 128, n0 = blockIdx.y * 128;

  f32x4 acc[2][4] = {};

  int aro[2], bro[2], scs[2];
#pragma unroll
  for (int i = 0; i < 2; ++i) {
    const int c = tid + i * 512;
    const int r = c >> 3, ch = c & 7;
    scs[i] = ch ^ (r & 7);
    aro[i] = (m0 + r > M - 1) ? (M - 1) : (m0 + r);
    bro[i] = n0 + r;
  }

  auto stage = [&](int buf, int kt) {
#pragma unroll
    for (int i = 0; i < 2; ++i) {
      const int c = tid + i * 512;
      gload16(A  + (size_t)aro[i] * K + kt + scs[i] * 8, &As[buf][c * 8]);
      gload16(Bt + (size_t)bro[i] * K + kt + scs[i] * 8, &Bs[buf][c * 8]);
    }
  };

  stage(0, 0);

  const int nkt = K >> 6;
  for (int t = 0; t < nkt; ++t) {
    const int cur = t & 1;
    if (t + 1 < nkt) {
      stage(cur ^ 1, (t + 1) << 6);
      asm volatile("s_waitcnt vmcnt(4)" ::: "memory");
    } else {
      asm volatile("s_waitcnt vmcnt(0)" ::: "memory");
    }
    __builtin_amdgcn_s_barrier();                        // B1

#pragma unroll
    for (int ks = 0; ks < 2; ++ks) {
      bf16x8 af[2], bfr[4];
#pragma unroll
      for (int mi = 0; mi < 2; ++mi) {
        int r = wr * 32 + mi * 16 + r16;
        int cph = (ks * 4 + g) ^ (r & 7);
        af[mi] = *(const bf16x8*)&As[cur][(r * 8 + cph) * 8];
      }
#pragma unroll
      for (int ni = 0; ni < 4; ++ni) {
        int r = wc * 64 + ni * 16 + r16;
        int cph = (ks * 4 + g) ^ (r & 7);
        bfr[ni] = *(const bf16x8*)&Bs[cur][(r * 8 + cph) * 8];
      }
      __builtin_amdgcn_s_setprio(1);
#pragma unroll
      for (int mi = 0; mi < 2; ++mi)
#pragma unroll
        for (int ni = 0; ni < 4; ++ni)
          acc[mi][ni] = mfma16(af[mi], bfr[ni], acc[mi][ni]);
      __builtin_amdgcn_s_setprio(0);
    }

    __builtin_amdgcn_s_barrier();                        // B2 (WAR)
  }

#pragma unroll
  for (int ni = 0; ni < 4; ++ni) {
    int col = n0 + wc * 64 + ni * 16 + r16;
    float bv = bias ? bias[col] : 0.0f;
#pragma unroll
    for (int mi = 0; mi < 2; ++mi) {
      f32x4 c = acc[mi][ni];
#pragma unroll
      for (int rg = 0; rg < 4; ++rg) {
        int row = m0 + wr * 32 + mi * 16 + g * 4 + rg;
        if (row < M) {
          float v = c[rg] + bv;
          size_t o = (size_t)row * N + col;
          if constexpr (MODE == 0) {
            obf[o] = f2bf(v);
          } else if constexpr (MODE == 6) {
            obf[o] = f2bf(v + residf[o]);
          } else if constexpr (MODE == 7) {
            obf[o] = f2bf(v + bf2f(residb[o]));
          } else {  // MODE 8
            of32[o] = v + bf2f(residb[o]);
          }
        }
      }
    }
  }
}

// ---------------- fused GEGLU GEMM (R5-proven): 512 thr, 128x128, 2-buf counted vmcnt
__global__ __launch_bounds__(512, 2)
void geglu_k(const u16* __restrict__ A, const u16* __restrict__ B1t,
             const u16* __restrict__ B2t,
             const float* __restrict__ ba, const float* __restrict__ bg,
             u16* __restrict__ out, int M, int N)
{
  __shared__ __align__(16) u16 As[2][128 * 32];
  __shared__ __align__(16) u16 B1s[2][128 * 32];
  __shared__ __align__(16) u16 B2s[2][128 * 32];
  const int tid = threadIdx.x;
  const int lane = tid & 63, wave = tid >> 6;
  const int wr = wave >> 1, wc = wave & 1;
  const int g = lane >> 4, r16 = lane & 15;
  const int m0 = blockIdx.x * 128, n0 = blockIdx.y * 128;
  const int K = 1024;

  f32x4 acca[2][4] = {}, accg[2][4] = {};

  const int srow = tid >> 2;
  const int sch  = tid & 3;
  const int schs = sch ^ ((srow >> 1) & 3);
  const size_t abase = (size_t)(m0 + srow) * K + schs * 8;
  const size_t bbase = (size_t)(n0 + srow) * K + schs * 8;

  auto stage = [&](int buf, int kt) {
    gload16(A   + abase + kt, &As[buf][tid * 8]);
    gload16(B1t + bbase + kt, &B1s[buf][tid * 8]);
    gload16(B2t + bbase + kt, &B2s[buf][tid * 8]);
  };

  stage(0, 0);

  const int nkt = K >> 5;
  for (int t = 0; t < nkt; ++t) {
    const int cur = t & 1;
    if (t + 1 < nkt) {
      stage(cur ^ 1, (t + 1) << 5);
      asm volatile("s_waitcnt vmcnt(3)" ::: "memory");
    } else {
      asm volatile("s_waitcnt vmcnt(0)" ::: "memory");
    }
    __builtin_amdgcn_s_barrier();                        // B1

    bf16x8 af[2], b1f[4], b2f[4];
#pragma unroll
    for (int mi = 0; mi < 2; ++mi) {
      int r = wr * 32 + mi * 16 + r16;
      int cph = g ^ ((r >> 1) & 3);
      af[mi] = *(const bf16x8*)&As[cur][(r * 4 + cph) * 8];
    }
#pragma unroll
    for (int ni = 0; ni < 4; ++ni) {
      int r = wc * 64 + ni * 16 + r16;
      int cph = g ^ ((r >> 1) & 3);
      b1f[ni] = *(const bf16x8*)&B1s[cur][(r * 4 + cph) * 8];
      b2f[ni] = *(const bf16x8*)&B2s[cur][(r * 4 + cph) * 8];
    }
    __builtin_amdgcn_s_setprio(1);
#pragma unroll
    for (int mi = 0; mi < 2; ++mi)
#pragma unroll
      for (int ni = 0; ni < 4; ++ni) {
        acca[mi][ni] = mfma16(af[mi], b1f[ni], acca[mi][ni]);
        accg[mi][ni] = mfma16(af[mi], b2f[ni], accg[mi][ni]);
      }
    __builtin_amdgcn_s_setprio(0);

    __builtin_amdgcn_s_barrier();                        // B2
  }

#pragma unroll
  for (int ni = 0; ni < 4; ++ni) {
    int col = n0 + wc * 64 + ni * 16 + r16;
    float bva = ba[col], bvg = bg[col];
#pragma unroll
    for (int mi = 0; mi < 2; ++mi) {
#pragma unroll
      for (int rg = 0; rg < 4; ++rg) {
        int row = m0 + wr * 32 + mi * 16 + g * 4 + rg;
        float a  = acca[mi][ni][rg] + bva;
        float gt = accg[mi][ni][rg] + bvg;
        float gl = 0.5f * gt * (1.0f + erff(gt * 0.70710678f));
        out[(size_t)row * N + col] = f2bf(a * gl);
      }
    }
  }
}

// ---------------- flash attention v5 (XCD-affine block swizzle; grid MUST be (16,32))
__global__ __launch_bounds__(256)
void attn_k(const u16* __restrict__ q, const u16* __restrict__ k,
            const u16* __restrict__ vt, u16* __restrict__ o,
            int kvlen, int seqk, int vstride)
{
  __shared__ __align__(16) u16 Ks[2][64 * 64];
  __shared__ __align__(16) u16 Vs[2][64 * 64];
  __shared__ __align__(16) u16 Ps[4][32 * 72];
  const int tid = threadIdx.x, lane = tid & 63, wave = tid >> 6;
  const int g = lane >> 4, r16 = lane & 15;

  // XCD-affine remap: hardware linear L = bx + by*16 dispatches round-robin
  // by XCD = L%8. Regroup so all 16 q-blocks of one (b,h) land on ONE XCD:
  // bijective for 512 blocks.
  const int L  = blockIdx.y * 16 + blockIdx.x;
  const int c8 = L & 7, tt = L >> 3;
  const int bx = tt & 15;
  const int bh = c8 + 8 * (tt >> 4);

  const int b = bh >> 4, h = bh & 15;
  const int q0 = bx * 128 + wave * 32;
  const float C = 0.18033688f;   // log2(e)/8

  bf16x8 aq[2][2];
#pragma unroll
  for (int qs = 0; qs < 2; ++qs) {
    const size_t qoff = (size_t)(b * SEQ + q0 + qs * 16 + r16) * DIMN + h * DHEAD;
#pragma unroll
    for (int kc = 0; kc < 2; ++kc)
      aq[qs][kc] = *(const bf16x8*)&q[qoff + kc * 32 + g * 8];
  }
  asm volatile("" :: "v"(aq[0][0]), "v"(aq[0][1]), "v"(aq[1][0]), "v"(aq[1][1]));

  f32x4 oacc[2][4] = {};
  float mi[2][4], li[2][4];
#pragma unroll
  for (int qs = 0; qs < 2; ++qs)
#pragma unroll
    for (int rg = 0; rg < 4; ++rg) { mi[qs][rg] = -3e38f; li[qs][rg] = 0.f; }

  const size_t vtbase = (size_t)(b * HEADS + h) * DHEAD * vstride;
  const size_t kbase  = (size_t)b * seqk * DIMN + h * DHEAD;
  const int nkv = (kvlen + 63) >> 6;

  auto stage = [&](int buf, int kv0) {
#pragma unroll
    for (int i = 0; i < 2; ++i) {
      const int c = tid + i * 256;
      const int row = c >> 3, ch = c & 7;
      const int chs = ch ^ (row & 7);
      int kr = kv0 + row; if (kr > kvlen - 1) kr = kvlen - 1;
      gload16(k + kbase + (size_t)kr * DIMN + chs * 8, &Ks[buf][c * 8]);
    }
#pragma unroll
    for (int i = 0; i < 2; ++i) {
      const int c = tid + i * 256;
      const int row = c >> 3, ch = c & 7;
      const int chs = ch ^ (row & 7);
      gload16(vt + vtbase + (size_t)row * vstride + kv0 + chs * 8, &Vs[buf][c * 8]);
    }
  };

  stage(0, 0);

  for (int kvb = 0; kvb < nkv; ++kvb) {
    const int kv0 = kvb * 64;
    const int cur = kvb & 1;
    if (kvb + 1 < nkv) {
      stage(cur ^ 1, kv0 + 64);
      asm volatile("s_waitcnt vmcnt(4)" ::: "memory");
    } else {
      asm volatile("s_waitcnt vmcnt(0)" ::: "memory");
    }
    __builtin_amdgcn_s_barrier();                        // B1

    // ---- QK^T: 16 MFMA
    f32x4 sa[2][4];
#pragma unroll
    for (int qs = 0; qs < 2; ++qs)
#pragma unroll
      for (int st = 0; st < 4; ++st) sa[qs][st] = (f32x4){0.f, 0.f, 0.f, 0.f};
    __builtin_amdgcn_s_setprio(1);
#pragma unroll
    for (int st = 0; st < 4; ++st) {
      const int kvr = st * 16 + r16;
#pragma unroll
      for (int kc = 0; kc < 2; ++kc) {
        const int chs = (kc * 4 + g) ^ (kvr & 7);
        const bf16x8 kf = *(const bf16x8*)&Ks[cur][kvr * 64 + chs * 8];
        sa[0][st] = mfma16(aq[0][kc], kf, sa[0][st]);
        sa[1][st] = mfma16(aq[1][kc], kf, sa[1][st]);
      }
    }
    __builtin_amdgcn_s_setprio(0);

    // ---- tail mask (cross-attn last tile only)
    if (kv0 + 64 > kvlen) {
#pragma unroll
      for (int st = 0; st < 4; ++st)
        if (kv0 + st * 16 + r16 >= kvlen) {
#pragma unroll
          for (int qs = 0; qs < 2; ++qs)
#pragma unroll
            for (int rg = 0; rg < 4; ++rg) sa[qs][st][rg] = -3e38f;
        }
    }

    // ---- defer-max check
    float bad = 0.f;
    float m4v[2][4];
#pragma unroll
    for (int qs = 0; qs < 2; ++qs)
#pragma unroll
      for (int rg = 0; rg < 4; ++rg) {
        float m4 = fmaxf(fmaxf(sa[qs][0][rg], sa[qs][1][rg]),
                         fmaxf(sa[qs][2][rg], sa[qs][3][rg]));
        m4v[qs][rg] = m4;
        bad = fmaxf(bad, m4 - mi[qs][rg]);
      }
    if (__any(bad > 16.0f)) {
#pragma unroll
      for (int qs = 0; qs < 2; ++qs)
#pragma unroll
        for (int rg = 0; rg < 4; ++rg) {
          float mx = m4v[qs][rg];
#pragma unroll
          for (int off = 1; off < 16; off <<= 1) mx = fmaxf(mx, __shfl_xor(mx, off));
          const float nm = fmaxf(mi[qs][rg], mx);
          const float corr = __builtin_amdgcn_exp2f((mi[qs][rg] - nm) * C);
          mi[qs][rg] = nm;
          li[qs][rg] *= corr;
#pragma unroll
          for (int ds = 0; ds < 4; ++ds) oacc[qs][ds][rg] *= corr;
        }
    }

    // ---- P = exp, lane-local li accumulate, packed bf16 store
#pragma unroll
    for (int qs = 0; qs < 2; ++qs) {
#pragma unroll
      for (int rg = 0; rg < 4; ++rg) {
        const float mc = mi[qs][rg] * C;
        const float p0 = __builtin_amdgcn_exp2f(__builtin_fmaf(sa[qs][0][rg], C, -mc));
        const float p1 = __builtin_amdgcn_exp2f(__builtin_fmaf(sa[qs][1][rg], C, -mc));
        const float p2 = __builtin_amdgcn_exp2f(__builtin_fmaf(sa[qs][2][rg], C, -mc));
        const float p3 = __builtin_amdgcn_exp2f(__builtin_fmaf(sa[qs][3][rg], C, -mc));
        li[qs][rg] += (p0 + p1) + (p2 + p3);
        unsigned lo, hi;
        asm("v_cvt_pk_bf16_f32 %0, %1, %2" : "=v"(lo) : "v"(p0), "v"(p1));
        asm("v_cvt_pk_bf16_f32 %0, %1, %2" : "=v"(hi) : "v"(p2), "v"(p3));
        const int prow = qs * 16 + g * 4 + rg;
        uint2 pk; pk.x = lo; pk.y = hi;
        *(uint2*)&Ps[wave][prow * 72 + r16 * 4] = pk;
      }
    }

    // ---- PV: 16 MFMA
    __builtin_amdgcn_s_setprio(1);
#pragma unroll
    for (int kc = 0; kc < 2; ++kc) {
      const bf16x8 pa0 = *(const bf16x8*)&Ps[wave][(r16)      * 72 + kc * 32 + g * 8];
      const bf16x8 pa1 = *(const bf16x8*)&Ps[wave][(16 + r16) * 72 + kc * 32 + g * 8];
#pragma unroll
      for (int ds = 0; ds < 4; ++ds) {
        const int dr = ds * 16 + r16;
        const int chs = (kc * 4 + g) ^ (dr & 7);
        const bf16x8 vf = *(const bf16x8*)&Vs[cur][dr * 64 + chs * 8];
        oacc[0][ds] = mfma16(pa0, vf, oacc[0][ds]);
        oacc[1][ds] = mfma16(pa1, vf, oacc[1][ds]);
      }
    }
    __builtin_amdgcn_s_setprio(0);

    __builtin_amdgcn_s_barrier();                        // B2
  }

#pragma unroll
  for (int qs = 0; qs < 2; ++qs)
#pragma unroll
    for (int rg = 0; rg < 4; ++rg) {
      float s = li[qs][rg];
#pragma unroll
      for (int off = 1; off < 16; off <<= 1) s += __shfl_xor(s, off);
      li[qs][rg] = s;
    }

#pragma unroll
  for (int qs = 0; qs < 2; ++qs)
#pragma unroll
    for (int rg = 0; rg < 4; ++rg) {
      const float inv = 1.0f / li[qs][rg];
      const int row = q0 + qs * 16 + g * 4 + rg;
      const size_t base = (size_t)(b * SEQ + row) * DIMN + h * DHEAD;
#pragma unroll
      for (int ds = 0; ds < 4; ++ds)
        o[base + ds * 16 + r16] = f2bf(oacc[qs][ds][rg] * inv);
    }
}

extern "C" void kernel_launch(void* const* d_in, const int* in_sizes, int n_in,
                              void* d_out, int out_size, void* d_ws, size_t ws_size,
                              hipStream_t stream)
{
  const float* x   = (const float*)d_in[0];
  const float* ctx = (const float*)d_in[1];
  const float* Wq1 = (const float*)d_in[2];
  const float* Wk1 = (const float*)d_in[3];
  const float* Wv1 = (const float*)d_in[4];
  const float* Wo1 = (const float*)d_in[5];
  const float* bo1 = (const float*)d_in[6];
  const float* Wq2 = (const float*)d_in[7];
  const float* Wk2 = (const float*)d_in[8];
  const float* Wv2 = (const float*)d_in[9];
  const float* Wo2 = (const float*)d_in[10];
  const float* bo2 = (const float*)d_in[11];
  const float* Wp  = (const float*)d_in[12];
  const float* bp  = (const float*)d_in[13];
  const float* W2  = (const float*)d_in[14];
  const float* b2  = (const float*)d_in[15];
  const float* g1  = (const float*)d_in[16];
  const float* be1 = (const float*)d_in[17];
  const float* g2  = (const float*)d_in[18];
  const float* be2 = (const float*)d_in[19];
  const float* g3  = (const float*)d_in[20];
  const float* be3 = (const float*)d_in[21];

  char* ws = (char*)d_ws;
  size_t off = 0;
  auto alloc = [&](size_t bytes) -> void* {
    void* p = ws + off;
    off += (bytes + 255) & ~(size_t)255;
    return p;
  };

  u16* WqT1 = (u16*)alloc((size_t)1024 * 1024 * 2);   // contiguous with WkT1, WvT1
  u16* WkT1 = (u16*)alloc((size_t)1024 * 1024 * 2);
  u16* WvT1 = (u16*)alloc((size_t)1024 * 1024 * 2);
  u16* WoT1 = (u16*)alloc((size_t)1024 * 1024 * 2);
  u16* WqT2 = (u16*)alloc((size_t)1024 * 1024 * 2);
  u16* WkT2 = (u16*)alloc((size_t)1024 * 768 * 2);    // contiguous with WvT2
  u16* WvT2 = (u16*)alloc((size_t)1024 * 768 * 2);
  u16* WoT2 = (u16*)alloc((size_t)1024 * 1024 * 2);
  u16* WpT  = (u16*)alloc((size_t)8192 * 1024 * 2);
  u16* W2T  = (u16*)alloc((size_t)1024 * 4096 * 2);
  u16* x1b  = (u16*)alloc((size_t)NTOK * DIMN * 2);
  u16* x2b  = (u16*)alloc((size_t)NTOK * DIMN * 2);
  u16* ctxb = (u16*)alloc((size_t)CTOK * CTXD * 2);
  u16* k2b  = (u16*)alloc((size_t)CTOK * DIMN * 2);
  u16* vt2b = (u16*)alloc((size_t)2 * HEADS * DHEAD * 128 * 2);
  u16* hb   = (u16*)alloc((size_t)NTOK * DIMN * 2);
  u16* qb   = (u16*)alloc((size_t)NTOK * DIMN * 2);
  u16* kb   = (u16*)alloc((size_t)NTOK * DIMN * 2);
  u16* vtb  = (u16*)alloc((size_t)NTOK * DIMN * 2);
  u16* ab   = (u16*)alloc((size_t)NTOK * DIMN * 2);
  u16* ub   = qb; // reuse qb..ab region (32MB) for FF intermediate [4096][4096]

  dim3 blk(256);
  dim3 blk5(512);

  // batched weight conversions
  WBatch wb6;
  wb6.s[0] = Wq1; wb6.d[0] = WqT1;
  wb6.s[1] = Wk1; wb6.d[1] = WkT1;
  wb6.s[2] = Wv1; wb6.d[2] = WvT1;
  wb6.s[3] = Wo1; wb6.d[3] = WoT1;
  wb6.s[4] = Wq2; wb6.d[4] = WqT2;
  wb6.s[5] = Wo2; wb6.d[5] = WoT2;
  wconvB_k<6><<<dim3(16, 16, 6), blk, 0, stream>>>(wb6, 1024, 1024);
  WBatch wb2;
  wb2.s[0] = Wk2; wb2.d[0] = WkT2;
  wb2.s[1] = Wv2; wb2.d[1] = WvT2;
  wb2.s[2] = nullptr; wb2.d[2] = nullptr;
  wb2.s[3] = nullptr; wb2.d[3] = nullptr;
  wb2.s[4] = nullptr; wb2.d[4] = nullptr;
  wb2.s[5] = nullptr; wb2.d[5] = nullptr;
  wconvB_k<2><<<dim3(16, 12, 2), blk, 0, stream>>>(wb2, 768, 1024);
  wconv_k<<<dim3(128, 16), blk, 0, stream>>>(Wp, WpT, 1024, 8192);
  wconv_k<<<dim3(16, 64), blk, 0, stream>>>(W2, W2T, 4096, 1024);
  cconv_k<<<dim3((CTOK * CTXD + 255) / 256), blk, 0, stream>>>(ctx, ctxb, CTOK * CTXD);

  // ---- self attention block (QKV fused: WqT1/WkT1/WvT1 contiguous, N=3072)
  ln_k<<<NTOK, 256, 0, stream>>>(x, g1, be1, hb);
  gemm_k<4><<<dim3(32, 24), blk5, 0, stream>>>(hb, WqT1, NTOK, 3072, 1024, nullptr, nullptr, qb, nullptr, SEQ, SEQ, kb, vtb);
  attn_k<<<dim3(16, 32), blk, 0, stream>>>(qb, kb, vtb, ab, SEQ, SEQ, SEQ);
  gemm64_k<6><<<dim3(32, 8), blk5, 0, stream>>>(ab, WoT1, NTOK, 1024, 1024, bo1, x, nullptr, x1b, nullptr);

  // ---- cross attention block (K2+V2 fused over ctx, N=2048)
  ln_b_k<<<NTOK, 256, 0, stream>>>(x1b, g2, be2, hb);
  gemm64_k<0><<<dim3(32, 8), blk5, 0, stream>>>(hb, WqT2, NTOK, 1024, 1024, nullptr, nullptr, nullptr, qb, nullptr);
  gemm_k<5><<<dim3(2, 16), blk5, 0, stream>>>(ctxb, WkT2, CTOK, 2048, 768, nullptr, nullptr, k2b, nullptr, NCTX, 128, nullptr, vt2b);
  attn_k<<<dim3(16, 32), blk, 0, stream>>>(qb, k2b, vt2b, ab, NCTX, NCTX, 128);
  gemm64_k<7><<<dim3(32, 8), blk5, 0, stream>>>(ab, WoT2, NTOK, 1024, 1024, bo2, nullptr, x1b, x2b, nullptr);

  // ---- GEGLU FF block
  ln_b_k<<<NTOK, 256, 0, stream>>>(x2b, g3, be3, hb);
  geglu_k<<<dim3(32, 32), blk5, 0, stream>>>(hb, WpT, WpT + (size_t)4096 * 1024, bp, bp + 4096, ub, NTOK, FFH);
  gemm64_k<8><<<dim3(32, 8), blk5, 0, stream>>>(ub, W2T, NTOK, 1024, 4096, b2, nullptr, x2b, nullptr, (float*)d_out);

  (void)in_sizes; (void)n_in; (void)out_size; (void)ws_size;
}

// Round 12
// 389.955 us; speedup vs baseline: 1.2012x; 1.0284x over previous
//
#include <hip/hip_runtime.h>
#include <hip/hip_bf16.h>
#include <math.h>

#define DIMN   1024
#define HEADS  16
#define DHEAD  64
#define CTXD   768
#define FFH    4096
#define NTOK   4096
#define SEQ    2048
#define NCTX   77
#define CTOK   154

typedef unsigned short u16;
typedef __bf16 bf16x8 __attribute__((ext_vector_type(8)));
typedef float  f32x4  __attribute__((ext_vector_type(4)));

__device__ __forceinline__ u16 f2bf(float f) {
  union { float f; unsigned u; } c; c.f = f;
  unsigned r = c.u + 0x7FFFu + ((c.u >> 16) & 1u);
  return (u16)(r >> 16);
}
__device__ __forceinline__ float bf2f(u16 h) {
  union { unsigned u; float f; } c; c.u = ((unsigned)h) << 16; return c.f;
}

__device__ __forceinline__ void gload16(const void* g, void* l) {
  __builtin_amdgcn_global_load_lds(
      (__attribute__((address_space(1))) void*)(void*)(g),
      (__attribute__((address_space(3))) void*)(l), 16, 0, 0);
}

__device__ __forceinline__ f32x4 mfma16(bf16x8 a, bf16x8 b, f32x4 c) {
  return __builtin_amdgcn_mfma_f32_16x16x32_bf16(a, b, c, 0, 0, 0);
}

// ---------------- batched weight convert+transpose: W[K][N] f32 -> WT[N][K] bf16
struct WBatch { const float* s[6]; u16* d[6]; };

template<int NB>
__global__ __launch_bounds__(256)
void wconvB_k(WBatch wb, int K, int N)
{
  __shared__ u16 t[64][65];
  const float* __restrict__ W  = wb.s[blockIdx.z];
  u16* __restrict__       WT   = wb.d[blockIdx.z];
  int n0 = blockIdx.x * 64, k0 = blockIdx.y * 64;
  int tid = threadIdx.x;
  int rr = tid >> 4, cc = tid & 15;
#pragma unroll
  for (int i = 0; i < 4; ++i) {
    int kr = rr + i * 16;
    const float4 v = *(const float4*)&W[(size_t)(k0 + kr) * N + n0 + cc * 4];
    t[kr][cc*4+0] = f2bf(v.x); t[kr][cc*4+1] = f2bf(v.y);
    t[kr][cc*4+2] = f2bf(v.z); t[kr][cc*4+3] = f2bf(v.w);
  }
  __syncthreads();
#pragma unroll
  for (int i = 0; i < 4; ++i) {
    int nr = rr + i * 16;
    int r0 = cc * 4;
    ushort4 o;
    o.x = t[r0+0][nr]; o.y = t[r0+1][nr]; o.z = t[r0+2][nr]; o.w = t[r0+3][nr];
    *(ushort4*)&WT[(size_t)(n0 + nr) * K + k0 + r0] = o;
  }
}

__global__ __launch_bounds__(256)
void wconv_k(const float* __restrict__ W, u16* __restrict__ WT, int K, int N)
{
  __shared__ u16 t[64][65];
  int n0 = blockIdx.x * 64, k0 = blockIdx.y * 64;
  int tid = threadIdx.x;
  int rr = tid >> 4, cc = tid & 15;
#pragma unroll
  for (int i = 0; i < 4; ++i) {
    int kr = rr + i * 16;
    const float4 v = *(const float4*)&W[(size_t)(k0 + kr) * N + n0 + cc * 4];
    t[kr][cc*4+0] = f2bf(v.x); t[kr][cc*4+1] = f2bf(v.y);
    t[kr][cc*4+2] = f2bf(v.z); t[kr][cc*4+3] = f2bf(v.w);
  }
  __syncthreads();
#pragma unroll
  for (int i = 0; i < 4; ++i) {
    int nr = rr + i * 16;
    int r0 = cc * 4;
    ushort4 o;
    o.x = t[r0+0][nr]; o.y = t[r0+1][nr]; o.z = t[r0+2][nr]; o.w = t[r0+3][nr];
    *(ushort4*)&WT[(size_t)(n0 + nr) * K + k0 + r0] = o;
  }
}

// ---------------- f32 -> bf16 elementwise (context)
__global__ void cconv_k(const float* __restrict__ c, u16* __restrict__ o, int n)
{
  int i = blockIdx.x * 256 + threadIdx.x;
  if (i < n) o[i] = f2bf(c[i]);
}

// ---------------- LayerNorm: f32 row[1024] -> bf16
__global__ __launch_bounds__(256)
void ln_k(const float* __restrict__ x, const float* __restrict__ gm,
          const float* __restrict__ bt, u16* __restrict__ o)
{
  int row = blockIdx.x;
  int tid = threadIdx.x;
  const float4 v = *(const float4*)&x[(size_t)row * DIMN + tid * 4];
  float s = v.x + v.y + v.z + v.w;
  float q = v.x*v.x + v.y*v.y + v.z*v.z + v.w*v.w;
#pragma unroll
  for (int off = 32; off; off >>= 1) { s += __shfl_xor(s, off); q += __shfl_xor(q, off); }
  __shared__ float ss[4], qq[4];
  int wave = tid >> 6;
  if ((tid & 63) == 0) { ss[wave] = s; qq[wave] = q; }
  __syncthreads();
  s = ss[0] + ss[1] + ss[2] + ss[3];
  q = qq[0] + qq[1] + qq[2] + qq[3];
  float mu = s * (1.0f / DIMN);
  float var = q * (1.0f / DIMN) - mu * mu;
  float rs = rsqrtf(var + 1e-5f);
  const float4 gv = *(const float4*)&gm[tid * 4];
  const float4 bv = *(const float4*)&bt[tid * 4];
  ushort4 r;
  r.x = f2bf((v.x - mu) * rs * gv.x + bv.x);
  r.y = f2bf((v.y - mu) * rs * gv.y + bv.y);
  r.z = f2bf((v.z - mu) * rs * gv.z + bv.z);
  r.w = f2bf((v.w - mu) * rs * gv.w + bv.w);
  *(ushort4*)&o[(size_t)row * DIMN + tid * 4] = r;
}

// ---------------- LayerNorm: bf16 row[1024] -> bf16
__global__ __launch_bounds__(256)
void ln_b_k(const u16* __restrict__ x, const float* __restrict__ gm,
            const float* __restrict__ bt, u16* __restrict__ o)
{
  int row = blockIdx.x;
  int tid = threadIdx.x;
  const ushort4 u = *(const ushort4*)&x[(size_t)row * DIMN + tid * 4];
  float4 v;
  v.x = bf2f(u.x); v.y = bf2f(u.y); v.z = bf2f(u.z); v.w = bf2f(u.w);
  float s = v.x + v.y + v.z + v.w;
  float q = v.x*v.x + v.y*v.y + v.z*v.z + v.w*v.w;
#pragma unroll
  for (int off = 32; off; off >>= 1) { s += __shfl_xor(s, off); q += __shfl_xor(q, off); }
  __shared__ float ss[4], qq[4];
  int wave = tid >> 6;
  if ((tid & 63) == 0) { ss[wave] = s; qq[wave] = q; }
  __syncthreads();
  s = ss[0] + ss[1] + ss[2] + ss[3];
  q = qq[0] + qq[1] + qq[2] + qq[3];
  float mu = s * (1.0f / DIMN);
  float var = q * (1.0f / DIMN) - mu * mu;
  float rs = rsqrtf(var + 1e-5f);
  const float4 gv = *(const float4*)&gm[tid * 4];
  const float4 bv = *(const float4*)&bt[tid * 4];
  ushort4 r;
  r.x = f2bf((v.x - mu) * rs * gv.x + bv.x);
  r.y = f2bf((v.y - mu) * rs * gv.y + bv.y);
  r.z = f2bf((v.z - mu) * rs * gv.z + bv.z);
  r.w = f2bf((v.w - mu) * rs * gv.w + bv.w);
  *(ushort4*)&o[(size_t)row * DIMN + tid * 4] = r;
}

// ---------------- GEMM (R5-proven): 512 threads, 8 waves (32x64 wave tile), 2-buf counted vmcnt
template<int MODE>
__global__ __launch_bounds__(512, 4)
void gemm_k(const u16* __restrict__ A, const u16* __restrict__ Bt,
            int M, int N, int K,
            const float* __restrict__ bias, const float* __restrict__ resid,
            u16* __restrict__ obf, float* __restrict__ of32,
            int seq, int vstride,
            u16* __restrict__ ob2, u16* __restrict__ ob3)
{
  __shared__ __align__(16) u16 As[2][128 * 32];
  __shared__ __align__(16) u16 Bs[2][128 * 32];
  const int tid = threadIdx.x;
  const int lane = tid & 63, wave = tid >> 6;
  const int wr = wave >> 1, wc = wave & 1;          // 4 x 2 wave grid
  const int g = lane >> 4, r16 = lane & 15;
  const int m0 = blockIdx.x * 128, n0 = blockIdx.y * 128;

  f32x4 acc[2][4] = {};

  const int srow = tid >> 2;          // 0..127
  const int sch  = tid & 3;           // 0..3
  const int schs = sch ^ ((srow >> 1) & 3);
  const int arow = (m0 + srow > M - 1) ? (M - 1) : (m0 + srow);
  const size_t abase = (size_t)arow * K + schs * 8;
  const size_t bbase = (size_t)(n0 + srow) * K + schs * 8;

  auto stage = [&](int buf, int kt) {
    gload16(A  + abase + kt, &As[buf][tid * 8]);
    gload16(Bt + bbase + kt, &Bs[buf][tid * 8]);
  };

  stage(0, 0);

  const int nkt = K >> 5;
  for (int t = 0; t < nkt; ++t) {
    const int cur = t & 1;
    if (t + 1 < nkt) {
      stage(cur ^ 1, (t + 1) << 5);
      asm volatile("s_waitcnt vmcnt(2)" ::: "memory");   // stage(t) landed; t+1 in flight
    } else {
      asm volatile("s_waitcnt vmcnt(0)" ::: "memory");
    }
    __builtin_amdgcn_s_barrier();                        // B1

    bf16x8 af[2], bfr[4];
#pragma unroll
    for (int mi = 0; mi < 2; ++mi) {
      int r = wr * 32 + mi * 16 + r16;
      int cph = g ^ ((r >> 1) & 3);
      af[mi] = *(const bf16x8*)&As[cur][(r * 4 + cph) * 8];
    }
#pragma unroll
    for (int ni = 0; ni < 4; ++ni) {
      int r = wc * 64 + ni * 16 + r16;
      int cph = g ^ ((r >> 1) & 3);
      bfr[ni] = *(const bf16x8*)&Bs[cur][(r * 4 + cph) * 8];
    }
    __builtin_amdgcn_s_setprio(1);
#pragma unroll
    for (int mi = 0; mi < 2; ++mi)
#pragma unroll
      for (int ni = 0; ni < 4; ++ni)
        acc[mi][ni] = mfma16(af[mi], bfr[ni], acc[mi][ni]);
    __builtin_amdgcn_s_setprio(0);

    __builtin_amdgcn_s_barrier();                        // B2 (WAR)
  }

  const int grp = n0 >> 10;           // column group for fused modes
#pragma unroll
  for (int ni = 0; ni < 4; ++ni) {
    int col = n0 + wc * 64 + ni * 16 + r16;
    float bv = 0.0f;
    if constexpr (MODE == 0) bv = bias ? bias[col] : 0.0f;
    const int c1 = col & 1023;
#pragma unroll
    for (int mi = 0; mi < 2; ++mi) {
      f32x4 c = acc[mi][ni];
#pragma unroll
      for (int rg = 0; rg < 4; ++rg) {
        int row = m0 + wr * 32 + mi * 16 + g * 4 + rg;
        if (row < M) {
          float v = c[rg] + bv;
          if constexpr (MODE == 0) {
            obf[(size_t)row * N + col] = f2bf(v);
          } else if constexpr (MODE == 4) {
            if (grp == 0) {
              obf[(size_t)row * 1024 + c1] = f2bf(v);
            } else if (grp == 1) {
              ob2[(size_t)row * 1024 + c1] = f2bf(v);
            } else {
              int b = row / seq, srow_ = row - b * seq;
              int jg = srow_ >> 6, j = srow_ & 63;
              int pos = jg * 64 + ((j & 15) << 2) + (j >> 4);
              ob3[((size_t)b * HEADS * DHEAD + c1) * vstride + pos] = f2bf(v);
            }
          } else {  // MODE 5
            if (grp == 0) {
              obf[(size_t)row * 1024 + c1] = f2bf(v);
            } else {
              int b = row / seq, srow_ = row - b * seq;
              int jg = srow_ >> 6, j = srow_ & 63;
              int pos = jg * 64 + ((j & 15) << 2) + (j >> 4);
              ob3[((size_t)b * HEADS * DHEAD + c1) * vstride + pos] = f2bf(v);
            }
          }
        }
      }
    }
  }
}

// ---------------- GEMM BK=64 for grid<=256 launches.
// MODE 0: out bf16 = acc + bias (no resid)
// MODE 6: out bf16 = acc + bias + residf (f32 resid)
// MODE 7: out bf16 = acc + bias + residb (bf16 resid)
// MODE 8: out f32  = acc + bias + residb (bf16 resid)
template<int MODE>
__global__ __launch_bounds__(512, 2)
void gemm64_k(const u16* __restrict__ A, const u16* __restrict__ Bt,
              int M, int N, int K,
              const float* __restrict__ bias, const float* __restrict__ residf,
              const u16* __restrict__ residb,
              u16* __restrict__ obf, float* __restrict__ of32)
{
  __shared__ __align__(16) u16 As[2][128 * 64];   // 32 KB
  __shared__ __align__(16) u16 Bs[2][128 * 64];   // 32 KB
  const int tid = threadIdx.x;
  const int lane = tid & 63, wave = tid >> 6;
  const int wr = wave >> 1, wc = wave & 1;          // 4 x 2 wave grid, 32x64 tiles
  const int g = lane >> 4, r16 = lane & 15;
  const int m0 = blockIdx.x * 128, n0 = blockIdx.y * 128;

  f32x4 acc[2][4] = {};

  int aro[2], bro[2], scs[2];
#pragma unroll
  for (int i = 0; i < 2; ++i) {
    const int c = tid + i * 512;
    const int r = c >> 3, ch = c & 7;
    scs[i] = ch ^ (r & 7);
    aro[i] = (m0 + r > M - 1) ? (M - 1) : (m0 + r);
    bro[i] = n0 + r;
  }

  auto stage = [&](int buf, int kt) {
#pragma unroll
    for (int i = 0; i < 2; ++i) {
      const int c = tid + i * 512;
      gload16(A  + (size_t)aro[i] * K + kt + scs[i] * 8, &As[buf][c * 8]);
      gload16(Bt + (size_t)bro[i] * K + kt + scs[i] * 8, &Bs[buf][c * 8]);
    }
  };

  stage(0, 0);

  const int nkt = K >> 6;
  for (int t = 0; t < nkt; ++t) {
    const int cur = t & 1;
    if (t + 1 < nkt) {
      stage(cur ^ 1, (t + 1) << 6);
      asm volatile("s_waitcnt vmcnt(4)" ::: "memory");
    } else {
      asm volatile("s_waitcnt vmcnt(0)" ::: "memory");
    }
    __builtin_amdgcn_s_barrier();                        // B1

#pragma unroll
    for (int ks = 0; ks < 2; ++ks) {
      bf16x8 af[2], bfr[4];
#pragma unroll
      for (int mi = 0; mi < 2; ++mi) {
        int r = wr * 32 + mi * 16 + r16;
        int cph = (ks * 4 + g) ^ (r & 7);
        af[mi] = *(const bf16x8*)&As[cur][(r * 8 + cph) * 8];
      }
#pragma unroll
      for (int ni = 0; ni < 4; ++ni) {
        int r = wc * 64 + ni * 16 + r16;
        int cph = (ks * 4 + g) ^ (r & 7);
        bfr[ni] = *(const bf16x8*)&Bs[cur][(r * 8 + cph) * 8];
      }
      __builtin_amdgcn_s_setprio(1);
#pragma unroll
      for (int mi = 0; mi < 2; ++mi)
#pragma unroll
        for (int ni = 0; ni < 4; ++ni)
          acc[mi][ni] = mfma16(af[mi], bfr[ni], acc[mi][ni]);
      __builtin_amdgcn_s_setprio(0);
    }

    __builtin_amdgcn_s_barrier();                        // B2 (WAR)
  }

#pragma unroll
  for (int ni = 0; ni < 4; ++ni) {
    int col = n0 + wc * 64 + ni * 16 + r16;
    float bv = bias ? bias[col] : 0.0f;
#pragma unroll
    for (int mi = 0; mi < 2; ++mi) {
      f32x4 c = acc[mi][ni];
#pragma unroll
      for (int rg = 0; rg < 4; ++rg) {
        int row = m0 + wr * 32 + mi * 16 + g * 4 + rg;
        if (row < M) {
          float v = c[rg] + bv;
          size_t o = (size_t)row * N + col;
          if constexpr (MODE == 0) {
            obf[o] = f2bf(v);
          } else if constexpr (MODE == 6) {
            obf[o] = f2bf(v + residf[o]);
          } else if constexpr (MODE == 7) {
            obf[o] = f2bf(v + bf2f(residb[o]));
          } else {  // MODE 8
            of32[o] = v + bf2f(residb[o]);
          }
        }
      }
    }
  }
}

// ---------------- fused GEGLU GEMM (R5-proven): 512 thr, 128x128, 2-buf counted vmcnt
__global__ __launch_bounds__(512, 2)
void geglu_k(const u16* __restrict__ A, const u16* __restrict__ B1t,
             const u16* __restrict__ B2t,
             const float* __restrict__ ba, const float* __restrict__ bg,
             u16* __restrict__ out, int M, int N)
{
  __shared__ __align__(16) u16 As[2][128 * 32];
  __shared__ __align__(16) u16 B1s[2][128 * 32];
  __shared__ __align__(16) u16 B2s[2][128 * 32];
  const int tid = threadIdx.x;
  const int lane = tid & 63, wave = tid >> 6;
  const int wr = wave >> 1, wc = wave & 1;
  const int g = lane >> 4, r16 = lane & 15;
  const int m0 = blockIdx.x * 128, n0 = blockIdx.y * 128;
  const int K = 1024;

  f32x4 acca[2][4] = {}, accg[2][4] = {};

  const int srow = tid >> 2;
  const int sch  = tid & 3;
  const int schs = sch ^ ((srow >> 1) & 3);
  const size_t abase = (size_t)(m0 + srow) * K + schs * 8;
  const size_t bbase = (size_t)(n0 + srow) * K + schs * 8;

  auto stage = [&](int buf, int kt) {
    gload16(A   + abase + kt, &As[buf][tid * 8]);
    gload16(B1t + bbase + kt, &B1s[buf][tid * 8]);
    gload16(B2t + bbase + kt, &B2s[buf][tid * 8]);
  };

  stage(0, 0);

  const int nkt = K >> 5;
  for (int t = 0; t < nkt; ++t) {
    const int cur = t & 1;
    if (t + 1 < nkt) {
      stage(cur ^ 1, (t + 1) << 5);
      asm volatile("s_waitcnt vmcnt(3)" ::: "memory");
    } else {
      asm volatile("s_waitcnt vmcnt(0)" ::: "memory");
    }
    __builtin_amdgcn_s_barrier();                        // B1

    bf16x8 af[2], b1f[4], b2f[4];
#pragma unroll
    for (int mi = 0; mi < 2; ++mi) {
      int r = wr * 32 + mi * 16 + r16;
      int cph = g ^ ((r >> 1) & 3);
      af[mi] = *(const bf16x8*)&As[cur][(r * 4 + cph) * 8];
    }
#pragma unroll
    for (int ni = 0; ni < 4; ++ni) {
      int r = wc * 64 + ni * 16 + r16;
      int cph = g ^ ((r >> 1) & 3);
      b1f[ni] = *(const bf16x8*)&B1s[cur][(r * 4 + cph) * 8];
      b2f[ni] = *(const bf16x8*)&B2s[cur][(r * 4 + cph) * 8];
    }
    __builtin_amdgcn_s_setprio(1);
#pragma unroll
    for (int mi = 0; mi < 2; ++mi)
#pragma unroll
      for (int ni = 0; ni < 4; ++ni) {
        acca[mi][ni] = mfma16(af[mi], b1f[ni], acca[mi][ni]);
        accg[mi][ni] = mfma16(af[mi], b2f[ni], accg[mi][ni]);
      }
    __builtin_amdgcn_s_setprio(0);

    __builtin_amdgcn_s_barrier();                        // B2
  }

#pragma unroll
  for (int ni = 0; ni < 4; ++ni) {
    int col = n0 + wc * 64 + ni * 16 + r16;
    float bva = ba[col], bvg = bg[col];
#pragma unroll
    for (int mi = 0; mi < 2; ++mi) {
#pragma unroll
      for (int rg = 0; rg < 4; ++rg) {
        int row = m0 + wr * 32 + mi * 16 + g * 4 + rg;
        float a  = acca[mi][ni][rg] + bva;
        float gt = accg[mi][ni][rg] + bvg;
        float gl = 0.5f * gt * (1.0f + erff(gt * 0.70710678f));
        out[(size_t)row * N + col] = f2bf(a * gl);
      }
    }
  }
}

// ---------------- flash attention v6: 8 waves (256 q/block), KVBLK=128, XCD-affine
// grid MUST be (8, 32)
__global__ __launch_bounds__(512, 1)
void attn_k(const u16* __restrict__ q, const u16* __restrict__ k,
            const u16* __restrict__ vt, u16* __restrict__ o,
            int kvlen, int seqk, int vstride)
{
  __shared__ __align__(16) u16 Ks[2][128 * 64];   // [kv][d], chunk-swizzled (8/row)
  __shared__ __align__(16) u16 Vs[2][64 * 128];   // [d][kv], chunk-swizzled (16/row)
  __shared__ __align__(16) u16 Ps[8][32 * 136];   // per-wave P, 2 granules of 64
  const int tid = threadIdx.x, lane = tid & 63, wave = tid >> 6;
  const int g = lane >> 4, r16 = lane & 15;

  // XCD-affine remap: L%8 = XCD. Each XCD c owns heads 4c..4c+3 fully.
  const int L  = blockIdx.y * 8 + blockIdx.x;
  const int c8 = L & 7, tt = L >> 3;
  const int bx = tt & 7;
  const int bh = c8 * 4 + (tt >> 3);

  const int b = bh >> 4, h = bh & 15;
  const int q0 = bx * 256 + wave * 32;
  const float C = 0.18033688f;   // log2(e)/8

  bf16x8 aq[2][2];
#pragma unroll
  for (int qs = 0; qs < 2; ++qs) {
    const size_t qoff = (size_t)(b * SEQ + q0 + qs * 16 + r16) * DIMN + h * DHEAD;
#pragma unroll
    for (int kc = 0; kc < 2; ++kc)
      aq[qs][kc] = *(const bf16x8*)&q[qoff + kc * 32 + g * 8];
  }
  asm volatile("" :: "v"(aq[0][0]), "v"(aq[0][1]), "v"(aq[1][0]), "v"(aq[1][1]));

  f32x4 oacc[2][4] = {};
  float mi[2][4], li[2][4];
#pragma unroll
  for (int qs = 0; qs < 2; ++qs)
#pragma unroll
    for (int rg = 0; rg < 4; ++rg) { mi[qs][rg] = -3e38f; li[qs][rg] = 0.f; }

  const size_t vtbase = (size_t)(b * HEADS + h) * DHEAD * vstride;
  const size_t kbase  = (size_t)b * seqk * DIMN + h * DHEAD;
  const int nkv = (kvlen + 127) >> 7;

  // K tile: 128 rows x 8 chunks = 1024; V tile: 64 rows x 16 chunks = 1024
  auto stage = [&](int buf, int kv0) {
#pragma unroll
    for (int i = 0; i < 2; ++i) {
      const int c = tid + i * 512;
      const int row = c >> 3, ch = c & 7;
      const int chs = ch ^ (row & 7);
      int kr = kv0 + row; if (kr > kvlen - 1) kr = kvlen - 1;
      gload16(k + kbase + (size_t)kr * DIMN + chs * 8, &Ks[buf][c * 8]);
    }
#pragma unroll
    for (int i = 0; i < 2; ++i) {
      const int c = tid + i * 512;
      const int row = c >> 4, ch = c & 15;
      const int chs = ch ^ (row & 15);
      gload16(vt + vtbase + (size_t)row * vstride + kv0 + chs * 8, &Vs[buf][c * 8]);
    }
  };

  stage(0, 0);

  for (int kvb = 0; kvb < nkv; ++kvb) {
    const int kv0 = kvb * 128;
    const int cur = kvb & 1;
    if (kvb + 1 < nkv) {
      stage(cur ^ 1, kv0 + 128);
      asm volatile("s_waitcnt vmcnt(4)" ::: "memory");
    } else {
      asm volatile("s_waitcnt vmcnt(0)" ::: "memory");
    }
    __builtin_amdgcn_s_barrier();                        // B1

    // ---- QK^T: 32 MFMA (8 st groups x 2 kc x 2 qs)
    f32x4 sa[2][8];
#pragma unroll
    for (int qs = 0; qs < 2; ++qs)
#pragma unroll
      for (int st = 0; st < 8; ++st) sa[qs][st] = (f32x4){0.f, 0.f, 0.f, 0.f};
    __builtin_amdgcn_s_setprio(1);
#pragma unroll
    for (int st = 0; st < 8; ++st) {
      const int kvr = st * 16 + r16;
#pragma unroll
      for (int kc = 0; kc < 2; ++kc) {
        const int chs = (kc * 4 + g) ^ (kvr & 7);
        const bf16x8 kf = *(const bf16x8*)&Ks[cur][kvr * 64 + chs * 8];
        sa[0][st] = mfma16(aq[0][kc], kf, sa[0][st]);
        sa[1][st] = mfma16(aq[1][kc], kf, sa[1][st]);
      }
    }
    __builtin_amdgcn_s_setprio(0);

    // ---- tail mask (cross-attn only)
    if (kv0 + 128 > kvlen) {
#pragma unroll
      for (int st = 0; st < 8; ++st)
        if (kv0 + st * 16 + r16 >= kvlen) {
#pragma unroll
          for (int qs = 0; qs < 2; ++qs)
#pragma unroll
            for (int rg = 0; rg < 4; ++rg) sa[qs][st][rg] = -3e38f;
        }
    }

    // ---- defer-max check
    float bad = 0.f;
    float m4v[2][4];
#pragma unroll
    for (int qs = 0; qs < 2; ++qs)
#pragma unroll
      for (int rg = 0; rg < 4; ++rg) {
        float m4 = fmaxf(fmaxf(sa[qs][0][rg], sa[qs][1][rg]),
                         fmaxf(sa[qs][2][rg], sa[qs][3][rg]));
        m4 = fmaxf(m4, fmaxf(fmaxf(sa[qs][4][rg], sa[qs][5][rg]),
                             fmaxf(sa[qs][6][rg], sa[qs][7][rg])));
        m4v[qs][rg] = m4;
        bad = fmaxf(bad, m4 - mi[qs][rg]);
      }
    if (__any(bad > 16.0f)) {
#pragma unroll
      for (int qs = 0; qs < 2; ++qs)
#pragma unroll
        for (int rg = 0; rg < 4; ++rg) {
          float mx = m4v[qs][rg];
#pragma unroll
          for (int off = 1; off < 16; off <<= 1) mx = fmaxf(mx, __shfl_xor(mx, off));
          const float nm = fmaxf(mi[qs][rg], mx);
          const float corr = __builtin_amdgcn_exp2f((mi[qs][rg] - nm) * C);
          mi[qs][rg] = nm;
          li[qs][rg] *= corr;
#pragma unroll
          for (int ds = 0; ds < 4; ++ds) oacc[qs][ds][rg] *= corr;
        }
    }

    // ---- P = exp (two 64-granules), lane-local li, packed bf16 store
#pragma unroll
    for (int qs = 0; qs < 2; ++qs) {
#pragma unroll
      for (int rg = 0; rg < 4; ++rg) {
        const float mc = mi[qs][rg] * C;
        float p[8];
#pragma unroll
        for (int st = 0; st < 8; ++st)
          p[st] = __builtin_amdgcn_exp2f(__builtin_fmaf(sa[qs][st][rg], C, -mc));
        li[qs][rg] += ((p[0] + p[1]) + (p[2] + p[3])) + ((p[4] + p[5]) + (p[6] + p[7]));
        unsigned w0, w1, w2, w3;
        asm("v_cvt_pk_bf16_f32 %0, %1, %2" : "=v"(w0) : "v"(p[0]), "v"(p[1]));
        asm("v_cvt_pk_bf16_f32 %0, %1, %2" : "=v"(w1) : "v"(p[2]), "v"(p[3]));
        asm("v_cvt_pk_bf16_f32 %0, %1, %2" : "=v"(w2) : "v"(p[4]), "v"(p[5]));
        asm("v_cvt_pk_bf16_f32 %0, %1, %2" : "=v"(w3) : "v"(p[6]), "v"(p[7]));
        const int prow = qs * 16 + g * 4 + rg;
        uint2 pk0; pk0.x = w0; pk0.y = w1;
        uint2 pk1; pk1.x = w2; pk1.y = w3;
        *(uint2*)&Ps[wave][prow * 136 + r16 * 4]      = pk0;
        *(uint2*)&Ps[wave][prow * 136 + 64 + r16 * 4] = pk1;
      }
    }

    // ---- PV: 32 MFMA (4 kc slices of 32 kv)
    __builtin_amdgcn_s_setprio(1);
#pragma unroll
    for (int kc = 0; kc < 4; ++kc) {
      const bf16x8 pa0 = *(const bf16x8*)&Ps[wave][(r16)      * 136 + kc * 32 + g * 8];
      const bf16x8 pa1 = *(const bf16x8*)&Ps[wave][(16 + r16) * 136 + kc * 32 + g * 8];
#pragma unroll
      for (int ds = 0; ds < 4; ++ds) {
        const int dr = ds * 16 + r16;
        const int cc = kc * 4 + g;
        const int chs = cc ^ (dr & 15);
        const bf16x8 vf = *(const bf16x8*)&Vs[cur][dr * 128 + chs * 8];
        oacc[0][ds] = mfma16(pa0, vf, oacc[0][ds]);
        oacc[1][ds] = mfma16(pa1, vf, oacc[1][ds]);
      }
    }
    __builtin_amdgcn_s_setprio(0);

    __builtin_amdgcn_s_barrier();                        // B2
  }

#pragma unroll
  for (int qs = 0; qs < 2; ++qs)
#pragma unroll
    for (int rg = 0; rg < 4; ++rg) {
      float s = li[qs][rg];
#pragma unroll
      for (int off = 1; off < 16; off <<= 1) s += __shfl_xor(s, off);
      li[qs][rg] = s;
    }

#pragma unroll
  for (int qs = 0; qs < 2; ++qs)
#pragma unroll
    for (int rg = 0; rg < 4; ++rg) {
      const float inv = 1.0f / li[qs][rg];
      const int row = q0 + qs * 16 + g * 4 + rg;
      const size_t base = (size_t)(b * SEQ + row) * DIMN + h * DHEAD;
#pragma unroll
      for (int ds = 0; ds < 4; ++ds)
        o[base + ds * 16 + r16] = f2bf(oacc[qs][ds][rg] * inv);
    }
}

extern "C" void kernel_launch(void* const* d_in, const int* in_sizes, int n_in,
                              void* d_out, int out_size, void* d_ws, size_t ws_size,
                              hipStream_t stream)
{
  const float* x   = (const float*)d_in[0];
  const float* ctx = (const float*)d_in[1];
  const float* Wq1 = (const float*)d_in[2];
  const float* Wk1 = (const float*)d_in[3];
  const float* Wv1 = (const float*)d_in[4];
  const float* Wo1 = (const float*)d_in[5];
  const float* bo1 = (const float*)d_in[6];
  const float* Wq2 = (const float*)d_in[7];
  const float* Wk2 = (const float*)d_in[8];
  const float* Wv2 = (const float*)d_in[9];
  const float* Wo2 = (const float*)d_in[10];
  const float* bo2 = (const float*)d_in[11];
  const float* Wp  = (const float*)d_in[12];
  const float* bp  = (const float*)d_in[13];
  const float* W2  = (const float*)d_in[14];
  const float* b2  = (const float*)d_in[15];
  const float* g1  = (const float*)d_in[16];
  const float* be1 = (const float*)d_in[17];
  const float* g2  = (const float*)d_in[18];
  const float* be2 = (const float*)d_in[19];
  const float* g3  = (const float*)d_in[20];
  const float* be3 = (const float*)d_in[21];

  char* ws = (char*)d_ws;
  size_t off = 0;
  auto alloc = [&](size_t bytes) -> void* {
    void* p = ws + off;
    off += (bytes + 255) & ~(size_t)255;
    return p;
  };

  u16* WqT1 = (u16*)alloc((size_t)1024 * 1024 * 2);   // contiguous with WkT1, WvT1
  u16* WkT1 = (u16*)alloc((size_t)1024 * 1024 * 2);
  u16* WvT1 = (u16*)alloc((size_t)1024 * 1024 * 2);
  u16* WoT1 = (u16*)alloc((size_t)1024 * 1024 * 2);
  u16* WqT2 = (u16*)alloc((size_t)1024 * 1024 * 2);
  u16* WkT2 = (u16*)alloc((size_t)1024 * 768 * 2);    // contiguous with WvT2
  u16* WvT2 = (u16*)alloc((size_t)1024 * 768 * 2);
  u16* WoT2 = (u16*)alloc((size_t)1024 * 1024 * 2);
  u16* WpT  = (u16*)alloc((size_t)8192 * 1024 * 2);
  u16* W2T  = (u16*)alloc((size_t)1024 * 4096 * 2);
  u16* x1b  = (u16*)alloc((size_t)NTOK * DIMN * 2);
  u16* x2b  = (u16*)alloc((size_t)NTOK * DIMN * 2);
  u16* ctxb = (u16*)alloc((size_t)CTOK * CTXD * 2);
  u16* k2b  = (u16*)alloc((size_t)CTOK * DIMN * 2);
  u16* vt2b = (u16*)alloc((size_t)2 * HEADS * DHEAD * 128 * 2);
  u16* hb   = (u16*)alloc((size_t)NTOK * DIMN * 2);
  u16* qb   = (u16*)alloc((size_t)NTOK * DIMN * 2);
  u16* kb   = (u16*)alloc((size_t)NTOK * DIMN * 2);
  u16* vtb  = (u16*)alloc((size_t)NTOK * DIMN * 2);
  u16* ab   = (u16*)alloc((size_t)NTOK * DIMN * 2);
  u16* ub   = qb; // reuse qb..ab region (32MB) for FF intermediate [4096][4096]

  dim3 blk(256);
  dim3 blk5(512);

  // batched weight conversions
  WBatch wb6;
  wb6.s[0] = Wq1; wb6.d[0] = WqT1;
  wb6.s[1] = Wk1; wb6.d[1] = WkT1;
  wb6.s[2] = Wv1; wb6.d[2] = WvT1;
  wb6.s[3] = Wo1; wb6.d[3] = WoT1;
  wb6.s[4] = Wq2; wb6.d[4] = WqT2;
  wb6.s[5] = Wo2; wb6.d[5] = WoT2;
  wconvB_k<6><<<dim3(16, 16, 6), blk, 0, stream>>>(wb6, 1024, 1024);
  WBatch wb2;
  wb2.s[0] = Wk2; wb2.d[0] = WkT2;
  wb2.s[1] = Wv2; wb2.d[1] = WvT2;
  wb2.s[2] = nullptr; wb2.d[2] = nullptr;
  wb2.s[3] = nullptr; wb2.d[3] = nullptr;
  wb2.s[4] = nullptr; wb2.d[4] = nullptr;
  wb2.s[5] = nullptr; wb2.d[5] = nullptr;
  wconvB_k<2><<<dim3(16, 12, 2), blk, 0, stream>>>(wb2, 768, 1024);
  wconv_k<<<dim3(128, 16), blk, 0, stream>>>(Wp, WpT, 1024, 8192);
  wconv_k<<<dim3(16, 64), blk, 0, stream>>>(W2, W2T, 4096, 1024);
  cconv_k<<<dim3((CTOK * CTXD + 255) / 256), blk, 0, stream>>>(ctx, ctxb, CTOK * CTXD);

  // ---- self attention block (QKV fused: WqT1/WkT1/WvT1 contiguous, N=3072)
  ln_k<<<NTOK, 256, 0, stream>>>(x, g1, be1, hb);
  gemm_k<4><<<dim3(32, 24), blk5, 0, stream>>>(hb, WqT1, NTOK, 3072, 1024, nullptr, nullptr, qb, nullptr, SEQ, SEQ, kb, vtb);
  attn_k<<<dim3(8, 32), blk5, 0, stream>>>(qb, kb, vtb, ab, SEQ, SEQ, SEQ);
  gemm64_k<6><<<dim3(32, 8), blk5, 0, stream>>>(ab, WoT1, NTOK, 1024, 1024, bo1, x, nullptr, x1b, nullptr);

  // ---- cross attention block (K2+V2 fused over ctx, N=2048)
  ln_b_k<<<NTOK, 256, 0, stream>>>(x1b, g2, be2, hb);
  gemm64_k<0><<<dim3(32, 8), blk5, 0, stream>>>(hb, WqT2, NTOK, 1024, 1024, nullptr, nullptr, nullptr, qb, nullptr);
  gemm_k<5><<<dim3(2, 16), blk5, 0, stream>>>(ctxb, WkT2, CTOK, 2048, 768, nullptr, nullptr, k2b, nullptr, NCTX, 128, nullptr, vt2b);
  attn_k<<<dim3(8, 32), blk5, 0, stream>>>(qb, k2b, vt2b, ab, NCTX, NCTX, 128);
  gemm64_k<7><<<dim3(32, 8), blk5, 0, stream>>>(ab, WoT2, NTOK, 1024, 1024, bo2, nullptr, x1b, x2b, nullptr);

  // ---- GEGLU FF block
  ln_b_k<<<NTOK, 256, 0, stream>>>(x2b, g3, be3, hb);
  geglu_k<<<dim3(32, 32), blk5, 0, stream>>>(hb, WpT, WpT + (size_t)4096 * 1024, bp, bp + 4096, ub, NTOK, FFH);
  gemm64_k<8><<<dim3(32, 8), blk5, 0, stream>>>(ub, W2T, NTOK, 1024, 4096, b2, nullptr, x2b, nullptr, (float*)d_out);

  (void)in_sizes; (void)n_in; (void)out_size; (void)ws_size;
}

// Round 13
// 369.919 us; speedup vs baseline: 1.2663x; 1.0542x over previous
//
#include <hip/hip_runtime.h>
#include <hip/hip_bf16.h>
#include <math.h>

#define DIMN   1024
#define HEADS  16
#define DHEAD  64
#define CTXD   768
#define FFH    4096
#define NTOK   4096
#define SEQ    2048
#define NCTX   77
#define CTOK   154

typedef unsigned short u16;
typedef __bf16 bf16x8 __attribute__((ext_vector_type(8)));
typedef float  f32x4  __attribute__((ext_vector_type(4)));

__device__ __forceinline__ u16 f2bf(float f) {
  union { float f; unsigned u; } c; c.f = f;
  unsigned r = c.u + 0x7FFFu + ((c.u >> 16) & 1u);
  return (u16)(r >> 16);
}
__device__ __forceinline__ float bf2f(u16 h) {
  union { unsigned u; float f; } c; c.u = ((unsigned)h) << 16; return c.f;
}

__device__ __forceinline__ void gload16(const void* g, void* l) {
  __builtin_amdgcn_global_load_lds(
      (__attribute__((address_space(1))) void*)(void*)(g),
      (__attribute__((address_space(3))) void*)(l), 16, 0, 0);
}

__device__ __forceinline__ f32x4 mfma16(bf16x8 a, bf16x8 b, f32x4 c) {
  return __builtin_amdgcn_mfma_f32_16x16x32_bf16(a, b, c, 0, 0, 0);
}

// ---------------- work-list weight convert+transpose: W[K][N] f32 -> WT[N][K] bf16
struct WAll {
  int nw;
  int start[10];
  const float* s[10];
  u16* d[10];
  int K[10];
  int N[10];
};

__global__ __launch_bounds__(256)
void wconvA_k(WAll wa)
{
  __shared__ u16 t[64][65];
  const int bid = blockIdx.x;
  int w = 0;
  while (w + 1 < wa.nw && bid >= wa.start[w + 1]) ++w;
  const int local = bid - wa.start[w];
  const float* __restrict__ W  = wa.s[w];
  u16* __restrict__       WT   = wa.d[w];
  const int K = wa.K[w], N = wa.N[w];
  const int tilesX = N >> 6;
  const int n0 = (local % tilesX) * 64;
  const int k0 = (local / tilesX) * 64;
  const int tid = threadIdx.x;
  const int rr = tid >> 4, cc = tid & 15;
#pragma unroll
  for (int i = 0; i < 4; ++i) {
    int kr = rr + i * 16;
    const float4 v = *(const float4*)&W[(size_t)(k0 + kr) * N + n0 + cc * 4];
    t[kr][cc*4+0] = f2bf(v.x); t[kr][cc*4+1] = f2bf(v.y);
    t[kr][cc*4+2] = f2bf(v.z); t[kr][cc*4+3] = f2bf(v.w);
  }
  __syncthreads();
#pragma unroll
  for (int i = 0; i < 4; ++i) {
    int nr = rr + i * 16;
    int r0 = cc * 4;
    ushort4 o;
    o.x = t[r0+0][nr]; o.y = t[r0+1][nr]; o.z = t[r0+2][nr]; o.w = t[r0+3][nr];
    *(ushort4*)&WT[(size_t)(n0 + nr) * K + k0 + r0] = o;
  }
}

// ---------------- f32 -> bf16 elementwise (context)
__global__ void cconv_k(const float* __restrict__ c, u16* __restrict__ o, int n)
{
  int i = blockIdx.x * 256 + threadIdx.x;
  if (i < n) o[i] = f2bf(c[i]);
}

// ---------------- LayerNorm: f32 row[1024] -> bf16
__global__ __launch_bounds__(256)
void ln_k(const float* __restrict__ x, const float* __restrict__ gm,
          const float* __restrict__ bt, u16* __restrict__ o)
{
  int row = blockIdx.x;
  int tid = threadIdx.x;
  const float4 v = *(const float4*)&x[(size_t)row * DIMN + tid * 4];
  float s = v.x + v.y + v.z + v.w;
  float q = v.x*v.x + v.y*v.y + v.z*v.z + v.w*v.w;
#pragma unroll
  for (int off = 32; off; off >>= 1) { s += __shfl_xor(s, off); q += __shfl_xor(q, off); }
  __shared__ float ss[4], qq[4];
  int wave = tid >> 6;
  if ((tid & 63) == 0) { ss[wave] = s; qq[wave] = q; }
  __syncthreads();
  s = ss[0] + ss[1] + ss[2] + ss[3];
  q = qq[0] + qq[1] + qq[2] + qq[3];
  float mu = s * (1.0f / DIMN);
  float var = q * (1.0f / DIMN) - mu * mu;
  float rs = rsqrtf(var + 1e-5f);
  const float4 gv = *(const float4*)&gm[tid * 4];
  const float4 bv = *(const float4*)&bt[tid * 4];
  ushort4 r;
  r.x = f2bf((v.x - mu) * rs * gv.x + bv.x);
  r.y = f2bf((v.y - mu) * rs * gv.y + bv.y);
  r.z = f2bf((v.z - mu) * rs * gv.z + bv.z);
  r.w = f2bf((v.w - mu) * rs * gv.w + bv.w);
  *(ushort4*)&o[(size_t)row * DIMN + tid * 4] = r;
}

// ---------------- LayerNorm: bf16 row[1024] -> bf16
__global__ __launch_bounds__(256)
void ln_b_k(const u16* __restrict__ x, const float* __restrict__ gm,
            const float* __restrict__ bt, u16* __restrict__ o)
{
  int row = blockIdx.x;
  int tid = threadIdx.x;
  const ushort4 u = *(const ushort4*)&x[(size_t)row * DIMN + tid * 4];
  float4 v;
  v.x = bf2f(u.x); v.y = bf2f(u.y); v.z = bf2f(u.z); v.w = bf2f(u.w);
  float s = v.x + v.y + v.z + v.w;
  float q = v.x*v.x + v.y*v.y + v.z*v.z + v.w*v.w;
#pragma unroll
  for (int off = 32; off; off >>= 1) { s += __shfl_xor(s, off); q += __shfl_xor(q, off); }
  __shared__ float ss[4], qq[4];
  int wave = tid >> 6;
  if ((tid & 63) == 0) { ss[wave] = s; qq[wave] = q; }
  __syncthreads();
  s = ss[0] + ss[1] + ss[2] + ss[3];
  q = qq[0] + qq[1] + qq[2] + qq[3];
  float mu = s * (1.0f / DIMN);
  float var = q * (1.0f / DIMN) - mu * mu;
  float rs = rsqrtf(var + 1e-5f);
  const float4 gv = *(const float4*)&gm[tid * 4];
  const float4 bv = *(const float4*)&bt[tid * 4];
  ushort4 r;
  r.x = f2bf((v.x - mu) * rs * gv.x + bv.x);
  r.y = f2bf((v.y - mu) * rs * gv.y + bv.y);
  r.z = f2bf((v.z - mu) * rs * gv.z + bv.z);
  r.w = f2bf((v.w - mu) * rs * gv.w + bv.w);
  *(ushort4*)&o[(size_t)row * DIMN + tid * 4] = r;
}

// ---------------- GEMM (R5-proven): 512 threads, 8 waves (32x64 wave tile), 2-buf counted vmcnt
// MODE 4: QKV fused: colgrp 0->obf (q), 1->ob2 (k), 2->ob3 (vt store)
template<int MODE>
__global__ __launch_bounds__(512, 4)
void gemm_k(const u16* __restrict__ A, const u16* __restrict__ Bt,
            int M, int N, int K,
            const float* __restrict__ bias, const float* __restrict__ resid,
            u16* __restrict__ obf, float* __restrict__ of32,
            int seq, int vstride,
            u16* __restrict__ ob2, u16* __restrict__ ob3)
{
  __shared__ __align__(16) u16 As[2][128 * 32];
  __shared__ __align__(16) u16 Bs[2][128 * 32];
  const int tid = threadIdx.x;
  const int lane = tid & 63, wave = tid >> 6;
  const int wr = wave >> 1, wc = wave & 1;          // 4 x 2 wave grid
  const int g = lane >> 4, r16 = lane & 15;
  const int m0 = blockIdx.x * 128, n0 = blockIdx.y * 128;

  f32x4 acc[2][4] = {};

  const int srow = tid >> 2;          // 0..127
  const int sch  = tid & 3;           // 0..3
  const int schs = sch ^ ((srow >> 1) & 3);
  const int arow = (m0 + srow > M - 1) ? (M - 1) : (m0 + srow);
  const size_t abase = (size_t)arow * K + schs * 8;
  const size_t bbase = (size_t)(n0 + srow) * K + schs * 8;

  auto stage = [&](int buf, int kt) {
    gload16(A  + abase + kt, &As[buf][tid * 8]);
    gload16(Bt + bbase + kt, &Bs[buf][tid * 8]);
  };

  stage(0, 0);

  const int nkt = K >> 5;
  for (int t = 0; t < nkt; ++t) {
    const int cur = t & 1;
    if (t + 1 < nkt) {
      stage(cur ^ 1, (t + 1) << 5);
      asm volatile("s_waitcnt vmcnt(2)" ::: "memory");   // stage(t) landed; t+1 in flight
    } else {
      asm volatile("s_waitcnt vmcnt(0)" ::: "memory");
    }
    __builtin_amdgcn_s_barrier();                        // B1

    bf16x8 af[2], bfr[4];
#pragma unroll
    for (int mi = 0; mi < 2; ++mi) {
      int r = wr * 32 + mi * 16 + r16;
      int cph = g ^ ((r >> 1) & 3);
      af[mi] = *(const bf16x8*)&As[cur][(r * 4 + cph) * 8];
    }
#pragma unroll
    for (int ni = 0; ni < 4; ++ni) {
      int r = wc * 64 + ni * 16 + r16;
      int cph = g ^ ((r >> 1) & 3);
      bfr[ni] = *(const bf16x8*)&Bs[cur][(r * 4 + cph) * 8];
    }
    __builtin_amdgcn_s_setprio(1);
#pragma unroll
    for (int mi = 0; mi < 2; ++mi)
#pragma unroll
      for (int ni = 0; ni < 4; ++ni)
        acc[mi][ni] = mfma16(af[mi], bfr[ni], acc[mi][ni]);
    __builtin_amdgcn_s_setprio(0);

    __builtin_amdgcn_s_barrier();                        // B2 (WAR)
  }

  const int grp = n0 >> 10;           // column group for fused modes
#pragma unroll
  for (int ni = 0; ni < 4; ++ni) {
    int col = n0 + wc * 64 + ni * 16 + r16;
    const int c1 = col & 1023;
#pragma unroll
    for (int mi = 0; mi < 2; ++mi) {
      f32x4 c = acc[mi][ni];
#pragma unroll
      for (int rg = 0; rg < 4; ++rg) {
        int row = m0 + wr * 32 + mi * 16 + g * 4 + rg;
        if (row < M) {
          float v = c[rg];
          if constexpr (MODE == 4) {
            if (grp == 0) {
              obf[(size_t)row * 1024 + c1] = f2bf(v);
            } else if (grp == 1) {
              ob2[(size_t)row * 1024 + c1] = f2bf(v);
            } else {
              int b = row / seq, srow_ = row - b * seq;
              int jg = srow_ >> 6, j = srow_ & 63;
              int pos = jg * 64 + ((j & 15) << 2) + (j >> 4);
              ob3[((size_t)b * HEADS * DHEAD + c1) * vstride + pos] = f2bf(v);
            }
          }
        }
      }
    }
  }
  (void)bias; (void)resid; (void)of32;
}

// ---------------- GEMM BK=64 for grid<=256 launches.
// MODE 0: out bf16 = acc + bias (no resid)
// MODE 6: out bf16 = acc + bias + residf (f32 resid)
// MODE 7: out bf16 = acc + bias + residb (bf16 resid)
// MODE 8: out f32  = acc + bias + residb (bf16 resid)
template<int MODE>
__global__ __launch_bounds__(512, 2)
void gemm64_k(const u16* __restrict__ A, const u16* __restrict__ Bt,
              int M, int N, int K,
              const float* __restrict__ bias, const float* __restrict__ residf,
              const u16* __restrict__ residb,
              u16* __restrict__ obf, float* __restrict__ of32)
{
  __shared__ __align__(16) u16 As[2][128 * 64];   // 32 KB
  __shared__ __align__(16) u16 Bs[2][128 * 64];   // 32 KB
  const int tid = threadIdx.x;
  const int lane = tid & 63, wave = tid >> 6;
  const int wr = wave >> 1, wc = wave & 1;          // 4 x 2 wave grid, 32x64 tiles
  const int g = lane >> 4, r16 = lane & 15;
  const int m0 = blockIdx.x * 128, n0 = blockIdx.y * 128;

  f32x4 acc[2][4] = {};

  int aro[2], bro[2], scs[2];
#pragma unroll
  for (int i = 0; i < 2; ++i) {
    const int c = tid + i * 512;
    const int r = c >> 3, ch = c & 7;
    scs[i] = ch ^ (r & 7);
    aro[i] = (m0 + r > M - 1) ? (M - 1) : (m0 + r);
    bro[i] = n0 + r;
  }

  auto stage = [&](int buf, int kt) {
#pragma unroll
    for (int i = 0; i < 2; ++i) {
      const int c = tid + i * 512;
      gload16(A  + (size_t)aro[i] * K + kt + scs[i] * 8, &As[buf][c * 8]);
      gload16(Bt + (size_t)bro[i] * K + kt + scs[i] * 8, &Bs[buf][c * 8]);
    }
  };

  stage(0, 0);

  const int nkt = K >> 6;
  for (int t = 0; t < nkt; ++t) {
    const int cur = t & 1;
    if (t + 1 < nkt) {
      stage(cur ^ 1, (t + 1) << 6);
      asm volatile("s_waitcnt vmcnt(4)" ::: "memory");
    } else {
      asm volatile("s_waitcnt vmcnt(0)" ::: "memory");
    }
    __builtin_amdgcn_s_barrier();                        // B1

#pragma unroll
    for (int ks = 0; ks < 2; ++ks) {
      bf16x8 af[2], bfr[4];
#pragma unroll
      for (int mi = 0; mi < 2; ++mi) {
        int r = wr * 32 + mi * 16 + r16;
        int cph = (ks * 4 + g) ^ (r & 7);
        af[mi] = *(const bf16x8*)&As[cur][(r * 8 + cph) * 8];
      }
#pragma unroll
      for (int ni = 0; ni < 4; ++ni) {
        int r = wc * 64 + ni * 16 + r16;
        int cph = (ks * 4 + g) ^ (r & 7);
        bfr[ni] = *(const bf16x8*)&Bs[cur][(r * 8 + cph) * 8];
      }
      __builtin_amdgcn_s_setprio(1);
#pragma unroll
      for (int mi = 0; mi < 2; ++mi)
#pragma unroll
        for (int ni = 0; ni < 4; ++ni)
          acc[mi][ni] = mfma16(af[mi], bfr[ni], acc[mi][ni]);
      __builtin_amdgcn_s_setprio(0);
    }

    __builtin_amdgcn_s_barrier();                        // B2 (WAR)
  }

#pragma unroll
  for (int ni = 0; ni < 4; ++ni) {
    int col = n0 + wc * 64 + ni * 16 + r16;
    float bv = bias ? bias[col] : 0.0f;
#pragma unroll
    for (int mi = 0; mi < 2; ++mi) {
      f32x4 c = acc[mi][ni];
#pragma unroll
      for (int rg = 0; rg < 4; ++rg) {
        int row = m0 + wr * 32 + mi * 16 + g * 4 + rg;
        if (row < M) {
          float v = c[rg] + bv;
          size_t o = (size_t)row * N + col;
          if constexpr (MODE == 0) {
            obf[o] = f2bf(v);
          } else if constexpr (MODE == 6) {
            obf[o] = f2bf(v + residf[o]);
          } else if constexpr (MODE == 7) {
            obf[o] = f2bf(v + bf2f(residb[o]));
          } else {  // MODE 8
            of32[o] = v + bf2f(residb[o]);
          }
        }
      }
    }
  }
}

// ---------------- merged Q2 (gemm64-style, 256 blocks) + KV2 (gemm-style, 32 blocks)
// grid = 288 x 512 threads
__global__ __launch_bounds__(512, 2)
void q2kv2_k(const u16* __restrict__ hb, const u16* __restrict__ WqT2,
             u16* __restrict__ qb,
             const u16* __restrict__ ctxb, const u16* __restrict__ WkT2,
             u16* __restrict__ k2b, u16* __restrict__ vt2b)
{
  __shared__ __align__(16) u16 AsB[2][128 * 64];
  __shared__ __align__(16) u16 BsB[2][128 * 64];
  const int tid = threadIdx.x;
  const int lane = tid & 63, wave = tid >> 6;
  const int wr = wave >> 1, wc = wave & 1;
  const int g = lane >> 4, r16 = lane & 15;
  const int bid = blockIdx.x;

  if (bid < 256) {
    // ======== Q2: M=4096 N=1024 K=1024, BK=64, out bf16 no bias ========
    const int K = 1024;
    const int m0 = (bid & 31) * 128, n0 = (bid >> 5) * 128;
    f32x4 acc[2][4] = {};

    int aro[2], bro[2], scs[2];
#pragma unroll
    for (int i = 0; i < 2; ++i) {
      const int c = tid + i * 512;
      const int r = c >> 3, ch = c & 7;
      scs[i] = ch ^ (r & 7);
      aro[i] = m0 + r;
      bro[i] = n0 + r;
    }
    auto stage = [&](int buf, int kt) {
#pragma unroll
      for (int i = 0; i < 2; ++i) {
        const int c = tid + i * 512;
        gload16(hb   + (size_t)aro[i] * K + kt + scs[i] * 8, &AsB[buf][c * 8]);
        gload16(WqT2 + (size_t)bro[i] * K + kt + scs[i] * 8, &BsB[buf][c * 8]);
      }
    };
    stage(0, 0);
    const int nkt = K >> 6;
    for (int t = 0; t < nkt; ++t) {
      const int cur = t & 1;
      if (t + 1 < nkt) {
        stage(cur ^ 1, (t + 1) << 6);
        asm volatile("s_waitcnt vmcnt(4)" ::: "memory");
      } else {
        asm volatile("s_waitcnt vmcnt(0)" ::: "memory");
      }
      __builtin_amdgcn_s_barrier();
#pragma unroll
      for (int ks = 0; ks < 2; ++ks) {
        bf16x8 af[2], bfr[4];
#pragma unroll
        for (int mi = 0; mi < 2; ++mi) {
          int r = wr * 32 + mi * 16 + r16;
          int cph = (ks * 4 + g) ^ (r & 7);
          af[mi] = *(const bf16x8*)&AsB[cur][(r * 8 + cph) * 8];
        }
#pragma unroll
        for (int ni = 0; ni < 4; ++ni) {
          int r = wc * 64 + ni * 16 + r16;
          int cph = (ks * 4 + g) ^ (r & 7);
          bfr[ni] = *(const bf16x8*)&BsB[cur][(r * 8 + cph) * 8];
        }
        __builtin_amdgcn_s_setprio(1);
#pragma unroll
        for (int mi = 0; mi < 2; ++mi)
#pragma unroll
          for (int ni = 0; ni < 4; ++ni)
            acc[mi][ni] = mfma16(af[mi], bfr[ni], acc[mi][ni]);
        __builtin_amdgcn_s_setprio(0);
      }
      __builtin_amdgcn_s_barrier();
    }
#pragma unroll
    for (int ni = 0; ni < 4; ++ni) {
      int col = n0 + wc * 64 + ni * 16 + r16;
#pragma unroll
      for (int mi = 0; mi < 2; ++mi) {
#pragma unroll
        for (int rg = 0; rg < 4; ++rg) {
          int row = m0 + wr * 32 + mi * 16 + g * 4 + rg;
          qb[(size_t)row * 1024 + col] = f2bf(acc[mi][ni][rg]);
        }
      }
    }
  } else {
    // ======== KV2: M=CTOK N=2048 K=768, BK=32, mode-5 epilogue ========
    const int K = 768, M = CTOK;
    const int local = bid - 256;
    const int m0 = (local & 1) * 128, n0 = (local >> 1) * 128;
    u16* As = &AsB[0][0];                 // use first 2x(128*32) region
    u16* Bs = &BsB[0][0];
    const int BUFS = 128 * 32;
    f32x4 acc[2][4] = {};

    const int srow = tid >> 2;
    const int sch  = tid & 3;
    const int schs = sch ^ ((srow >> 1) & 3);
    const int arow = (m0 + srow > M - 1) ? (M - 1) : (m0 + srow);
    const size_t abase = (size_t)arow * K + schs * 8;
    const size_t bbase = (size_t)(n0 + srow) * K + schs * 8;

    auto stage = [&](int buf, int kt) {
      gload16(ctxb + abase + kt, &As[buf * BUFS + tid * 8]);
      gload16(WkT2 + bbase + kt, &Bs[buf * BUFS + tid * 8]);
    };
    stage(0, 0);
    const int nkt = K >> 5;
    for (int t = 0; t < nkt; ++t) {
      const int cur = t & 1;
      if (t + 1 < nkt) {
        stage(cur ^ 1, (t + 1) << 5);
        asm volatile("s_waitcnt vmcnt(2)" ::: "memory");
      } else {
        asm volatile("s_waitcnt vmcnt(0)" ::: "memory");
      }
      __builtin_amdgcn_s_barrier();

      bf16x8 af[2], bfr[4];
#pragma unroll
      for (int mi = 0; mi < 2; ++mi) {
        int r = wr * 32 + mi * 16 + r16;
        int cph = g ^ ((r >> 1) & 3);
        af[mi] = *(const bf16x8*)&As[cur * BUFS + (r * 4 + cph) * 8];
      }
#pragma unroll
      for (int ni = 0; ni < 4; ++ni) {
        int r = wc * 64 + ni * 16 + r16;
        int cph = g ^ ((r >> 1) & 3);
        bfr[ni] = *(const bf16x8*)&Bs[cur * BUFS + (r * 4 + cph) * 8];
      }
      __builtin_amdgcn_s_setprio(1);
#pragma unroll
      for (int mi = 0; mi < 2; ++mi)
#pragma unroll
        for (int ni = 0; ni < 4; ++ni)
          acc[mi][ni] = mfma16(af[mi], bfr[ni], acc[mi][ni]);
      __builtin_amdgcn_s_setprio(0);

      __builtin_amdgcn_s_barrier();
    }

    const int grp = n0 >> 10;
#pragma unroll
    for (int ni = 0; ni < 4; ++ni) {
      int col = n0 + wc * 64 + ni * 16 + r16;
      const int c1 = col & 1023;
#pragma unroll
      for (int mi = 0; mi < 2; ++mi) {
#pragma unroll
        for (int rg = 0; rg < 4; ++rg) {
          int row = m0 + wr * 32 + mi * 16 + g * 4 + rg;
          if (row < M) {
            float v = acc[mi][ni][rg];
            if (grp == 0) {
              k2b[(size_t)row * 1024 + c1] = f2bf(v);
            } else {
              int b = row / NCTX, srow_ = row - b * NCTX;
              int jg = srow_ >> 6, j = srow_ & 63;
              int pos = jg * 64 + ((j & 15) << 2) + (j >> 4);
              vt2b[((size_t)b * HEADS * DHEAD + c1) * 128 + pos] = f2bf(v);
            }
          }
        }
      }
    }
  }
}

// ---------------- fused GEGLU GEMM (R5-proven): 512 thr, 128x128, 2-buf counted vmcnt
__global__ __launch_bounds__(512, 2)
void geglu_k(const u16* __restrict__ A, const u16* __restrict__ B1t,
             const u16* __restrict__ B2t,
             const float* __restrict__ ba, const float* __restrict__ bg,
             u16* __restrict__ out, int M, int N)
{
  __shared__ __align__(16) u16 As[2][128 * 32];
  __shared__ __align__(16) u16 B1s[2][128 * 32];
  __shared__ __align__(16) u16 B2s[2][128 * 32];
  const int tid = threadIdx.x;
  const int lane = tid & 63, wave = tid >> 6;
  const int wr = wave >> 1, wc = wave & 1;
  const int g = lane >> 4, r16 = lane & 15;
  const int m0 = blockIdx.x * 128, n0 = blockIdx.y * 128;
  const int K = 1024;

  f32x4 acca[2][4] = {}, accg[2][4] = {};

  const int srow = tid >> 2;
  const int sch  = tid & 3;
  const int schs = sch ^ ((srow >> 1) & 3);
  const size_t abase = (size_t)(m0 + srow) * K + schs * 8;
  const size_t bbase = (size_t)(n0 + srow) * K + schs * 8;

  auto stage = [&](int buf, int kt) {
    gload16(A   + abase + kt, &As[buf][tid * 8]);
    gload16(B1t + bbase + kt, &B1s[buf][tid * 8]);
    gload16(B2t + bbase + kt, &B2s[buf][tid * 8]);
  };

  stage(0, 0);

  const int nkt = K >> 5;
  for (int t = 0; t < nkt; ++t) {
    const int cur = t & 1;
    if (t + 1 < nkt) {
      stage(cur ^ 1, (t + 1) << 5);
      asm volatile("s_waitcnt vmcnt(3)" ::: "memory");
    } else {
      asm volatile("s_waitcnt vmcnt(0)" ::: "memory");
    }
    __builtin_amdgcn_s_barrier();                        // B1

    bf16x8 af[2], b1f[4], b2f[4];
#pragma unroll
    for (int mi = 0; mi < 2; ++mi) {
      int r = wr * 32 + mi * 16 + r16;
      int cph = g ^ ((r >> 1) & 3);
      af[mi] = *(const bf16x8*)&As[cur][(r * 4 + cph) * 8];
    }
#pragma unroll
    for (int ni = 0; ni < 4; ++ni) {
      int r = wc * 64 + ni * 16 + r16;
      int cph = g ^ ((r >> 1) & 3);
      b1f[ni] = *(const bf16x8*)&B1s[cur][(r * 4 + cph) * 8];
      b2f[ni] = *(const bf16x8*)&B2s[cur][(r * 4 + cph) * 8];
    }
    __builtin_amdgcn_s_setprio(1);
#pragma unroll
    for (int mi = 0; mi < 2; ++mi)
#pragma unroll
      for (int ni = 0; ni < 4; ++ni) {
        acca[mi][ni] = mfma16(af[mi], b1f[ni], acca[mi][ni]);
        accg[mi][ni] = mfma16(af[mi], b2f[ni], accg[mi][ni]);
      }
    __builtin_amdgcn_s_setprio(0);

    __builtin_amdgcn_s_barrier();                        // B2
  }

#pragma unroll
  for (int ni = 0; ni < 4; ++ni) {
    int col = n0 + wc * 64 + ni * 16 + r16;
    float bva = ba[col], bvg = bg[col];
#pragma unroll
    for (int mi = 0; mi < 2; ++mi) {
#pragma unroll
      for (int rg = 0; rg < 4; ++rg) {
        int row = m0 + wr * 32 + mi * 16 + g * 4 + rg;
        float a  = acca[mi][ni][rg] + bva;
        float gt = accg[mi][ni][rg] + bvg;
        float gl = 0.5f * gt * (1.0f + erff(gt * 0.70710678f));
        out[(size_t)row * N + col] = f2bf(a * gl);
      }
    }
  }
}

// ---------------- flash attention v6: 8 waves (256 q/block), KVBLK=128, XCD-affine
// grid MUST be (8, 32)
__global__ __launch_bounds__(512, 1)
void attn_k(const u16* __restrict__ q, const u16* __restrict__ k,
            const u16* __restrict__ vt, u16* __restrict__ o,
            int kvlen, int seqk, int vstride)
{
  __shared__ __align__(16) u16 Ks[2][128 * 64];   // [kv][d], chunk-swizzled (8/row)
  __shared__ __align__(16) u16 Vs[2][64 * 128];   // [d][kv], chunk-swizzled (16/row)
  __shared__ __align__(16) u16 Ps[8][32 * 136];   // per-wave P, 2 granules of 64
  const int tid = threadIdx.x, lane = tid & 63, wave = tid >> 6;
  const int g = lane >> 4, r16 = lane & 15;

  // XCD-affine remap: L%8 = XCD. Each XCD c owns heads 4c..4c+3 fully.
  const int L  = blockIdx.y * 8 + blockIdx.x;
  const int c8 = L & 7, tt = L >> 3;
  const int bx = tt & 7;
  const int bh = c8 * 4 + (tt >> 3);

  const int b = bh >> 4, h = bh & 15;
  const int q0 = bx * 256 + wave * 32;
  const float C = 0.18033688f;   // log2(e)/8

  bf16x8 aq[2][2];
#pragma unroll
  for (int qs = 0; qs < 2; ++qs) {
    const size_t qoff = (size_t)(b * SEQ + q0 + qs * 16 + r16) * DIMN + h * DHEAD;
#pragma unroll
    for (int kc = 0; kc < 2; ++kc)
      aq[qs][kc] = *(const bf16x8*)&q[qoff + kc * 32 + g * 8];
  }
  asm volatile("" :: "v"(aq[0][0]), "v"(aq[0][1]), "v"(aq[1][0]), "v"(aq[1][1]));

  f32x4 oacc[2][4] = {};
  float mi[2][4], li[2][4];
#pragma unroll
  for (int qs = 0; qs < 2; ++qs)
#pragma unroll
    for (int rg = 0; rg < 4; ++rg) { mi[qs][rg] = -3e38f; li[qs][rg] = 0.f; }

  const size_t vtbase = (size_t)(b * HEADS + h) * DHEAD * vstride;
  const size_t kbase  = (size_t)b * seqk * DIMN + h * DHEAD;
  const int nkv = (kvlen + 127) >> 7;

  auto stage = [&](int buf, int kv0) {
#pragma unroll
    for (int i = 0; i < 2; ++i) {
      const int c = tid + i * 512;
      const int row = c >> 3, ch = c & 7;
      const int chs = ch ^ (row & 7);
      int kr = kv0 + row; if (kr > kvlen - 1) kr = kvlen - 1;
      gload16(k + kbase + (size_t)kr * DIMN + chs * 8, &Ks[buf][c * 8]);
    }
#pragma unroll
    for (int i = 0; i < 2; ++i) {
      const int c = tid + i * 512;
      const int row = c >> 4, ch = c & 15;
      const int chs = ch ^ (row & 15);
      gload16(vt + vtbase + (size_t)row * vstride + kv0 + chs * 8, &Vs[buf][c * 8]);
    }
  };

  stage(0, 0);

  for (int kvb = 0; kvb < nkv; ++kvb) {
    const int kv0 = kvb * 128;
    const int cur = kvb & 1;
    if (kvb + 1 < nkv) {
      stage(cur ^ 1, kv0 + 128);
      asm volatile("s_waitcnt vmcnt(4)" ::: "memory");
    } else {
      asm volatile("s_waitcnt vmcnt(0)" ::: "memory");
    }
    __builtin_amdgcn_s_barrier();                        // B1

    // ---- QK^T: 32 MFMA
    f32x4 sa[2][8];
#pragma unroll
    for (int qs = 0; qs < 2; ++qs)
#pragma unroll
      for (int st = 0; st < 8; ++st) sa[qs][st] = (f32x4){0.f, 0.f, 0.f, 0.f};
    __builtin_amdgcn_s_setprio(1);
#pragma unroll
    for (int st = 0; st < 8; ++st) {
      const int kvr = st * 16 + r16;
#pragma unroll
      for (int kc = 0; kc < 2; ++kc) {
        const int chs = (kc * 4 + g) ^ (kvr & 7);
        const bf16x8 kf = *(const bf16x8*)&Ks[cur][kvr * 64 + chs * 8];
        sa[0][st] = mfma16(aq[0][kc], kf, sa[0][st]);
        sa[1][st] = mfma16(aq[1][kc], kf, sa[1][st]);
      }
    }
    __builtin_amdgcn_s_setprio(0);

    // ---- tail mask (cross-attn only)
    if (kv0 + 128 > kvlen) {
#pragma unroll
      for (int st = 0; st < 8; ++st)
        if (kv0 + st * 16 + r16 >= kvlen) {
#pragma unroll
          for (int qs = 0; qs < 2; ++qs)
#pragma unroll
            for (int rg = 0; rg < 4; ++rg) sa[qs][st][rg] = -3e38f;
        }
    }

    // ---- defer-max check
    float bad = 0.f;
    float m4v[2][4];
#pragma unroll
    for (int qs = 0; qs < 2; ++qs)
#pragma unroll
      for (int rg = 0; rg < 4; ++rg) {
        float m4 = fmaxf(fmaxf(sa[qs][0][rg], sa[qs][1][rg]),
                         fmaxf(sa[qs][2][rg], sa[qs][3][rg]));
        m4 = fmaxf(m4, fmaxf(fmaxf(sa[qs][4][rg], sa[qs][5][rg]),
                             fmaxf(sa[qs][6][rg], sa[qs][7][rg])));
        m4v[qs][rg] = m4;
        bad = fmaxf(bad, m4 - mi[qs][rg]);
      }
    if (__any(bad > 16.0f)) {
#pragma unroll
      for (int qs = 0; qs < 2; ++qs)
#pragma unroll
        for (int rg = 0; rg < 4; ++rg) {
          float mx = m4v[qs][rg];
#pragma unroll
          for (int off = 1; off < 16; off <<= 1) mx = fmaxf(mx, __shfl_xor(mx, off));
          const float nm = fmaxf(mi[qs][rg], mx);
          const float corr = __builtin_amdgcn_exp2f((mi[qs][rg] - nm) * C);
          mi[qs][rg] = nm;
          li[qs][rg] *= corr;
#pragma unroll
          for (int ds = 0; ds < 4; ++ds) oacc[qs][ds][rg] *= corr;
        }
    }

    // ---- P = exp (two 64-granules), lane-local li, packed bf16 store
#pragma unroll
    for (int qs = 0; qs < 2; ++qs) {
#pragma unroll
      for (int rg = 0; rg < 4; ++rg) {
        const float mc = mi[qs][rg] * C;
        float p[8];
#pragma unroll
        for (int st = 0; st < 8; ++st)
          p[st] = __builtin_amdgcn_exp2f(__builtin_fmaf(sa[qs][st][rg], C, -mc));
        li[qs][rg] += ((p[0] + p[1]) + (p[2] + p[3])) + ((p[4] + p[5]) + (p[6] + p[7]));
        unsigned w0, w1, w2, w3;
        asm("v_cvt_pk_bf16_f32 %0, %1, %2" : "=v"(w0) : "v"(p[0]), "v"(p[1]));
        asm("v_cvt_pk_bf16_f32 %0, %1, %2" : "=v"(w1) : "v"(p[2]), "v"(p[3]));
        asm("v_cvt_pk_bf16_f32 %0, %1, %2" : "=v"(w2) : "v"(p[4]), "v"(p[5]));
        asm("v_cvt_pk_bf16_f32 %0, %1, %2" : "=v"(w3) : "v"(p[6]), "v"(p[7]));
        const int prow = qs * 16 + g * 4 + rg;
        uint2 pk0; pk0.x = w0; pk0.y = w1;
        uint2 pk1; pk1.x = w2; pk1.y = w3;
        *(uint2*)&Ps[wave][prow * 136 + r16 * 4]      = pk0;
        *(uint2*)&Ps[wave][prow * 136 + 64 + r16 * 4] = pk1;
      }
    }

    // ---- PV: 32 MFMA
    __builtin_amdgcn_s_setprio(1);
#pragma unroll
    for (int kc = 0; kc < 4; ++kc) {
      const bf16x8 pa0 = *(const bf16x8*)&Ps[wave][(r16)      * 136 + kc * 32 + g * 8];
      const bf16x8 pa1 = *(const bf16x8*)&Ps[wave][(16 + r16) * 136 + kc * 32 + g * 8];
#pragma unroll
      for (int ds = 0; ds < 4; ++ds) {
        const int dr = ds * 16 + r16;
        const int cc = kc * 4 + g;
        const int chs = cc ^ (dr & 15);
        const bf16x8 vf = *(const bf16x8*)&Vs[cur][dr * 128 + chs * 8];
        oacc[0][ds] = mfma16(pa0, vf, oacc[0][ds]);
        oacc[1][ds] = mfma16(pa1, vf, oacc[1][ds]);
      }
    }
    __builtin_amdgcn_s_setprio(0);

    __builtin_amdgcn_s_barrier();                        // B2
  }

#pragma unroll
  for (int qs = 0; qs < 2; ++qs)
#pragma unroll
    for (int rg = 0; rg < 4; ++rg) {
      float s = li[qs][rg];
#pragma unroll
      for (int off = 1; off < 16; off <<= 1) s += __shfl_xor(s, off);
      li[qs][rg] = s;
    }

#pragma unroll
  for (int qs = 0; qs < 2; ++qs)
#pragma unroll
    for (int rg = 0; rg < 4; ++rg) {
      const float inv = 1.0f / li[qs][rg];
      const int row = q0 + qs * 16 + g * 4 + rg;
      const size_t base = (size_t)(b * SEQ + row) * DIMN + h * DHEAD;
#pragma unroll
      for (int ds = 0; ds < 4; ++ds)
        o[base + ds * 16 + r16] = f2bf(oacc[qs][ds][rg] * inv);
    }
}

extern "C" void kernel_launch(void* const* d_in, const int* in_sizes, int n_in,
                              void* d_out, int out_size, void* d_ws, size_t ws_size,
                              hipStream_t stream)
{
  const float* x   = (const float*)d_in[0];
  const float* ctx = (const float*)d_in[1];
  const float* Wq1 = (const float*)d_in[2];
  const float* Wk1 = (const float*)d_in[3];
  const float* Wv1 = (const float*)d_in[4];
  const float* Wo1 = (const float*)d_in[5];
  const float* bo1 = (const float*)d_in[6];
  const float* Wq2 = (const float*)d_in[7];
  const float* Wk2 = (const float*)d_in[8];
  const float* Wv2 = (const float*)d_in[9];
  const float* Wo2 = (const float*)d_in[10];
  const float* bo2 = (const float*)d_in[11];
  const float* Wp  = (const float*)d_in[12];
  const float* bp  = (const float*)d_in[13];
  const float* W2  = (const float*)d_in[14];
  const float* b2  = (const float*)d_in[15];
  const float* g1  = (const float*)d_in[16];
  const float* be1 = (const float*)d_in[17];
  const float* g2  = (const float*)d_in[18];
  const float* be2 = (const float*)d_in[19];
  const float* g3  = (const float*)d_in[20];
  const float* be3 = (const float*)d_in[21];

  char* ws = (char*)d_ws;
  size_t off = 0;
  auto alloc = [&](size_t bytes) -> void* {
    void* p = ws + off;
    off += (bytes + 255) & ~(size_t)255;
    return p;
  };

  u16* WqT1 = (u16*)alloc((size_t)1024 * 1024 * 2);   // contiguous with WkT1, WvT1
  u16* WkT1 = (u16*)alloc((size_t)1024 * 1024 * 2);
  u16* WvT1 = (u16*)alloc((size_t)1024 * 1024 * 2);
  u16* WoT1 = (u16*)alloc((size_t)1024 * 1024 * 2);
  u16* WqT2 = (u16*)alloc((size_t)1024 * 1024 * 2);
  u16* WkT2 = (u16*)alloc((size_t)1024 * 768 * 2);    // contiguous with WvT2
  u16* WvT2 = (u16*)alloc((size_t)1024 * 768 * 2);
  u16* WoT2 = (u16*)alloc((size_t)1024 * 1024 * 2);
  u16* WpT  = (u16*)alloc((size_t)8192 * 1024 * 2);
  u16* W2T  = (u16*)alloc((size_t)1024 * 4096 * 2);
  u16* x1b  = (u16*)alloc((size_t)NTOK * DIMN * 2);
  u16* x2b  = (u16*)alloc((size_t)NTOK * DIMN * 2);
  u16* ctxb = (u16*)alloc((size_t)CTOK * CTXD * 2);
  u16* k2b  = (u16*)alloc((size_t)CTOK * DIMN * 2);
  u16* vt2b = (u16*)alloc((size_t)2 * HEADS * DHEAD * 128 * 2);
  u16* hb   = (u16*)alloc((size_t)NTOK * DIMN * 2);
  u16* qb   = (u16*)alloc((size_t)NTOK * DIMN * 2);
  u16* kb   = (u16*)alloc((size_t)NTOK * DIMN * 2);
  u16* vtb  = (u16*)alloc((size_t)NTOK * DIMN * 2);
  u16* ab   = (u16*)alloc((size_t)NTOK * DIMN * 2);
  u16* ub   = qb; // reuse qb..ab region (32MB) for FF intermediate [4096][4096]

  dim3 blk(256);
  dim3 blk5(512);

  // single work-list weight conversion (10 weights, 4992 tiles)
  WAll wa;
  wa.nw = 10;
  const float* srcs[10] = {Wq1, Wk1, Wv1, Wo1, Wq2, Wo2, Wk2, Wv2, Wp, W2};
  u16* dsts[10]         = {WqT1, WkT1, WvT1, WoT1, WqT2, WoT2, WkT2, WvT2, WpT, W2T};
  const int Ksz[10]     = {1024, 1024, 1024, 1024, 1024, 1024, 768, 768, 1024, 4096};
  const int Nsz[10]     = {1024, 1024, 1024, 1024, 1024, 1024, 1024, 1024, 8192, 1024};
  int tot = 0;
  for (int i = 0; i < 10; ++i) {
    wa.start[i] = tot; wa.s[i] = srcs[i]; wa.d[i] = dsts[i];
    wa.K[i] = Ksz[i];  wa.N[i] = Nsz[i];
    tot += (Nsz[i] >> 6) * (Ksz[i] >> 6);
  }
  wconvA_k<<<dim3(tot), blk, 0, stream>>>(wa);
  cconv_k<<<dim3((CTOK * CTXD + 255) / 256), blk, 0, stream>>>(ctx, ctxb, CTOK * CTXD);

  // ---- self attention block (QKV fused: WqT1/WkT1/WvT1 contiguous, N=3072)
  ln_k<<<NTOK, 256, 0, stream>>>(x, g1, be1, hb);
  gemm_k<4><<<dim3(32, 24), blk5, 0, stream>>>(hb, WqT1, NTOK, 3072, 1024, nullptr, nullptr, qb, nullptr, SEQ, SEQ, kb, vtb);
  attn_k<<<dim3(8, 32), blk5, 0, stream>>>(qb, kb, vtb, ab, SEQ, SEQ, SEQ);
  gemm64_k<6><<<dim3(32, 8), blk5, 0, stream>>>(ab, WoT1, NTOK, 1024, 1024, bo1, x, nullptr, x1b, nullptr);

  // ---- cross attention block (Q2 + KV2 merged into one dispatch)
  ln_b_k<<<NTOK, 256, 0, stream>>>(x1b, g2, be2, hb);
  q2kv2_k<<<dim3(288), blk5, 0, stream>>>(hb, WqT2, qb, ctxb, WkT2, k2b, vt2b);
  attn_k<<<dim3(8, 32), blk5, 0, stream>>>(qb, k2b, vt2b, ab, NCTX, NCTX, 128);
  gemm64_k<7><<<dim3(32, 8), blk5, 0, stream>>>(ab, WoT2, NTOK, 1024, 1024, bo2, nullptr, x1b, x2b, nullptr);

  // ---- GEGLU FF block
  ln_b_k<<<NTOK, 256, 0, stream>>>(x2b, g3, be3, hb);
  geglu_k<<<dim3(32, 32), blk5, 0, stream>>>(hb, WpT, WpT + (size_t)4096 * 1024, bp, bp + 4096, ub, NTOK, FFH);
  gemm64_k<8><<<dim3(32, 8), blk5, 0, stream>>>(ub, W2T, NTOK, 1024, 4096, b2, nullptr, x2b, nullptr, (float*)d_out);

  (void)in_sizes; (void)n_in; (void)out_size; (void)ws_size;
}

// Round 14
// 364.303 us; speedup vs baseline: 1.2858x; 1.0154x over previous
//
#include <hip/hip_runtime.h>
#include <hip/hip_bf16.h>
#include <math.h>

#define DIMN   1024
#define HEADS  16
#define DHEAD  64
#define CTXD   768
#define FFH    4096
#define NTOK   4096
#define SEQ    2048
#define NCTX   77
#define CTOK   154

typedef unsigned short u16;
typedef __bf16 bf16x8 __attribute__((ext_vector_type(8)));
typedef float  f32x4  __attribute__((ext_vector_type(4)));

__device__ __forceinline__ u16 f2bf(float f) {
  union { float f; unsigned u; } c; c.f = f;
  unsigned r = c.u + 0x7FFFu + ((c.u >> 16) & 1u);
  return (u16)(r >> 16);
}
__device__ __forceinline__ float bf2f(u16 h) {
  union { unsigned u; float f; } c; c.u = ((unsigned)h) << 16; return c.f;
}

__device__ __forceinline__ void gload16(const void* g, void* l) {
  __builtin_amdgcn_global_load_lds(
      (__attribute__((address_space(1))) void*)(void*)(g),
      (__attribute__((address_space(3))) void*)(l), 16, 0, 0);
}

__device__ __forceinline__ f32x4 mfma16(bf16x8 a, bf16x8 b, f32x4 c) {
  return __builtin_amdgcn_mfma_f32_16x16x32_bf16(a, b, c, 0, 0, 0);
}

// ---------------- prologue work-list: 10 weight transposes + LN1 + ctx conversion
struct WAll {
  int nw;
  int start[10];
  const float* s[10];
  u16* d[10];
  int K[10];
  int N[10];
  int lnStart, ccStart;
  const float* x; const float* g1; const float* be1; u16* hb;
  const float* ctx; u16* ctxb;
};

__global__ __launch_bounds__(256)
void wconvA_k(WAll wa)
{
  __shared__ u16 t[64][65];
  __shared__ float ss[4], qq[4];
  const int bid = blockIdx.x;
  const int tid = threadIdx.x;

  if (bid >= wa.ccStart) {
    // ---- ctx f32 -> bf16
    const int i = (bid - wa.ccStart) * 256 + tid;
    if (i < CTOK * CTXD) wa.ctxb[i] = f2bf(wa.ctx[i]);
    return;
  }
  if (bid >= wa.lnStart) {
    // ---- LayerNorm row (f32 -> bf16)
    const int row = bid - wa.lnStart;
    const float4 v = *(const float4*)&wa.x[(size_t)row * DIMN + tid * 4];
    float s = v.x + v.y + v.z + v.w;
    float q = v.x*v.x + v.y*v.y + v.z*v.z + v.w*v.w;
#pragma unroll
    for (int off = 32; off; off >>= 1) { s += __shfl_xor(s, off); q += __shfl_xor(q, off); }
    const int wave = tid >> 6;
    if ((tid & 63) == 0) { ss[wave] = s; qq[wave] = q; }
    __syncthreads();
    s = ss[0] + ss[1] + ss[2] + ss[3];
    q = qq[0] + qq[1] + qq[2] + qq[3];
    const float mu = s * (1.0f / DIMN);
    const float var = q * (1.0f / DIMN) - mu * mu;
    const float rs = rsqrtf(var + 1e-5f);
    const float4 gv = *(const float4*)&wa.g1[tid * 4];
    const float4 bv = *(const float4*)&wa.be1[tid * 4];
    ushort4 r;
    r.x = f2bf((v.x - mu) * rs * gv.x + bv.x);
    r.y = f2bf((v.y - mu) * rs * gv.y + bv.y);
    r.z = f2bf((v.z - mu) * rs * gv.z + bv.z);
    r.w = f2bf((v.w - mu) * rs * gv.w + bv.w);
    *(ushort4*)&wa.hb[(size_t)row * DIMN + tid * 4] = r;
    return;
  }

  // ---- weight transpose tile
  int w = 0;
  while (w + 1 < wa.nw && bid >= wa.start[w + 1]) ++w;
  const int local = bid - wa.start[w];
  const float* __restrict__ W  = wa.s[w];
  u16* __restrict__       WT   = wa.d[w];
  const int K = wa.K[w], N = wa.N[w];
  const int tilesX = N >> 6;
  const int n0 = (local % tilesX) * 64;
  const int k0 = (local / tilesX) * 64;
  const int rr = tid >> 4, cc = tid & 15;
#pragma unroll
  for (int i = 0; i < 4; ++i) {
    int kr = rr + i * 16;
    const float4 v = *(const float4*)&W[(size_t)(k0 + kr) * N + n0 + cc * 4];
    t[kr][cc*4+0] = f2bf(v.x); t[kr][cc*4+1] = f2bf(v.y);
    t[kr][cc*4+2] = f2bf(v.z); t[kr][cc*4+3] = f2bf(v.w);
  }
  __syncthreads();
#pragma unroll
  for (int i = 0; i < 4; ++i) {
    int nr = rr + i * 16;
    int r0 = cc * 4;
    ushort4 o;
    o.x = t[r0+0][nr]; o.y = t[r0+1][nr]; o.z = t[r0+2][nr]; o.w = t[r0+3][nr];
    *(ushort4*)&WT[(size_t)(n0 + nr) * K + k0 + r0] = o;
  }
}

// ---------------- LayerNorm: bf16 row[1024] -> bf16
__global__ __launch_bounds__(256)
void ln_b_k(const u16* __restrict__ x, const float* __restrict__ gm,
            const float* __restrict__ bt, u16* __restrict__ o)
{
  int row = blockIdx.x;
  int tid = threadIdx.x;
  const ushort4 u = *(const ushort4*)&x[(size_t)row * DIMN + tid * 4];
  float4 v;
  v.x = bf2f(u.x); v.y = bf2f(u.y); v.z = bf2f(u.z); v.w = bf2f(u.w);
  float s = v.x + v.y + v.z + v.w;
  float q = v.x*v.x + v.y*v.y + v.z*v.z + v.w*v.w;
#pragma unroll
  for (int off = 32; off; off >>= 1) { s += __shfl_xor(s, off); q += __shfl_xor(q, off); }
  __shared__ float ss[4], qq[4];
  int wave = tid >> 6;
  if ((tid & 63) == 0) { ss[wave] = s; qq[wave] = q; }
  __syncthreads();
  s = ss[0] + ss[1] + ss[2] + ss[3];
  q = qq[0] + qq[1] + qq[2] + qq[3];
  float mu = s * (1.0f / DIMN);
  float var = q * (1.0f / DIMN) - mu * mu;
  float rs = rsqrtf(var + 1e-5f);
  const float4 gv = *(const float4*)&gm[tid * 4];
  const float4 bv = *(const float4*)&bt[tid * 4];
  ushort4 r;
  r.x = f2bf((v.x - mu) * rs * gv.x + bv.x);
  r.y = f2bf((v.y - mu) * rs * gv.y + bv.y);
  r.z = f2bf((v.z - mu) * rs * gv.z + bv.z);
  r.w = f2bf((v.w - mu) * rs * gv.w + bv.w);
  *(ushort4*)&o[(size_t)row * DIMN + tid * 4] = r;
}

// ---------------- QKV GEMM, BK=64: M=4096 N=3072 K=1024, routed epilogue
// grid (32, 24), 512 threads
__global__ __launch_bounds__(512, 2)
void qkv64_k(const u16* __restrict__ A, const u16* __restrict__ Bt,
             u16* __restrict__ qb, u16* __restrict__ kb, u16* __restrict__ vtb)
{
  __shared__ __align__(16) u16 As[2][128 * 64];   // 32 KB
  __shared__ __align__(16) u16 Bs[2][128 * 64];   // 32 KB
  const int tid = threadIdx.x;
  const int lane = tid & 63, wave = tid >> 6;
  const int wr = wave >> 1, wc = wave & 1;
  const int g = lane >> 4, r16 = lane & 15;
  const int m0 = blockIdx.x * 128, n0 = blockIdx.y * 128;
  const int K = 1024;

  f32x4 acc[2][4] = {};

  int aro[2], bro[2], scs[2];
#pragma unroll
  for (int i = 0; i < 2; ++i) {
    const int c = tid + i * 512;
    const int r = c >> 3, ch = c & 7;
    scs[i] = ch ^ (r & 7);
    aro[i] = m0 + r;
    bro[i] = n0 + r;
  }

  auto stage = [&](int buf, int kt) {
#pragma unroll
    for (int i = 0; i < 2; ++i) {
      const int c = tid + i * 512;
      gload16(A  + (size_t)aro[i] * K + kt + scs[i] * 8, &As[buf][c * 8]);
      gload16(Bt + (size_t)bro[i] * K + kt + scs[i] * 8, &Bs[buf][c * 8]);
    }
  };

  stage(0, 0);

  const int nkt = K >> 6;
  for (int t = 0; t < nkt; ++t) {
    const int cur = t & 1;
    if (t + 1 < nkt) {
      stage(cur ^ 1, (t + 1) << 6);
      asm volatile("s_waitcnt vmcnt(4)" ::: "memory");
    } else {
      asm volatile("s_waitcnt vmcnt(0)" ::: "memory");
    }
    __builtin_amdgcn_s_barrier();                        // B1

#pragma unroll
    for (int ks = 0; ks < 2; ++ks) {
      bf16x8 af[2], bfr[4];
#pragma unroll
      for (int mi = 0; mi < 2; ++mi) {
        int r = wr * 32 + mi * 16 + r16;
        int cph = (ks * 4 + g) ^ (r & 7);
        af[mi] = *(const bf16x8*)&As[cur][(r * 8 + cph) * 8];
      }
#pragma unroll
      for (int ni = 0; ni < 4; ++ni) {
        int r = wc * 64 + ni * 16 + r16;
        int cph = (ks * 4 + g) ^ (r & 7);
        bfr[ni] = *(const bf16x8*)&Bs[cur][(r * 8 + cph) * 8];
      }
      __builtin_amdgcn_s_setprio(1);
#pragma unroll
      for (int mi = 0; mi < 2; ++mi)
#pragma unroll
        for (int ni = 0; ni < 4; ++ni)
          acc[mi][ni] = mfma16(af[mi], bfr[ni], acc[mi][ni]);
      __builtin_amdgcn_s_setprio(0);
    }

    __builtin_amdgcn_s_barrier();                        // B2 (WAR)
  }

  const int grp = n0 >> 10;
#pragma unroll
  for (int ni = 0; ni < 4; ++ni) {
    int col = n0 + wc * 64 + ni * 16 + r16;
    const int c1 = col & 1023;
#pragma unroll
    for (int mi = 0; mi < 2; ++mi) {
#pragma unroll
      for (int rg = 0; rg < 4; ++rg) {
        int row = m0 + wr * 32 + mi * 16 + g * 4 + rg;
        float v = acc[mi][ni][rg];
        if (grp == 0) {
          qb[(size_t)row * 1024 + c1] = f2bf(v);
        } else if (grp == 1) {
          kb[(size_t)row * 1024 + c1] = f2bf(v);
        } else {
          int b = row >> 11, srow_ = row & 2047;      // seq = 2048
          int jg = srow_ >> 6, j = srow_ & 63;
          int pos = jg * 64 + ((j & 15) << 2) + (j >> 4);
          vtb[((size_t)b * HEADS * DHEAD + c1) * SEQ + pos] = f2bf(v);
        }
      }
    }
  }
}

// ---------------- GEMM BK=64 for grid<=256 launches.
// MODE 0: out bf16 = acc + bias (no resid)
// MODE 6: out bf16 = acc + bias + residf (f32 resid)
// MODE 7: out bf16 = acc + bias + residb (bf16 resid)
// MODE 8: out f32  = acc + bias + residb (bf16 resid)
template<int MODE>
__global__ __launch_bounds__(512, 2)
void gemm64_k(const u16* __restrict__ A, const u16* __restrict__ Bt,
              int M, int N, int K,
              const float* __restrict__ bias, const float* __restrict__ residf,
              const u16* __restrict__ residb,
              u16* __restrict__ obf, float* __restrict__ of32)
{
  __shared__ __align__(16) u16 As[2][128 * 64];   // 32 KB
  __shared__ __align__(16) u16 Bs[2][128 * 64];   // 32 KB
  const int tid = threadIdx.x;
  const int lane = tid & 63, wave = tid >> 6;
  const int wr = wave >> 1, wc = wave & 1;          // 4 x 2 wave grid, 32x64 tiles
  const int g = lane >> 4, r16 = lane & 15;
  const int m0 = blockIdx.x * 128, n0 = blockIdx.y * 128;

  f32x4 acc[2][4] = {};

  int aro[2], bro[2], scs[2];
#pragma unroll
  for (int i = 0; i < 2; ++i) {
    const int c = tid + i * 512;
    const int r = c >> 3, ch = c & 7;
    scs[i] = ch ^ (r & 7);
    aro[i] = (m0 + r > M - 1) ? (M - 1) : (m0 + r);
    bro[i] = n0 + r;
  }

  auto stage = [&](int buf, int kt) {
#pragma unroll
    for (int i = 0; i < 2; ++i) {
      const int c = tid + i * 512;
      gload16(A  + (size_t)aro[i] * K + kt + scs[i] * 8, &As[buf][c * 8]);
      gload16(Bt + (size_t)bro[i] * K + kt + scs[i] * 8, &Bs[buf][c * 8]);
    }
  };

  stage(0, 0);

  const int nkt = K >> 6;
  for (int t = 0; t < nkt; ++t) {
    const int cur = t & 1;
    if (t + 1 < nkt) {
      stage(cur ^ 1, (t + 1) << 6);
      asm volatile("s_waitcnt vmcnt(4)" ::: "memory");
    } else {
      asm volatile("s_waitcnt vmcnt(0)" ::: "memory");
    }
    __builtin_amdgcn_s_barrier();                        // B1

#pragma unroll
    for (int ks = 0; ks < 2; ++ks) {
      bf16x8 af[2], bfr[4];
#pragma unroll
      for (int mi = 0; mi < 2; ++mi) {
        int r = wr * 32 + mi * 16 + r16;
        int cph = (ks * 4 + g) ^ (r & 7);
        af[mi] = *(const bf16x8*)&As[cur][(r * 8 + cph) * 8];
      }
#pragma unroll
      for (int ni = 0; ni < 4; ++ni) {
        int r = wc * 64 + ni * 16 + r16;
        int cph = (ks * 4 + g) ^ (r & 7);
        bfr[ni] = *(const bf16x8*)&Bs[cur][(r * 8 + cph) * 8];
      }
      __builtin_amdgcn_s_setprio(1);
#pragma unroll
      for (int mi = 0; mi < 2; ++mi)
#pragma unroll
        for (int ni = 0; ni < 4; ++ni)
          acc[mi][ni] = mfma16(af[mi], bfr[ni], acc[mi][ni]);
      __builtin_amdgcn_s_setprio(0);
    }

    __builtin_amdgcn_s_barrier();                        // B2 (WAR)
  }

#pragma unroll
  for (int ni = 0; ni < 4; ++ni) {
    int col = n0 + wc * 64 + ni * 16 + r16;
    float bv = bias ? bias[col] : 0.0f;
#pragma unroll
    for (int mi = 0; mi < 2; ++mi) {
      f32x4 c = acc[mi][ni];
#pragma unroll
      for (int rg = 0; rg < 4; ++rg) {
        int row = m0 + wr * 32 + mi * 16 + g * 4 + rg;
        if (row < M) {
          float v = c[rg] + bv;
          size_t o = (size_t)row * N + col;
          if constexpr (MODE == 0) {
            obf[o] = f2bf(v);
          } else if constexpr (MODE == 6) {
            obf[o] = f2bf(v + residf[o]);
          } else if constexpr (MODE == 7) {
            obf[o] = f2bf(v + bf2f(residb[o]));
          } else {  // MODE 8
            of32[o] = v + bf2f(residb[o]);
          }
        }
      }
    }
  }
}

// ---------------- merged Q2 (BK=64, 256 blocks) + KV2 (BK=32, 32 blocks)
// grid = 288 x 512 threads
__global__ __launch_bounds__(512, 2)
void q2kv2_k(const u16* __restrict__ hb, const u16* __restrict__ WqT2,
             u16* __restrict__ qb,
             const u16* __restrict__ ctxb, const u16* __restrict__ WkT2,
             u16* __restrict__ k2b, u16* __restrict__ vt2b)
{
  __shared__ __align__(16) u16 AsB[2][128 * 64];
  __shared__ __align__(16) u16 BsB[2][128 * 64];
  const int tid = threadIdx.x;
  const int lane = tid & 63, wave = tid >> 6;
  const int wr = wave >> 1, wc = wave & 1;
  const int g = lane >> 4, r16 = lane & 15;
  const int bid = blockIdx.x;

  if (bid < 256) {
    // ======== Q2: M=4096 N=1024 K=1024, BK=64, out bf16 no bias ========
    const int K = 1024;
    const int m0 = (bid & 31) * 128, n0 = (bid >> 5) * 128;
    f32x4 acc[2][4] = {};

    int aro[2], bro[2], scs[2];
#pragma unroll
    for (int i = 0; i < 2; ++i) {
      const int c = tid + i * 512;
      const int r = c >> 3, ch = c & 7;
      scs[i] = ch ^ (r & 7);
      aro[i] = m0 + r;
      bro[i] = n0 + r;
    }
    auto stage = [&](int buf, int kt) {
#pragma unroll
      for (int i = 0; i < 2; ++i) {
        const int c = tid + i * 512;
        gload16(hb   + (size_t)aro[i] * K + kt + scs[i] * 8, &AsB[buf][c * 8]);
        gload16(WqT2 + (size_t)bro[i] * K + kt + scs[i] * 8, &BsB[buf][c * 8]);
      }
    };
    stage(0, 0);
    const int nkt = K >> 6;
    for (int t = 0; t < nkt; ++t) {
      const int cur = t & 1;
      if (t + 1 < nkt) {
        stage(cur ^ 1, (t + 1) << 6);
        asm volatile("s_waitcnt vmcnt(4)" ::: "memory");
      } else {
        asm volatile("s_waitcnt vmcnt(0)" ::: "memory");
      }
      __builtin_amdgcn_s_barrier();
#pragma unroll
      for (int ks = 0; ks < 2; ++ks) {
        bf16x8 af[2], bfr[4];
#pragma unroll
        for (int mi = 0; mi < 2; ++mi) {
          int r = wr * 32 + mi * 16 + r16;
          int cph = (ks * 4 + g) ^ (r & 7);
          af[mi] = *(const bf16x8*)&AsB[cur][(r * 8 + cph) * 8];
        }
#pragma unroll
        for (int ni = 0; ni < 4; ++ni) {
          int r = wc * 64 + ni * 16 + r16;
          int cph = (ks * 4 + g) ^ (r & 7);
          bfr[ni] = *(const bf16x8*)&BsB[cur][(r * 8 + cph) * 8];
        }
        __builtin_amdgcn_s_setprio(1);
#pragma unroll
        for (int mi = 0; mi < 2; ++mi)
#pragma unroll
          for (int ni = 0; ni < 4; ++ni)
            acc[mi][ni] = mfma16(af[mi], bfr[ni], acc[mi][ni]);
        __builtin_amdgcn_s_setprio(0);
      }
      __builtin_amdgcn_s_barrier();
    }
#pragma unroll
    for (int ni = 0; ni < 4; ++ni) {
      int col = n0 + wc * 64 + ni * 16 + r16;
#pragma unroll
      for (int mi = 0; mi < 2; ++mi) {
#pragma unroll
        for (int rg = 0; rg < 4; ++rg) {
          int row = m0 + wr * 32 + mi * 16 + g * 4 + rg;
          qb[(size_t)row * 1024 + col] = f2bf(acc[mi][ni][rg]);
        }
      }
    }
  } else {
    // ======== KV2: M=CTOK N=2048 K=768, BK=32, mode-5 epilogue ========
    const int K = 768, M = CTOK;
    const int local = bid - 256;
    const int m0 = (local & 1) * 128, n0 = (local >> 1) * 128;
    u16* As = &AsB[0][0];
    u16* Bs = &BsB[0][0];
    const int BUFS = 128 * 32;
    f32x4 acc[2][4] = {};

    const int srow = tid >> 2;
    const int sch  = tid & 3;
    const int schs = sch ^ ((srow >> 1) & 3);
    const int arow = (m0 + srow > M - 1) ? (M - 1) : (m0 + srow);
    const size_t abase = (size_t)arow * K + schs * 8;
    const size_t bbase = (size_t)(n0 + srow) * K + schs * 8;

    auto stage = [&](int buf, int kt) {
      gload16(ctxb + abase + kt, &As[buf * BUFS + tid * 8]);
      gload16(WkT2 + bbase + kt, &Bs[buf * BUFS + tid * 8]);
    };
    stage(0, 0);
    const int nkt = K >> 5;
    for (int t = 0; t < nkt; ++t) {
      const int cur = t & 1;
      if (t + 1 < nkt) {
        stage(cur ^ 1, (t + 1) << 5);
        asm volatile("s_waitcnt vmcnt(2)" ::: "memory");
      } else {
        asm volatile("s_waitcnt vmcnt(0)" ::: "memory");
      }
      __builtin_amdgcn_s_barrier();

      bf16x8 af[2], bfr[4];
#pragma unroll
      for (int mi = 0; mi < 2; ++mi) {
        int r = wr * 32 + mi * 16 + r16;
        int cph = g ^ ((r >> 1) & 3);
        af[mi] = *(const bf16x8*)&As[cur * BUFS + (r * 4 + cph) * 8];
      }
#pragma unroll
      for (int ni = 0; ni < 4; ++ni) {
        int r = wc * 64 + ni * 16 + r16;
        int cph = g ^ ((r >> 1) & 3);
        bfr[ni] = *(const bf16x8*)&Bs[cur * BUFS + (r * 4 + cph) * 8];
      }
      __builtin_amdgcn_s_setprio(1);
#pragma unroll
      for (int mi = 0; mi < 2; ++mi)
#pragma unroll
        for (int ni = 0; ni < 4; ++ni)
          acc[mi][ni] = mfma16(af[mi], bfr[ni], acc[mi][ni]);
      __builtin_amdgcn_s_setprio(0);

      __builtin_amdgcn_s_barrier();
    }

    const int grp = n0 >> 10;
#pragma unroll
    for (int ni = 0; ni < 4; ++ni) {
      int col = n0 + wc * 64 + ni * 16 + r16;
      const int c1 = col & 1023;
#pragma unroll
      for (int mi = 0; mi < 2; ++mi) {
#pragma unroll
        for (int rg = 0; rg < 4; ++rg) {
          int row = m0 + wr * 32 + mi * 16 + g * 4 + rg;
          if (row < M) {
            float v = acc[mi][ni][rg];
            if (grp == 0) {
              k2b[(size_t)row * 1024 + c1] = f2bf(v);
            } else {
              int b = row / NCTX, srow_ = row - b * NCTX;
              int jg = srow_ >> 6, j = srow_ & 63;
              int pos = jg * 64 + ((j & 15) << 2) + (j >> 4);
              vt2b[((size_t)b * HEADS * DHEAD + c1) * 128 + pos] = f2bf(v);
            }
          }
        }
      }
    }
  }
}

// ---------------- fused GEGLU GEMM (R5-proven): 512 thr, 128x128, 2-buf counted vmcnt
__global__ __launch_bounds__(512, 2)
void geglu_k(const u16* __restrict__ A, const u16* __restrict__ B1t,
             const u16* __restrict__ B2t,
             const float* __restrict__ ba, const float* __restrict__ bg,
             u16* __restrict__ out, int M, int N)
{
  __shared__ __align__(16) u16 As[2][128 * 32];
  __shared__ __align__(16) u16 B1s[2][128 * 32];
  __shared__ __align__(16) u16 B2s[2][128 * 32];
  const int tid = threadIdx.x;
  const int lane = tid & 63, wave = tid >> 6;
  const int wr = wave >> 1, wc = wave & 1;
  const int g = lane >> 4, r16 = lane & 15;
  const int m0 = blockIdx.x * 128, n0 = blockIdx.y * 128;
  const int K = 1024;

  f32x4 acca[2][4] = {}, accg[2][4] = {};

  const int srow = tid >> 2;
  const int sch  = tid & 3;
  const int schs = sch ^ ((srow >> 1) & 3);
  const size_t abase = (size_t)(m0 + srow) * K + schs * 8;
  const size_t bbase = (size_t)(n0 + srow) * K + schs * 8;

  auto stage = [&](int buf, int kt) {
    gload16(A   + abase + kt, &As[buf][tid * 8]);
    gload16(B1t + bbase + kt, &B1s[buf][tid * 8]);
    gload16(B2t + bbase + kt, &B2s[buf][tid * 8]);
  };

  stage(0, 0);

  const int nkt = K >> 5;
  for (int t = 0; t < nkt; ++t) {
    const int cur = t & 1;
    if (t + 1 < nkt) {
      stage(cur ^ 1, (t + 1) << 5);
      asm volatile("s_waitcnt vmcnt(3)" ::: "memory");
    } else {
      asm volatile("s_waitcnt vmcnt(0)" ::: "memory");
    }
    __builtin_amdgcn_s_barrier();                        // B1

    bf16x8 af[2], b1f[4], b2f[4];
#pragma unroll
    for (int mi = 0; mi < 2; ++mi) {
      int r = wr * 32 + mi * 16 + r16;
      int cph = g ^ ((r >> 1) & 3);
      af[mi] = *(const bf16x8*)&As[cur][(r * 4 + cph) * 8];
    }
#pragma unroll
    for (int ni = 0; ni < 4; ++ni) {
      int r = wc * 64 + ni * 16 + r16;
      int cph = g ^ ((r >> 1) & 3);
      b1f[ni] = *(const bf16x8*)&B1s[cur][(r * 4 + cph) * 8];
      b2f[ni] = *(const bf16x8*)&B2s[cur][(r * 4 + cph) * 8];
    }
    __builtin_amdgcn_s_setprio(1);
#pragma unroll
    for (int mi = 0; mi < 2; ++mi)
#pragma unroll
      for (int ni = 0; ni < 4; ++ni) {
        acca[mi][ni] = mfma16(af[mi], b1f[ni], acca[mi][ni]);
        accg[mi][ni] = mfma16(af[mi], b2f[ni], accg[mi][ni]);
      }
    __builtin_amdgcn_s_setprio(0);

    __builtin_amdgcn_s_barrier();                        // B2
  }

#pragma unroll
  for (int ni = 0; ni < 4; ++ni) {
    int col = n0 + wc * 64 + ni * 16 + r16;
    float bva = ba[col], bvg = bg[col];
#pragma unroll
    for (int mi = 0; mi < 2; ++mi) {
#pragma unroll
      for (int rg = 0; rg < 4; ++rg) {
        int row = m0 + wr * 32 + mi * 16 + g * 4 + rg;
        float a  = acca[mi][ni][rg] + bva;
        float gt = accg[mi][ni][rg] + bvg;
        float gl = 0.5f * gt * (1.0f + erff(gt * 0.70710678f));
        out[(size_t)row * N + col] = f2bf(a * gl);
      }
    }
  }
}

// ---------------- flash attention v6: 8 waves (256 q/block), KVBLK=128, XCD-affine
// grid MUST be (8, 32)
__global__ __launch_bounds__(512, 1)
void attn_k(const u16* __restrict__ q, const u16* __restrict__ k,
            const u16* __restrict__ vt, u16* __restrict__ o,
            int kvlen, int seqk, int vstride)
{
  __shared__ __align__(16) u16 Ks[2][128 * 64];   // [kv][d], chunk-swizzled (8/row)
  __shared__ __align__(16) u16 Vs[2][64 * 128];   // [d][kv], chunk-swizzled (16/row)
  __shared__ __align__(16) u16 Ps[8][32 * 136];   // per-wave P, 2 granules of 64
  const int tid = threadIdx.x, lane = tid & 63, wave = tid >> 6;
  const int g = lane >> 4, r16 = lane & 15;

  // XCD-affine remap: L%8 = XCD. Each XCD c owns heads 4c..4c+3 fully.
  const int L  = blockIdx.y * 8 + blockIdx.x;
  const int c8 = L & 7, tt = L >> 3;
  const int bx = tt & 7;
  const int bh = c8 * 4 + (tt >> 3);

  const int b = bh >> 4, h = bh & 15;
  const int q0 = bx * 256 + wave * 32;
  const float C = 0.18033688f;   // log2(e)/8

  bf16x8 aq[2][2];
#pragma unroll
  for (int qs = 0; qs < 2; ++qs) {
    const size_t qoff = (size_t)(b * SEQ + q0 + qs * 16 + r16) * DIMN + h * DHEAD;
#pragma unroll
    for (int kc = 0; kc < 2; ++kc)
      aq[qs][kc] = *(const bf16x8*)&q[qoff + kc * 32 + g * 8];
  }
  asm volatile("" :: "v"(aq[0][0]), "v"(aq[0][1]), "v"(aq[1][0]), "v"(aq[1][1]));

  f32x4 oacc[2][4] = {};
  float mi[2][4], li[2][4];
#pragma unroll
  for (int qs = 0; qs < 2; ++qs)
#pragma unroll
    for (int rg = 0; rg < 4; ++rg) { mi[qs][rg] = -3e38f; li[qs][rg] = 0.f; }

  const size_t vtbase = (size_t)(b * HEADS + h) * DHEAD * vstride;
  const size_t kbase  = (size_t)b * seqk * DIMN + h * DHEAD;
  const int nkv = (kvlen + 127) >> 7;

  auto stage = [&](int buf, int kv0) {
#pragma unroll
    for (int i = 0; i < 2; ++i) {
      const int c = tid + i * 512;
      const int row = c >> 3, ch = c & 7;
      const int chs = ch ^ (row & 7);
      int kr = kv0 + row; if (kr > kvlen - 1) kr = kvlen - 1;
      gload16(k + kbase + (size_t)kr * DIMN + chs * 8, &Ks[buf][c * 8]);
    }
#pragma unroll
    for (int i = 0; i < 2; ++i) {
      const int c = tid + i * 512;
      const int row = c >> 4, ch = c & 15;
      const int chs = ch ^ (row & 15);
      gload16(vt + vtbase + (size_t)row * vstride + kv0 + chs * 8, &Vs[buf][c * 8]);
    }
  };

  stage(0, 0);

  for (int kvb = 0; kvb < nkv; ++kvb) {
    const int kv0 = kvb * 128;
    const int cur = kvb & 1;
    if (kvb + 1 < nkv) {
      stage(cur ^ 1, kv0 + 128);
      asm volatile("s_waitcnt vmcnt(4)" ::: "memory");
    } else {
      asm volatile("s_waitcnt vmcnt(0)" ::: "memory");
    }
    __builtin_amdgcn_s_barrier();                        // B1

    // ---- QK^T: 32 MFMA
    f32x4 sa[2][8];
#pragma unroll
    for (int qs = 0; qs < 2; ++qs)
#pragma unroll
      for (int st = 0; st < 8; ++st) sa[qs][st] = (f32x4){0.f, 0.f, 0.f, 0.f};
    __builtin_amdgcn_s_setprio(1);
#pragma unroll
    for (int st = 0; st < 8; ++st) {
      const int kvr = st * 16 + r16;
#pragma unroll
      for (int kc = 0; kc < 2; ++kc) {
        const int chs = (kc * 4 + g) ^ (kvr & 7);
        const bf16x8 kf = *(const bf16x8*)&Ks[cur][kvr * 64 + chs * 8];
        sa[0][st] = mfma16(aq[0][kc], kf, sa[0][st]);
        sa[1][st] = mfma16(aq[1][kc], kf, sa[1][st]);
      }
    }
    __builtin_amdgcn_s_setprio(0);

    // ---- tail mask (cross-attn only)
    if (kv0 + 128 > kvlen) {
#pragma unroll
      for (int st = 0; st < 8; ++st)
        if (kv0 + st * 16 + r16 >= kvlen) {
#pragma unroll
          for (int qs = 0; qs < 2; ++qs)
#pragma unroll
            for (int rg = 0; rg < 4; ++rg) sa[qs][st][rg] = -3e38f;
        }
    }

    // ---- defer-max check
    float bad = 0.f;
    float m4v[2][4];
#pragma unroll
    for (int qs = 0; qs < 2; ++qs)
#pragma unroll
      for (int rg = 0; rg < 4; ++rg) {
        float m4 = fmaxf(fmaxf(sa[qs][0][rg], sa[qs][1][rg]),
                         fmaxf(sa[qs][2][rg], sa[qs][3][rg]));
        m4 = fmaxf(m4, fmaxf(fmaxf(sa[qs][4][rg], sa[qs][5][rg]),
                             fmaxf(sa[qs][6][rg], sa[qs][7][rg])));
        m4v[qs][rg] = m4;
        bad = fmaxf(bad, m4 - mi[qs][rg]);
      }
    if (__any(bad > 16.0f)) {
#pragma unroll
      for (int qs = 0; qs < 2; ++qs)
#pragma unroll
        for (int rg = 0; rg < 4; ++rg) {
          float mx = m4v[qs][rg];
#pragma unroll
          for (int off = 1; off < 16; off <<= 1) mx = fmaxf(mx, __shfl_xor(mx, off));
          const float nm = fmaxf(mi[qs][rg], mx);
          const float corr = __builtin_amdgcn_exp2f((mi[qs][rg] - nm) * C);
          mi[qs][rg] = nm;
          li[qs][rg] *= corr;
#pragma unroll
          for (int ds = 0; ds < 4; ++ds) oacc[qs][ds][rg] *= corr;
        }
    }

    // ---- P = exp (two 64-granules), lane-local li, packed bf16 store
#pragma unroll
    for (int qs = 0; qs < 2; ++qs) {
#pragma unroll
      for (int rg = 0; rg < 4; ++rg) {
        const float mc = mi[qs][rg] * C;
        float p[8];
#pragma unroll
        for (int st = 0; st < 8; ++st)
          p[st] = __builtin_amdgcn_exp2f(__builtin_fmaf(sa[qs][st][rg], C, -mc));
        li[qs][rg] += ((p[0] + p[1]) + (p[2] + p[3])) + ((p[4] + p[5]) + (p[6] + p[7]));
        unsigned w0, w1, w2, w3;
        asm("v_cvt_pk_bf16_f32 %0, %1, %2" : "=v"(w0) : "v"(p[0]), "v"(p[1]));
        asm("v_cvt_pk_bf16_f32 %0, %1, %2" : "=v"(w1) : "v"(p[2]), "v"(p[3]));
        asm("v_cvt_pk_bf16_f32 %0, %1, %2" : "=v"(w2) : "v"(p[4]), "v"(p[5]));
        asm("v_cvt_pk_bf16_f32 %0, %1, %2" : "=v"(w3) : "v"(p[6]), "v"(p[7]));
        const int prow = qs * 16 + g * 4 + rg;
        uint2 pk0; pk0.x = w0; pk0.y = w1;
        uint2 pk1; pk1.x = w2; pk1.y = w3;
        *(uint2*)&Ps[wave][prow * 136 + r16 * 4]      = pk0;
        *(uint2*)&Ps[wave][prow * 136 + 64 + r16 * 4] = pk1;
      }
    }

    // ---- PV: 32 MFMA
    __builtin_amdgcn_s_setprio(1);
#pragma unroll
    for (int kc = 0; kc < 4; ++kc) {
      const bf16x8 pa0 = *(const bf16x8*)&Ps[wave][(r16)      * 136 + kc * 32 + g * 8];
      const bf16x8 pa1 = *(const bf16x8*)&Ps[wave][(16 + r16) * 136 + kc * 32 + g * 8];
#pragma unroll
      for (int ds = 0; ds < 4; ++ds) {
        const int dr = ds * 16 + r16;
        const int cc = kc * 4 + g;
        const int chs = cc ^ (dr & 15);
        const bf16x8 vf = *(const bf16x8*)&Vs[cur][dr * 128 + chs * 8];
        oacc[0][ds] = mfma16(pa0, vf, oacc[0][ds]);
        oacc[1][ds] = mfma16(pa1, vf, oacc[1][ds]);
      }
    }
    __builtin_amdgcn_s_setprio(0);

    __builtin_amdgcn_s_barrier();                        // B2
  }

#pragma unroll
  for (int qs = 0; qs < 2; ++qs)
#pragma unroll
    for (int rg = 0; rg < 4; ++rg) {
      float s = li[qs][rg];
#pragma unroll
      for (int off = 1; off < 16; off <<= 1) s += __shfl_xor(s, off);
      li[qs][rg] = s;
    }

#pragma unroll
  for (int qs = 0; qs < 2; ++qs)
#pragma unroll
    for (int rg = 0; rg < 4; ++rg) {
      const float inv = 1.0f / li[qs][rg];
      const int row = q0 + qs * 16 + g * 4 + rg;
      const size_t base = (size_t)(b * SEQ + row) * DIMN + h * DHEAD;
#pragma unroll
      for (int ds = 0; ds < 4; ++ds)
        o[base + ds * 16 + r16] = f2bf(oacc[qs][ds][rg] * inv);
    }
}

extern "C" void kernel_launch(void* const* d_in, const int* in_sizes, int n_in,
                              void* d_out, int out_size, void* d_ws, size_t ws_size,
                              hipStream_t stream)
{
  const float* x   = (const float*)d_in[0];
  const float* ctx = (const float*)d_in[1];
  const float* Wq1 = (const float*)d_in[2];
  const float* Wk1 = (const float*)d_in[3];
  const float* Wv1 = (const float*)d_in[4];
  const float* Wo1 = (const float*)d_in[5];
  const float* bo1 = (const float*)d_in[6];
  const float* Wq2 = (const float*)d_in[7];
  const float* Wk2 = (const float*)d_in[8];
  const float* Wv2 = (const float*)d_in[9];
  const float* Wo2 = (const float*)d_in[10];
  const float* bo2 = (const float*)d_in[11];
  const float* Wp  = (const float*)d_in[12];
  const float* bp  = (const float*)d_in[13];
  const float* W2  = (const float*)d_in[14];
  const float* b2  = (const float*)d_in[15];
  const float* g1  = (const float*)d_in[16];
  const float* be1 = (const float*)d_in[17];
  const float* g2  = (const float*)d_in[18];
  const float* be2 = (const float*)d_in[19];
  const float* g3  = (const float*)d_in[20];
  const float* be3 = (const float*)d_in[21];

  char* ws = (char*)d_ws;
  size_t off = 0;
  auto alloc = [&](size_t bytes) -> void* {
    void* p = ws + off;
    off += (bytes + 255) & ~(size_t)255;
    return p;
  };

  u16* WqT1 = (u16*)alloc((size_t)1024 * 1024 * 2);   // contiguous with WkT1, WvT1
  u16* WkT1 = (u16*)alloc((size_t)1024 * 1024 * 2);
  u16* WvT1 = (u16*)alloc((size_t)1024 * 1024 * 2);
  u16* WoT1 = (u16*)alloc((size_t)1024 * 1024 * 2);
  u16* WqT2 = (u16*)alloc((size_t)1024 * 1024 * 2);
  u16* WkT2 = (u16*)alloc((size_t)1024 * 768 * 2);    // contiguous with WvT2
  u16* WvT2 = (u16*)alloc((size_t)1024 * 768 * 2);
  u16* WoT2 = (u16*)alloc((size_t)1024 * 1024 * 2);
  u16* WpT  = (u16*)alloc((size_t)8192 * 1024 * 2);
  u16* W2T  = (u16*)alloc((size_t)1024 * 4096 * 2);
  u16* x1b  = (u16*)alloc((size_t)NTOK * DIMN * 2);
  u16* x2b  = (u16*)alloc((size_t)NTOK * DIMN * 2);
  u16* ctxb = (u16*)alloc((size_t)CTOK * CTXD * 2);
  u16* k2b  = (u16*)alloc((size_t)CTOK * DIMN * 2);
  u16* vt2b = (u16*)alloc((size_t)2 * HEADS * DHEAD * 128 * 2);
  u16* hb   = (u16*)alloc((size_t)NTOK * DIMN * 2);
  u16* qb   = (u16*)alloc((size_t)NTOK * DIMN * 2);
  u16* kb   = (u16*)alloc((size_t)NTOK * DIMN * 2);
  u16* vtb  = (u16*)alloc((size_t)NTOK * DIMN * 2);
  u16* ab   = (u16*)alloc((size_t)NTOK * DIMN * 2);
  u16* ub   = qb; // reuse qb..ab region (32MB) for FF intermediate [4096][4096]

  dim3 blk(256);
  dim3 blk5(512);

  // single prologue dispatch: 10 weight transposes + LN1 + ctx conversion
  WAll wa;
  wa.nw = 10;
  const float* srcs[10] = {Wq1, Wk1, Wv1, Wo1, Wq2, Wo2, Wk2, Wv2, Wp, W2};
  u16* dsts[10]         = {WqT1, WkT1, WvT1, WoT1, WqT2, WoT2, WkT2, WvT2, WpT, W2T};
  const int Ksz[10]     = {1024, 1024, 1024, 1024, 1024, 1024, 768, 768, 1024, 4096};
  const int Nsz[10]     = {1024, 1024, 1024, 1024, 1024, 1024, 1024, 1024, 8192, 1024};
  int tot = 0;
  for (int i = 0; i < 10; ++i) {
    wa.start[i] = tot; wa.s[i] = srcs[i]; wa.d[i] = dsts[i];
    wa.K[i] = Ksz[i];  wa.N[i] = Nsz[i];
    tot += (Nsz[i] >> 6) * (Ksz[i] >> 6);
  }
  wa.lnStart = tot;
  wa.ccStart = tot + NTOK;
  wa.x = x; wa.g1 = g1; wa.be1 = be1; wa.hb = hb;
  wa.ctx = ctx; wa.ctxb = ctxb;
  const int ccBlocks = (CTOK * CTXD + 255) / 256;
  wconvA_k<<<dim3(tot + NTOK + ccBlocks), blk, 0, stream>>>(wa);

  // ---- self attention block (QKV fused, BK=64)
  qkv64_k<<<dim3(32, 24), blk5, 0, stream>>>(hb, WqT1, qb, kb, vtb);
  attn_k<<<dim3(8, 32), blk5, 0, stream>>>(qb, kb, vtb, ab, SEQ, SEQ, SEQ);
  gemm64_k<6><<<dim3(32, 8), blk5, 0, stream>>>(ab, WoT1, NTOK, 1024, 1024, bo1, x, nullptr, x1b, nullptr);

  // ---- cross attention block (Q2 + KV2 merged into one dispatch)
  ln_b_k<<<NTOK, 256, 0, stream>>>(x1b, g2, be2, hb);
  q2kv2_k<<<dim3(288), blk5, 0, stream>>>(hb, WqT2, qb, ctxb, WkT2, k2b, vt2b);
  attn_k<<<dim3(8, 32), blk5, 0, stream>>>(qb, k2b, vt2b, ab, NCTX, NCTX, 128);
  gemm64_k<7><<<dim3(32, 8), blk5, 0, stream>>>(ab, WoT2, NTOK, 1024, 1024, bo2, nullptr, x1b, x2b, nullptr);

  // ---- GEGLU FF block
  ln_b_k<<<NTOK, 256, 0, stream>>>(x2b, g3, be3, hb);
  geglu_k<<<dim3(32, 32), blk5, 0, stream>>>(hb, WpT, WpT + (size_t)4096 * 1024, bp, bp + 4096, ub, NTOK, FFH);
  gemm64_k<8><<<dim3(32, 8), blk5, 0, stream>>>(ub, W2T, NTOK, 1024, 4096, b2, nullptr, x2b, nullptr, (float*)d_out);

  (void)in_sizes; (void)n_in; (void)out_size; (void)ws_size;
}